// Round 1
// baseline (2905.210 us; speedup 1.0000x reference)
//
#include <hip/hip_runtime.h>
#include <hip/hip_bf16.h>

#define QMAXF (127.0f/128.0f)

// ---- workspace layout (floats), written by prep_kernel every launch ----
enum {
  OFF_W1  = 0,                     // [3][2][128]   lw1 transposed [tap][c][o]
  OFF_B1  = OFF_W1 + 768,          // [128]
  OFF_CW  = OFF_B1 + 128,          // [3][32][128][4]  folded cw*cs, interleave-4 over c
  OFF_CB  = OFF_CW + 3*16384,      // [3][128]         cb*cs + ct
  OFF_LW  = OFF_CB + 384,          // [2][3][32][128][4]
  OFF_LB  = OFF_LW + 6*16384,      // [2][128]
  OFF_FW  = OFF_LB + 256,          // [32][48][4]      folded cwf*csf
  OFF_FB  = OFF_FW + 6144,         // [48]
  OFF_PW1 = OFF_FB + 48,           // [16][16]
  OFF_PB1 = OFF_PW1 + 256,
  OFF_PW2 = OFF_PB1 + 16,
  OFF_PB2 = OFF_PW2 + 256,
  OFF_PQ  = OFF_PB2 + 16,          // [49][16]
  OFF_QW  = OFF_PQ + 784,          // [3][32][32] fake-quantized vw
  OFF_QB  = OFF_QW + 3072,         // [3][32]     fake-quantized vb
  OFF_QW4 = OFF_QB + 96,           // [3][32]     fake-quantized vw4
  OFF_QB4 = OFF_QW4 + 96,          // [3]
  WS_TOTAL = OFF_QB4 + 3           // 159779 floats ~ 639 KB
};

// Runtime dtype sniff: bf16 storage -> even u16 indices are valid (0,1)-ish
// exponents; fp32 storage -> even indices are random low-mantissa bits.
__device__ __forceinline__ bool detect_bf16(const void* x){
  const unsigned short* u = (const unsigned short*)x;
  int hits = 0;
  #pragma unroll
  for (int i = 0; i < 32; i += 2){
    unsigned short h = u[i];
    hits += (h >= 0x3800 && h <= 0x3F80) ? 1 : 0;
  }
  return hits >= 12;
}

__device__ __forceinline__ float rd(const void* p, int i, bool bfl){
  return bfl ? __bfloat162float(((const __hip_bfloat16*)p)[i]) : ((const float*)p)[i];
}

// mish(x) = x * tanh(softplus(x)); softplus = max(x,0)+log1p(exp(-|x|))
__device__ __forceinline__ float mish_f(float v){
  float e  = __expf(-fabsf(v));
  float sp = fmaxf(v, 0.0f) + __logf(1.0f + e);
  float q  = __expf(-2.0f * sp);
  float t  = (1.0f - q) / (1.0f + q);
  return v * t;
}

__global__ void prep_kernel(const void* x, const void* lw1, const void* lb1, const void* lw23,
                            const void* lb23, const void* cw, const void* cb, const void* cs,
                            const void* ct, const void* cwf, const void* cbf, const void* csf,
                            const void* ctf, const void* pw1, const void* pb1, const void* pw2,
                            const void* pb2, const void* pq, const void* vw, const void* vb,
                            const void* vw4, const void* vb4, float* ws)
{
  const bool bfl = detect_bf16(x);
  for (int i = blockIdx.x*blockDim.x + threadIdx.x; i < WS_TOTAL; i += gridDim.x*blockDim.x){
    float v;
    if (i < OFF_B1){                       // W1 [tap][c][o] <- lw1[tap][o][c]
      int idx = i - OFF_W1; int tap = idx>>8, r = idx&255, c = r>>7, o = r&127;
      v = rd(lw1, (tap*128 + o)*2 + c, bfl);
    } else if (i < OFF_CW){ v = rd(lb1, i - OFF_B1, bfl); }
    else if (i < OFF_CB){                  // CW4: cw[l][o][c]*cs[l][o]
      int idx = i - OFF_CW; int l = idx/16384, r = idx&16383;
      int c4 = r>>9, r2 = r&511, o = r2>>2, j = r2&3, cc = c4*4 + j;
      v = rd(cw, (l*128 + o)*128 + cc, bfl) * rd(cs, l*128 + o, bfl);
    } else if (i < OFF_LW){                // CB: cb*cs + ct
      int idx = i - OFF_CB;
      v = rd(cb, idx, bfl)*rd(cs, idx, bfl) + rd(ct, idx, bfl);
    } else if (i < OFF_LB){                // LW4: lw23[l][tap][o][c]
      int idx = i - OFF_LW; int lt = idx/16384, r = idx&16383;
      int c4 = r>>9, r2 = r&511, o = r2>>2, j = r2&3, cc = c4*4 + j;
      v = rd(lw23, (lt*128 + o)*128 + cc, bfl);
    } else if (i < OFF_FW){ v = rd(lb23, i - OFF_LB, bfl); }
    else if (i < OFF_FB){                  // FW4: cwf[m][c]*csf[m]
      int idx = i - OFF_FW; int c4 = idx/192, r = idx%192, m = r>>2, j = r&3, cc = c4*4 + j;
      v = rd(cwf, m*128 + cc, bfl) * rd(csf, m, bfl);
    } else if (i < OFF_PW1){ int m = i - OFF_FB; v = rd(cbf, m, bfl)*rd(csf, m, bfl) + rd(ctf, m, bfl); }
    else if (i < OFF_PB1){ v = rd(pw1, i - OFF_PW1, bfl); }
    else if (i < OFF_PW2){ v = rd(pb1, i - OFF_PB1, bfl); }
    else if (i < OFF_PB2){ v = rd(pw2, i - OFF_PW2, bfl); }
    else if (i < OFF_PQ ){ v = rd(pb2, i - OFF_PB2, bfl); }
    else if (i < OFF_QW ){ v = rd(pq,  i - OFF_PQ,  bfl); }
    else if (i < OFF_QB ){                 // quantized vw (same linear layout)
      float w = rd(vw, i - OFF_QW, bfl); w = fminf(fmaxf(w, -1.0f), QMAXF);
      v = rintf(w * 128.0f) * 0.0078125f;
    }
    else if (i < OFF_QW4){ v = rintf(rd(vb,  i - OFF_QB,  bfl) * 16384.0f) * 6.103515625e-05f; }
    else if (i < OFF_QB4){
      float w = rd(vw4, i - OFF_QW4, bfl); w = fminf(fmaxf(w, -1.0f), QMAXF);
      v = rintf(w * 128.0f) * 0.0078125f;
    }
    else { v = rintf(rd(vb4, i - OFF_QB4, bfl) * 16384.0f) * 6.103515625e-05f; }
    ws[i] = v;
  }
}

// conv1x1 over NPOS positions, 8 chunks split (s,o): each thread does 4 chunks, 1 out-channel
template<int NPOS, bool ACT>
__device__ __forceinline__ void conv1x1_layer(const float* __restrict__ ws, int woff, int boff,
                                              const float* src, float* dst, int o, int s)
{
  float acc[4][NPOS];
  const float bb = ws[boff + o];
  #pragma unroll
  for (int gi = 0; gi < 4; ++gi)
    #pragma unroll
    for (int p = 0; p < NPOS; ++p) acc[gi][p] = bb;

  const float4* w4 = reinterpret_cast<const float4*>(ws + woff);
  for (int c4 = 0; c4 < 32; ++c4){
    const float4 w = w4[c4*128 + o];
    #pragma unroll
    for (int gi = 0; gi < 4; ++gi){
      const int g = s + 2*gi;
      #pragma unroll
      for (int p = 0; p < NPOS; ++p){
        const float4 a = *reinterpret_cast<const float4*>(&src[(g*9 + p)*128 + c4*4]);
        acc[gi][p] = fmaf(w.x, a.x, fmaf(w.y, a.y, fmaf(w.z, a.z, fmaf(w.w, a.w, acc[gi][p]))));
      }
    }
  }
  #pragma unroll
  for (int gi = 0; gi < 4; ++gi){
    const int g = s + 2*gi;
    #pragma unroll
    for (int p = 0; p < NPOS; ++p)
      dst[(g*9 + p)*128 + o] = ACT ? mish_f(acc[gi][p]) : acc[gi][p];
  }
}

// ladder conv: taps at (0,0),(1,0),(1,1); NIN x NIN -> NOUT x NOUT, always + mish
template<int NIN, int NOUT>
__device__ __forceinline__ void ladder_layer(const float* __restrict__ ws, int woff, int boff,
                                             const float* src, float* dst, int o, int s)
{
  float acc[4][NOUT*NOUT];
  const float bb = ws[boff + o];
  #pragma unroll
  for (int gi = 0; gi < 4; ++gi)
    #pragma unroll
    for (int p = 0; p < NOUT*NOUT; ++p) acc[gi][p] = bb;

  const float4* w4 = reinterpret_cast<const float4*>(ws + woff);
  #pragma unroll
  for (int tap = 0; tap < 3; ++tap){
    for (int c4 = 0; c4 < 32; ++c4){
      const float4 w = w4[(tap*32 + c4)*128 + o];
      #pragma unroll
      for (int gi = 0; gi < 4; ++gi){
        const int g = s + 2*gi;
        #pragma unroll
        for (int i = 0; i < NOUT; ++i)
        #pragma unroll
        for (int j = 0; j < NOUT; ++j){
          const int q = (tap == 0) ? (i*NIN + j) : ((tap == 1) ? ((i+1)*NIN + j) : ((i+1)*NIN + j + 1));
          const float4 a = *reinterpret_cast<const float4*>(&src[(g*9 + q)*128 + c4*4]);
          acc[gi][i*NOUT + j] = fmaf(w.x, a.x, fmaf(w.y, a.y, fmaf(w.z, a.z, fmaf(w.w, a.w, acc[gi][i*NOUT + j]))));
        }
      }
    }
  }
  #pragma unroll
  for (int gi = 0; gi < 4; ++gi){
    const int g = s + 2*gi;
    #pragma unroll
    for (int p = 0; p < NOUT*NOUT; ++p)
      dst[(g*9 + p)*128 + o] = mish_f(acc[gi][p]);
  }
}

__global__ __launch_bounds__(256, 2)
void fused_kernel(const void* __restrict__ xv, const float* __restrict__ ws, void* __restrict__ outv)
{
  __shared__ __align__(16) float actA[8*9*128];   // [g*9+p][c], 36 KB
  __shared__ __align__(16) float actB[8*9*128];   // 36 KB
  __shared__ float xin[8][2][16];
  __shared__ float xraw[98];
  __shared__ float qbuf[8][48];
  __shared__ float featL[48];
  __shared__ float pkA[16], pkB[16];
  __shared__ float vA[32], vB[32];

  const int tid = threadIdx.x;
  const int o = tid & 127;       // out-channel
  const int s = tid >> 7;        // chunk-parity group; handles g = s, s+2, s+4, s+6
  const int b = blockIdx.x;
  const bool bfl = detect_bf16(xv);

  if (tid < 98) xraw[tid] = rd(xv, b*98 + tid, bfl);
  __syncthreads();

  // build 8 rotated 4x4 crops: out[i,j] = crop[f_k(i,j)]
  {
    const int g = tid >> 5, r = tid & 31, c = r >> 4, p = r & 15;
    const int ri = p >> 2, rj = p & 3;
    const int k  = (0x13023120u >> (g*4)) & 0xF;    // {0,2,1,3,2,0,3,1}
    const int y0 = (g >= 4) ? 3 : 0;
    const int x0 = (g >= 2 && g <= 5) ? 3 : 0;
    int sy, sx;
    if      (k == 0){ sy = ri;     sx = rj;     }
    else if (k == 1){ sy = rj;     sx = 3 - ri; }
    else if (k == 2){ sy = 3 - ri; sx = 3 - rj; }
    else            { sy = 3 - rj; sx = ri;     }
    xin[g][c][p] = xraw[c*49 + (y0 + sy)*7 + (x0 + sx)];
  }
  __syncthreads();

  // L1 ladder (ci=2): 4x4 -> 3x3, + mish
  {
    float wt[3][2];
    #pragma unroll
    for (int tp = 0; tp < 3; ++tp){
      wt[tp][0] = ws[OFF_W1 + (tp*2 + 0)*128 + o];
      wt[tp][1] = ws[OFF_W1 + (tp*2 + 1)*128 + o];
    }
    const float bb = ws[OFF_B1 + o];
    #pragma unroll
    for (int gi = 0; gi < 4; ++gi){
      const int g = s + 2*gi;
      #pragma unroll
      for (int i = 0; i < 3; ++i)
      #pragma unroll
      for (int j = 0; j < 3; ++j){
        float a = bb;
        a = fmaf(wt[0][0], xin[g][0][i*4 + j],         a);
        a = fmaf(wt[0][1], xin[g][1][i*4 + j],         a);
        a = fmaf(wt[1][0], xin[g][0][(i+1)*4 + j],     a);
        a = fmaf(wt[1][1], xin[g][1][(i+1)*4 + j],     a);
        a = fmaf(wt[2][0], xin[g][0][(i+1)*4 + j + 1], a);
        a = fmaf(wt[2][1], xin[g][1][(i+1)*4 + j + 1], a);
        actA[(g*9 + i*3 + j)*128 + o] = mish_f(a);
      }
    }
  }
  __syncthreads();

  conv1x1_layer<9, true>(ws, OFF_CW + 0*16384, OFF_CB + 0*128, actA, actB, o, s);
  __syncthreads();
  ladder_layer<3, 2>(ws, OFF_LW + 0*49152, OFF_LB + 0*128, actB, actA, o, s);
  __syncthreads();
  conv1x1_layer<4, true>(ws, OFF_CW + 1*16384, OFF_CB + 1*128, actA, actB, o, s);
  __syncthreads();
  ladder_layer<2, 1>(ws, OFF_LW + 1*49152, OFF_LB + 1*128, actB, actA, o, s);
  __syncthreads();
  conv1x1_layer<1, true>(ws, OFF_CW + 2*16384, OFF_CB + 2*128, actA, actB, o, s);
  __syncthreads();

  // final 128 -> 48 (no act) + fake_quant into qbuf
  if (o < 48){
    float acc[4];
    const float bb = ws[OFF_FB + o];
    #pragma unroll
    for (int gi = 0; gi < 4; ++gi) acc[gi] = bb;
    const float4* w4 = reinterpret_cast<const float4*>(ws + OFF_FW);
    for (int c4 = 0; c4 < 32; ++c4){
      const float4 w = w4[c4*48 + o];
      #pragma unroll
      for (int gi = 0; gi < 4; ++gi){
        const int g = s + 2*gi;
        const float4 a = *reinterpret_cast<const float4*>(&actB[(g*9)*128 + c4*4]);
        acc[gi] = fmaf(w.x, a.x, fmaf(w.y, a.y, fmaf(w.z, a.z, fmaf(w.w, a.w, acc[gi]))));
      }
    }
    #pragma unroll
    for (int gi = 0; gi < 4; ++gi){
      const int g = s + 2*gi;
      const float h = fminf(fmaxf(acc[gi], -1.0f), QMAXF);
      qbuf[g][o] = rintf(h * 128.0f) * 0.0078125f;
    }
  }
  __syncthreads();

  if (tid < 48){
    float f = 0.0f;
    #pragma unroll
    for (int g = 0; g < 8; ++g) f += qbuf[g][tid];
    featL[tid] = f;
  }
  __syncthreads();

  // heads: policy (threads 0..48) and value (threads 64..95) in lockstep stages
  if (tid < 16){
    float a = ws[OFF_PB1 + tid];
    #pragma unroll
    for (int c = 0; c < 16; ++c) a = fmaf(featL[c], ws[OFF_PW1 + tid*16 + c], a);
    pkA[tid] = fmaxf(a, 0.0f);
  } else if (tid >= 64 && tid < 96){
    const int oo = tid - 64;
    float a = ws[OFF_QB + oo];
    #pragma unroll
    for (int c = 0; c < 32; ++c)
      a = fmaf(fminf(fmaxf(featL[16 + c], 0.0f), QMAXF), ws[OFF_QW + oo*32 + c], a);
    vA[oo] = a;
  }
  __syncthreads();

  if (tid < 16){
    float a = ws[OFF_PB2 + tid];
    #pragma unroll
    for (int c = 0; c < 16; ++c) a = fmaf(pkA[c], ws[OFF_PW2 + tid*16 + c], a);
    pkB[tid] = a;
  } else if (tid >= 64 && tid < 96){
    const int oo = tid - 64;
    float a = ws[OFF_QB + 32 + oo];
    #pragma unroll
    for (int c = 0; c < 32; ++c)
      a = fmaf(fminf(fmaxf(vA[c], 0.0f), QMAXF), ws[OFF_QW + 1024 + oo*32 + c], a);
    vB[oo] = a;
  }
  __syncthreads();

  if (tid < 49){
    float a = 0.0f;
    #pragma unroll
    for (int c = 0; c < 16; ++c) a = fmaf(pkB[c], ws[OFF_PQ + tid*16 + c], a);
    const int idx = 49152 + b*49 + tid;   // policy after v (16384*3)
    if (bfl) ((__hip_bfloat16*)outv)[idx] = __float2bfloat16(a);
    else     ((float*)outv)[idx] = a;
  } else if (tid >= 64 && tid < 96){
    const int oo = tid - 64;
    float a = ws[OFF_QB + 64 + oo];
    #pragma unroll
    for (int c = 0; c < 32; ++c)
      a = fmaf(fminf(fmaxf(vB[c], 0.0f), QMAXF), ws[OFF_QW + 2048 + oo*32 + c], a);
    vA[oo] = a;
  }
  __syncthreads();

  if (tid < 3){
    float a = ws[OFF_QB4 + tid];
    #pragma unroll
    for (int c = 0; c < 32; ++c)
      a = fmaf(fminf(fmaxf(vA[c], 0.0f), QMAXF), ws[OFF_QW4 + tid*32 + c], a);
    const int idx = b*3 + tid;
    if (bfl) ((__hip_bfloat16*)outv)[idx] = __float2bfloat16(a);
    else     ((float*)outv)[idx] = a;
  }
}

extern "C" void kernel_launch(void* const* d_in, const int* in_sizes, int n_in,
                              void* d_out, int out_size, void* d_ws, size_t ws_size,
                              hipStream_t stream)
{
  (void)in_sizes; (void)n_in; (void)out_size; (void)ws_size;
  float* ws = (float*)d_ws;
  prep_kernel<<<128, 256, 0, stream>>>(
      d_in[0],  d_in[1],  d_in[2],  d_in[3],  d_in[4],  d_in[5],  d_in[6],  d_in[7],
      d_in[8],  d_in[9],  d_in[10], d_in[11], d_in[12], d_in[13], d_in[14], d_in[15],
      d_in[16], d_in[17], d_in[18], d_in[19], d_in[20], d_in[21], ws);
  fused_kernel<<<16384, 256, 0, stream>>>(d_in[0], ws, d_out);
}

// Round 2
// 896.875 us; speedup vs baseline: 3.2393x; 3.2393x over previous
//
#include <hip/hip_runtime.h>
#include <hip/hip_bf16.h>

typedef _Float16 f16;
typedef f16 f16x8 __attribute__((ext_vector_type(8)));
typedef float f32x4 __attribute__((ext_vector_type(4)));

#define QMAXF (127.0f/128.0f)
#define LO_SCALE 2048.0f
#define LO_INV  (1.0f/2048.0f)

// float-slot offsets: f16 weight region occupies slots [0,153600); scalars after.
enum {
  OFF_W1 = 153600, OFF_B1 = 154368, OFF_CB = 154496, OFF_LB = 154880,
  OFF_FB = 155136, OFF_PW1 = 155184, OFF_PB1 = 155440, OFF_PW2 = 155456,
  OFF_PB2 = 155712, OFF_PQ = 155728, OFF_QW = 156512, OFF_QB = 159584,
  OFF_QW4 = 159680, OFF_QB4 = 159776, WS_TOTAL = 159779
};
// f16-element offsets inside the weight region
enum {
  FW_CH = 0, FW_CL = 49152, FW_LH = 98304, FW_LL = 196608,
  FW_FH = 294912, FW_FL = 301056, FW_TOTAL = 307200
};

__device__ __forceinline__ bool detect_bf16(const void* x){
  const unsigned short* u = (const unsigned short*)x;
  int hits = 0;
  #pragma unroll
  for (int i = 0; i < 32; i += 2){
    unsigned short h = u[i];
    hits += (h >= 0x3800 && h <= 0x3F80) ? 1 : 0;
  }
  return hits >= 12;
}

__device__ __forceinline__ float rd(const void* p, int i, bool bfl){
  return bfl ? __bfloat162float(((const __hip_bfloat16*)p)[i]) : ((const float*)p)[i];
}

__device__ __forceinline__ float mish_f(float v){
  float e  = __expf(-fabsf(v));
  float sp = fmaxf(v, 0.0f) + __logf(1.0f + e);
  float q  = __expf(-2.0f * sp);
  float t  = (1.0f - q) / (1.0f + q);
  return v * t;
}

__global__ void prep_kernel(const void* x, const void* lw1, const void* lb1, const void* lw23,
                            const void* lb23, const void* cw, const void* cb, const void* cs,
                            const void* ct, const void* cwf, const void* cbf, const void* csf,
                            const void* ctf, const void* pw1, const void* pb1, const void* pw2,
                            const void* pb2, const void* pq, const void* vw, const void* vb,
                            const void* vw4, const void* vb4, float* ws)
{
  const bool bfl = detect_bf16(x);
  f16* wf = (f16*)ws;
  const int t0 = blockIdx.x*blockDim.x + threadIdx.x;
  const int stride = gridDim.x*blockDim.x;

  // ---- f16 fragment-packed weights (hi and scaled-lo parts) ----
  for (int e = t0; e < FW_TOTAL; e += stride){
    float w; bool lo = false;
    if (e < 98304){                                   // conv1x1 layers (cw*cs)
      int ee = e; if (ee >= 49152){ lo = true; ee -= 49152; }
      int l = ee >> 14, r = ee & 16383;
      int kseg = r >> 10, col = (r >> 3) & 127, j = r & 7, k = kseg*8 + j;
      w = rd(cw, (l*128 + col)*128 + k, bfl) * rd(cs, l*128 + col, bfl);
    } else if (e < 294912){                           // ladder taps lw23
      int ee = e - 98304; if (ee >= 98304){ lo = true; ee -= 98304; }
      int lt = ee >> 14, r = ee & 16383;
      int kseg = r >> 10, col = (r >> 3) & 127, j = r & 7, k = kseg*8 + j;
      w = rd(lw23, lt*16384 + col*128 + k, bfl);
    } else {                                          // final 128->48 (cwf*csf)
      int ee = e - 294912; if (ee >= 6144){ lo = true; ee -= 6144; }
      int kseg = ee / 384, r = ee % 384, col = r >> 3, j = r & 7, k = kseg*8 + j;
      w = rd(cwf, col*128 + k, bfl) * rd(csf, col, bfl);
    }
    f16 hi = (f16)w;
    wf[e] = lo ? (f16)((w - (float)hi) * LO_SCALE) : hi;
  }

  // ---- fp32 scalar region ----
  for (int i = t0; i < 6179; i += stride){
    float v; int s = i;
    if (s < 768){ int tap = s>>8, r = s&255, c = r>>7, o = r&127; v = rd(lw1,(tap*128+o)*2+c,bfl); }
    else if (s < 896){ v = rd(lb1, s-768, bfl); }
    else if (s < 1280){ int idx = s-896; v = rd(cb,idx,bfl)*rd(cs,idx,bfl)+rd(ct,idx,bfl); }
    else if (s < 1536){ v = rd(lb23, s-1280, bfl); }
    else if (s < 1584){ int m = s-1536; v = rd(cbf,m,bfl)*rd(csf,m,bfl)+rd(ctf,m,bfl); }
    else if (s < 1840){ v = rd(pw1, s-1584, bfl); }
    else if (s < 1856){ v = rd(pb1, s-1840, bfl); }
    else if (s < 2112){ v = rd(pw2, s-1856, bfl); }
    else if (s < 2128){ v = rd(pb2, s-2112, bfl); }
    else if (s < 2912){ v = rd(pq, s-2128, bfl); }
    else if (s < 5984){ float w = rd(vw, s-2912, bfl); w = fminf(fmaxf(w,-1.f),QMAXF); v = rintf(w*128.f)*0.0078125f; }
    else if (s < 6080){ v = rintf(rd(vb, s-5984, bfl)*16384.f)*6.103515625e-05f; }
    else if (s < 6176){ float w = rd(vw4, s-6080, bfl); w = fminf(fmaxf(w,-1.f),QMAXF); v = rintf(w*128.f)*0.0078125f; }
    else { v = rintf(rd(vb4, s-6176, bfl)*16384.f)*6.103515625e-05f; }
    ws[153600 + i] = v;
  }
}

// row mapping: 0 = identity(1x1), 1 = ladder 3x3->2x2, 2 = ladder 2x2->1
template<int LMAP, int MSRC>
__device__ __forceinline__ int map_row(int ro, int tap){
  if (LMAP == 0){ return ro < MSRC ? ro : MSRC-1; }
  if (LMAP == 1){
    int g = ro >> 2, p = ro & 3;
    int base = g*9 + (p>>1)*3 + (p&1);
    return base + (tap==0 ? 0 : (tap==1 ? 3 : 4));
  }
  int g = ro > 7 ? 7 : ro;
  return g*4 + (tap==0 ? 0 : (tap==1 ? 2 : 3));
}

// store value as hi + scaled-lo into activation buffer [32 kseg][MDST][8] f16
template<int MDST>
__device__ __forceinline__ void store_hl(f16* buf, int row, int col, float v){
  f16 hi = (f16)v;
  f16 lo = (f16)((v - (float)hi) * LO_SCALE);
  int base = ((col>>3)*MDST + row)*8 + (col&7);
  buf[base] = hi;
  buf[16*MDST*8 + base] = lo;
}

template<int MTILES, int MSRC, int MDST, int TAPS, int LMAP>
__device__ __forceinline__ void mfma_layer(const f16* __restrict__ wf, int whbase, int wlbase,
                                           const float* __restrict__ ws, int boff,
                                           const f16* src, f16* dst, int lane, int wv)
{
  const int lr = lane & 15;
  const int lk = lane >> 4;
  const int c0 = wv*32 + lr;          // cols: c0 + nt*16

  f32x4 acc1[MTILES][2], acc2[MTILES][2];
  #pragma unroll
  for (int mt = 0; mt < MTILES; ++mt){
    #pragma unroll
    for (int nt = 0; nt < 2; ++nt){
      float bb = ws[boff + c0 + nt*16];
      acc1[mt][nt] = (f32x4){bb, bb, bb, bb};
      acc2[mt][nt] = (f32x4){0.f, 0.f, 0.f, 0.f};
    }
  }

  #pragma unroll
  for (int tap = 0; tap < TAPS; ++tap){
    int rowin[MTILES];
    #pragma unroll
    for (int mt = 0; mt < MTILES; ++mt)
      rowin[mt] = map_row<LMAP, MSRC>(mt*16 + lr, tap);

    const f16* wh = wf + whbase + tap*16384;
    const f16* wl = wf + wlbase + tap*16384;

    #pragma unroll
    for (int s = 0; s < 4; ++s){
      const int kseg = 4*s + lk;
      f16x8 ah[MTILES], bh[2];
      #pragma unroll
      for (int mt = 0; mt < MTILES; ++mt)
        ah[mt] = *(const f16x8*)(src + (kseg*MSRC + rowin[mt])*8);
      #pragma unroll
      for (int nt = 0; nt < 2; ++nt)
        bh[nt] = *(const f16x8*)(wh + (kseg*128 + c0 + nt*16)*8);
      #pragma unroll
      for (int mt = 0; mt < MTILES; ++mt)
        #pragma unroll
        for (int nt = 0; nt < 2; ++nt)
          acc1[mt][nt] = __builtin_amdgcn_mfma_f32_16x16x32_f16(ah[mt], bh[nt], acc1[mt][nt], 0, 0, 0);
      #pragma unroll
      for (int nt = 0; nt < 2; ++nt){
        f16x8 bl = *(const f16x8*)(wl + (kseg*128 + c0 + nt*16)*8);
        #pragma unroll
        for (int mt = 0; mt < MTILES; ++mt)
          acc2[mt][nt] = __builtin_amdgcn_mfma_f32_16x16x32_f16(ah[mt], bl, acc2[mt][nt], 0, 0, 0);
      }
      #pragma unroll
      for (int mt = 0; mt < MTILES; ++mt){
        f16x8 al = *(const f16x8*)(src + ((16 + kseg)*MSRC + rowin[mt])*8);
        #pragma unroll
        for (int nt = 0; nt < 2; ++nt)
          acc2[mt][nt] = __builtin_amdgcn_mfma_f32_16x16x32_f16(al, bh[nt], acc2[mt][nt], 0, 0, 0);
      }
    }
  }

  // epilogue: bias already in acc1; combine, mish, split hi/lo, store
  #pragma unroll
  for (int mt = 0; mt < MTILES; ++mt){
    #pragma unroll
    for (int nt = 0; nt < 2; ++nt){
      const int col = c0 + nt*16;
      #pragma unroll
      for (int r = 0; r < 4; ++r){
        const int row = mt*16 + lk*4 + r;
        if (row < MDST){
          float v = acc1[mt][nt][r] + acc2[mt][nt][r]*LO_INV;
          store_hl<MDST>(dst, row, col, mish_f(v));
        }
      }
    }
  }
}

__global__ __launch_bounds__(256, 2)
void fused_kernel(const void* __restrict__ xv, const float* __restrict__ ws, void* __restrict__ outv)
{
  __shared__ __align__(16) f16 bufA[18432];   // [32][72][8] worst case, 36.9 KB
  __shared__ __align__(16) f16 bufB[18432];
  __shared__ float xraw[98];
  __shared__ float xin[8][2][16];
  __shared__ float qbuf[8][48];
  __shared__ float featL[48];
  __shared__ float pkA[16], pkB[16];
  __shared__ float vA[32], vB[32];

  const int tid  = threadIdx.x;
  const int lane = tid & 63;
  const int wv   = tid >> 6;
  const int b    = blockIdx.x;
  const bool bfl = detect_bf16(xv);
  const f16* wf  = (const f16*)ws;

  if (tid < 98) xraw[tid] = rd(xv, b*98 + tid, bfl);
  __syncthreads();

  // 8 rotated 4x4 crops
  {
    const int g = tid >> 5, r = tid & 31, c = r >> 4, p = r & 15;
    const int ri = p >> 2, rj = p & 3;
    const int k  = (0x13023120u >> (g*4)) & 0xF;
    const int y0 = (g >= 4) ? 3 : 0;
    const int x0 = (g >= 2 && g <= 5) ? 3 : 0;
    int sy, sx;
    if      (k == 0){ sy = ri;     sx = rj;     }
    else if (k == 1){ sy = rj;     sx = 3 - ri; }
    else if (k == 2){ sy = 3 - ri; sx = 3 - rj; }
    else            { sy = 3 - rj; sx = ri;     }
    xin[g][c][p] = xraw[c*49 + (y0 + sy)*7 + (x0 + sx)];
  }
  __syncthreads();

  // L1 ladder (ci=2): 4x4 -> 3x3 + mish, VALU, write hi/lo into bufA (72 rows)
  {
    const int o = tid & 127, sgp = tid >> 7;
    float wt[3][2];
    #pragma unroll
    for (int tp = 0; tp < 3; ++tp){
      wt[tp][0] = ws[OFF_W1 + (tp*2 + 0)*128 + o];
      wt[tp][1] = ws[OFF_W1 + (tp*2 + 1)*128 + o];
    }
    const float bb = ws[OFF_B1 + o];
    #pragma unroll
    for (int gi = 0; gi < 4; ++gi){
      const int g = sgp + 2*gi;
      #pragma unroll
      for (int i = 0; i < 3; ++i)
      #pragma unroll
      for (int j = 0; j < 3; ++j){
        float a = bb;
        a = fmaf(wt[0][0], xin[g][0][i*4 + j],         a);
        a = fmaf(wt[0][1], xin[g][1][i*4 + j],         a);
        a = fmaf(wt[1][0], xin[g][0][(i+1)*4 + j],     a);
        a = fmaf(wt[1][1], xin[g][1][(i+1)*4 + j],     a);
        a = fmaf(wt[2][0], xin[g][0][(i+1)*4 + j + 1], a);
        a = fmaf(wt[2][1], xin[g][1][(i+1)*4 + j + 1], a);
        store_hl<72>(bufA, g*9 + i*3 + j, o, mish_f(a));
      }
    }
  }
  __syncthreads();

  mfma_layer<5,72,72,1,0>(wf, FW_CH,          FW_CL,          ws, OFF_CB,       bufA, bufB, lane, wv);
  __syncthreads();
  mfma_layer<2,72,32,3,1>(wf, FW_LH,          FW_LL,          ws, OFF_LB,       bufB, bufA, lane, wv);
  __syncthreads();
  mfma_layer<2,32,32,1,0>(wf, FW_CH + 16384,  FW_CL + 16384,  ws, OFF_CB + 128, bufA, bufB, lane, wv);
  __syncthreads();
  mfma_layer<1,32, 8,3,2>(wf, FW_LH + 49152,  FW_LL + 49152,  ws, OFF_LB + 128, bufB, bufA, lane, wv);
  __syncthreads();
  mfma_layer<1, 8, 8,1,0>(wf, FW_CH + 32768,  FW_CL + 32768,  ws, OFF_CB + 256, bufA, bufB, lane, wv);
  __syncthreads();

  // final 128 -> 48 (no act) + fake_quant into qbuf; waves 0..2, one 16-col tile each
  if (wv < 3){
    const int lr = lane & 15, lk = lane >> 4;
    const int col = wv*16 + lr;
    const int rowin = lr > 7 ? 7 : lr;
    const float bb = ws[OFF_FB + col];
    f32x4 a1 = (f32x4){bb, bb, bb, bb};
    f32x4 a2 = (f32x4){0.f, 0.f, 0.f, 0.f};
    f16x8 af[4];
    #pragma unroll
    for (int s = 0; s < 4; ++s){
      const int kseg = 4*s + lk;
      af[s] = *(const f16x8*)(bufB + (kseg*8 + rowin)*8);
      f16x8 bh = *(const f16x8*)(wf + FW_FH + (kseg*48 + col)*8);
      a1 = __builtin_amdgcn_mfma_f32_16x16x32_f16(af[s], bh, a1, 0, 0, 0);
      f16x8 bl = *(const f16x8*)(wf + FW_FL + (kseg*48 + col)*8);
      a2 = __builtin_amdgcn_mfma_f32_16x16x32_f16(af[s], bl, a2, 0, 0, 0);
      f16x8 al = *(const f16x8*)(bufB + ((16 + kseg)*8 + rowin)*8);
      a2 = __builtin_amdgcn_mfma_f32_16x16x32_f16(al, bh, a2, 0, 0, 0);
    }
    #pragma unroll
    for (int r = 0; r < 4; ++r){
      const int row = lk*4 + r;
      if (row < 8){
        float v = a1[r] + a2[r]*LO_INV;
        float h = fminf(fmaxf(v, -1.0f), QMAXF);
        qbuf[row][col] = rintf(h * 128.0f) * 0.0078125f;
      }
    }
  }
  __syncthreads();

  if (tid < 48){
    float f = 0.0f;
    #pragma unroll
    for (int g = 0; g < 8; ++g) f += qbuf[g][tid];
    featL[tid] = f;
  }
  __syncthreads();

  // heads (fp32 VALU, exact integer-grid value head)
  if (tid < 16){
    float a = ws[OFF_PB1 + tid];
    #pragma unroll
    for (int c = 0; c < 16; ++c) a = fmaf(featL[c], ws[OFF_PW1 + tid*16 + c], a);
    pkA[tid] = fmaxf(a, 0.0f);
  } else if (tid >= 64 && tid < 96){
    const int oo = tid - 64;
    float a = ws[OFF_QB + oo];
    #pragma unroll
    for (int c = 0; c < 32; ++c)
      a = fmaf(fminf(fmaxf(featL[16 + c], 0.0f), QMAXF), ws[OFF_QW + oo*32 + c], a);
    vA[oo] = a;
  }
  __syncthreads();

  if (tid < 16){
    float a = ws[OFF_PB2 + tid];
    #pragma unroll
    for (int c = 0; c < 16; ++c) a = fmaf(pkA[c], ws[OFF_PW2 + tid*16 + c], a);
    pkB[tid] = a;
  } else if (tid >= 64 && tid < 96){
    const int oo = tid - 64;
    float a = ws[OFF_QB + 32 + oo];
    #pragma unroll
    for (int c = 0; c < 32; ++c)
      a = fmaf(fminf(fmaxf(vA[c], 0.0f), QMAXF), ws[OFF_QW + 1024 + oo*32 + c], a);
    vB[oo] = a;
  }
  __syncthreads();

  if (tid < 49){
    float a = 0.0f;
    #pragma unroll
    for (int c = 0; c < 16; ++c) a = fmaf(pkB[c], ws[OFF_PQ + tid*16 + c], a);
    const int idx = 49152 + b*49 + tid;
    if (bfl) ((__hip_bfloat16*)outv)[idx] = __float2bfloat16(a);
    else     ((float*)outv)[idx] = a;
  } else if (tid >= 64 && tid < 96){
    const int oo = tid - 64;
    float a = ws[OFF_QB + 64 + oo];
    #pragma unroll
    for (int c = 0; c < 32; ++c)
      a = fmaf(fminf(fmaxf(vB[c], 0.0f), QMAXF), ws[OFF_QW + 2048 + oo*32 + c], a);
    vA[oo] = a;
  }
  __syncthreads();

  if (tid < 3){
    float a = ws[OFF_QB4 + tid];
    #pragma unroll
    for (int c = 0; c < 32; ++c)
      a = fmaf(fminf(fmaxf(vA[c], 0.0f), QMAXF), ws[OFF_QW4 + tid*32 + c], a);
    const int idx = b*3 + tid;
    if (bfl) ((__hip_bfloat16*)outv)[idx] = __float2bfloat16(a);
    else     ((float*)outv)[idx] = a;
  }
}

extern "C" void kernel_launch(void* const* d_in, const int* in_sizes, int n_in,
                              void* d_out, int out_size, void* d_ws, size_t ws_size,
                              hipStream_t stream)
{
  (void)in_sizes; (void)n_in; (void)out_size; (void)ws_size;
  float* ws = (float*)d_ws;
  prep_kernel<<<256, 256, 0, stream>>>(
      d_in[0],  d_in[1],  d_in[2],  d_in[3],  d_in[4],  d_in[5],  d_in[6],  d_in[7],
      d_in[8],  d_in[9],  d_in[10], d_in[11], d_in[12], d_in[13], d_in[14], d_in[15],
      d_in[16], d_in[17], d_in[18], d_in[19], d_in[20], d_in[21], ws);
  fused_kernel<<<16384, 256, 0, stream>>>(d_in[0], ws, d_out);
}

// Round 4
// 681.396 us; speedup vs baseline: 4.2636x; 1.3162x over previous
//
#include <hip/hip_runtime.h>
#include <hip/hip_bf16.h>

typedef _Float16 f16;
typedef f16 f16x8 __attribute__((ext_vector_type(8)));
typedef float f32x4 __attribute__((ext_vector_type(4)));

#define QMAXF (127.0f/128.0f)
#define LO_SCALE 2048.0f
#define LO_INV  (1.0f/2048.0f)

// float-slot offsets: f16 weight region occupies slots [0,153600); scalars after.
enum {
  OFF_W1 = 153600, OFF_B1 = 154368, OFF_CB = 154496, OFF_LB = 154880,
  OFF_FB = 155136, OFF_PW1 = 155184, OFF_PB1 = 155440, OFF_PW2 = 155456,
  OFF_PB2 = 155712, OFF_PQ = 155728, OFF_QW = 156512, OFF_QB = 159584,
  OFF_QW4 = 159680, OFF_QB4 = 159776, WS_TOTAL = 159779
};
// f16-element offsets inside the weight region
enum {
  FW_CH = 0, FW_CL = 49152, FW_LH = 98304, FW_LL = 196608,
  FW_FH = 294912, FW_FL = 301056, FW_TOTAL = 307200
};

__device__ __forceinline__ bool detect_bf16(const void* x){
  const unsigned short* u = (const unsigned short*)x;
  int hits = 0;
  #pragma unroll
  for (int i = 0; i < 32; i += 2){
    unsigned short h = u[i];
    hits += (h >= 0x3800 && h <= 0x3F80) ? 1 : 0;
  }
  return hits >= 12;
}

__device__ __forceinline__ float rd(const void* p, int i, bool bfl){
  return bfl ? __bfloat162float(((const __hip_bfloat16*)p)[i]) : ((const float*)p)[i];
}

// mish(x) = x * tanh(softplus(x)) = x * n/(n+2),  n = u*(u+2), u = exp(x).
// 1 transcendental + 1 approx-rcp instead of 3 transcendentals + IEEE divide.
__device__ __forceinline__ float mish_f(float x){
  float u = __expf(fminf(x, 30.0f));
  float n = u * (u + 2.0f);
  return x * n * __builtin_amdgcn_rcpf(n + 2.0f);
}

__global__ void prep_kernel(const void* x, const void* lw1, const void* lb1, const void* lw23,
                            const void* lb23, const void* cw, const void* cb, const void* cs,
                            const void* ct, const void* cwf, const void* cbf, const void* csf,
                            const void* ctf, const void* pw1, const void* pb1, const void* pw2,
                            const void* pb2, const void* pq, const void* vw, const void* vb,
                            const void* vw4, const void* vb4, float* ws)
{
  const bool bfl = detect_bf16(x);
  f16* wf = (f16*)ws;
  const int t0 = blockIdx.x*blockDim.x + threadIdx.x;
  const int stride = gridDim.x*blockDim.x;

  // ---- f16 fragment-packed weights (hi and scaled-lo parts) ----
  for (int e = t0; e < FW_TOTAL; e += stride){
    float w; bool lo = false;
    if (e < 98304){                                   // conv1x1 layers (cw*cs)
      int ee = e; if (ee >= 49152){ lo = true; ee -= 49152; }
      int l = ee >> 14, r = ee & 16383;
      int kseg = r >> 10, col = (r >> 3) & 127, j = r & 7, k = kseg*8 + j;
      w = rd(cw, (l*128 + col)*128 + k, bfl) * rd(cs, l*128 + col, bfl);
    } else if (e < 294912){                           // ladder taps lw23
      int ee = e - 98304; if (ee >= 98304){ lo = true; ee -= 98304; }
      int lt = ee >> 14, r = ee & 16383;
      int kseg = r >> 10, col = (r >> 3) & 127, j = r & 7, k = kseg*8 + j;
      w = rd(lw23, lt*16384 + col*128 + k, bfl);
    } else {                                          // final 128->48 (cwf*csf)
      int ee = e - 294912; if (ee >= 6144){ lo = true; ee -= 6144; }
      int kseg = ee / 384, r = ee % 384, col = r >> 3, j = r & 7, k = kseg*8 + j;
      w = rd(cwf, col*128 + k, bfl) * rd(csf, col, bfl);
    }
    f16 hi = (f16)w;
    wf[e] = lo ? (f16)((w - (float)hi) * LO_SCALE) : hi;
  }

  // ---- fp32 scalar region ----
  for (int i = t0; i < 6179; i += stride){
    float v; int s = i;
    if (s < 768){ int tap = s>>8, r = s&255, c = r>>7, o = r&127; v = rd(lw1,(tap*128+o)*2+c,bfl); }
    else if (s < 896){ v = rd(lb1, s-768, bfl); }
    else if (s < 1280){ int idx = s-896; v = rd(cb,idx,bfl)*rd(cs,idx,bfl)+rd(ct,idx,bfl); }
    else if (s < 1536){ v = rd(lb23, s-1280, bfl); }
    else if (s < 1584){ int m = s-1536; v = rd(cbf,m,bfl)*rd(csf,m,bfl)+rd(ctf,m,bfl); }
    else if (s < 1840){ v = rd(pw1, s-1584, bfl); }
    else if (s < 1856){ v = rd(pb1, s-1840, bfl); }
    else if (s < 2112){ v = rd(pw2, s-1856, bfl); }
    else if (s < 2128){ v = rd(pb2, s-2112, bfl); }
    else if (s < 2912){ v = rd(pq, s-2128, bfl); }
    else if (s < 5984){ float w = rd(vw, s-2912, bfl); w = fminf(fmaxf(w,-1.f),QMAXF); v = rintf(w*128.f)*0.0078125f; }
    else if (s < 6080){ v = rintf(rd(vb, s-5984, bfl)*16384.f)*6.103515625e-05f; }
    else if (s < 6176){ float w = rd(vw4, s-6080, bfl); w = fminf(fmaxf(w,-1.f),QMAXF); v = rintf(w*128.f)*0.0078125f; }
    else { v = rintf(rd(vb4, s-6176, bfl)*16384.f)*6.103515625e-05f; }
    ws[153600 + i] = v;
  }
}

// row mapping: 0 = identity(1x1), 1 = ladder 3x3->2x2, 2 = ladder 2x2->1
template<int LMAP, int MSRC>
__device__ __forceinline__ int map_row(int ro, int tap){
  if (LMAP == 0){ return ro < MSRC ? ro : MSRC-1; }
  if (LMAP == 1){
    int g = ro >> 2, p = ro & 3;
    int base = g*9 + (p>>1)*3 + (p&1);
    return base + (tap==0 ? 0 : (tap==1 ? 3 : 4));
  }
  int g = ro > 7 ? 7 : ro;
  return g*4 + (tap==0 ? 0 : (tap==1 ? 2 : 3));
}

// Activation buffer layout: [32 kseg-planes][M+2 rows][8 f16].
// Plane stride M+2 is EVEN, so group index q = plane*(M+2)+row has
// parity(q) == parity(row); the XOR e^=(row&8) then swaps rows 8<->9,
// 10<->11, ... within the same plane — a bijective, 16B-aligned involution
// applied identically on store and load (rule 21). It spreads the
// epilogue's lk-strided 2B stores from banks {0,16,0,16} to {0,16,4,20}.
template<int M>
__device__ __forceinline__ int aidx(int plane, int row, int c7){
  int e = (plane*(M+2) + row)*8 + c7;
  return e ^ (row & 8);
}

template<int MDST>
__device__ __forceinline__ void store_hl(f16* buf, int row, int col, float v){
  f16 hi = (f16)v;
  f16 lo = (f16)((v - (float)hi) * LO_SCALE);
  int base = aidx<MDST>(col >> 3, row, col & 7);
  buf[base] = hi;
  buf[16*(MDST+2)*8 + base] = lo;
}

template<int MTILES, int MSRC, int MDST, int TAPS, int LMAP>
__device__ __forceinline__ void mfma_layer(const f16* __restrict__ wf, int whbase, int wlbase,
                                           const float* __restrict__ ws, int boff,
                                           const f16* src, f16* dst, int lane, int wv)
{
  const int lr = lane & 15;
  const int lk = lane >> 4;
  const int c0 = wv*32 + lr;          // cols: c0 + nt*16

  f32x4 acc1[MTILES][2], acc2[MTILES][2];
  #pragma unroll
  for (int mt = 0; mt < MTILES; ++mt){
    #pragma unroll
    for (int nt = 0; nt < 2; ++nt){
      float bb = ws[boff + c0 + nt*16];
      acc1[mt][nt] = (f32x4){bb, bb, bb, bb};
      acc2[mt][nt] = (f32x4){0.f, 0.f, 0.f, 0.f};
    }
  }

  #pragma unroll
  for (int tap = 0; tap < TAPS; ++tap){
    int rowin[MTILES];
    #pragma unroll
    for (int mt = 0; mt < MTILES; ++mt)
      rowin[mt] = map_row<LMAP, MSRC>(mt*16 + lr, tap);

    const f16* wh = wf + whbase + tap*16384;
    const f16* wl = wf + wlbase + tap*16384;

    #pragma unroll
    for (int s = 0; s < 4; ++s){
      const int kseg = 4*s + lk;
      f16x8 ah[MTILES], bh[2];
      #pragma unroll
      for (int mt = 0; mt < MTILES; ++mt)
        ah[mt] = *(const f16x8*)(src + aidx<MSRC>(kseg, rowin[mt], 0));
      #pragma unroll
      for (int nt = 0; nt < 2; ++nt)
        bh[nt] = *(const f16x8*)(wh + (kseg*128 + c0 + nt*16)*8);
      #pragma unroll
      for (int mt = 0; mt < MTILES; ++mt)
        #pragma unroll
        for (int nt = 0; nt < 2; ++nt)
          acc1[mt][nt] = __builtin_amdgcn_mfma_f32_16x16x32_f16(ah[mt], bh[nt], acc1[mt][nt], 0, 0, 0);
      #pragma unroll
      for (int nt = 0; nt < 2; ++nt){
        f16x8 bl = *(const f16x8*)(wl + (kseg*128 + c0 + nt*16)*8);
        #pragma unroll
        for (int mt = 0; mt < MTILES; ++mt)
          acc2[mt][nt] = __builtin_amdgcn_mfma_f32_16x16x32_f16(ah[mt], bl, acc2[mt][nt], 0, 0, 0);
      }
      #pragma unroll
      for (int mt = 0; mt < MTILES; ++mt){
        f16x8 al = *(const f16x8*)(src + aidx<MSRC>(16 + kseg, rowin[mt], 0));
        #pragma unroll
        for (int nt = 0; nt < 2; ++nt)
          acc2[mt][nt] = __builtin_amdgcn_mfma_f32_16x16x32_f16(al, bh[nt], acc2[mt][nt], 0, 0, 0);
      }
    }
  }

  // epilogue: bias already in acc1; combine, mish, split hi/lo, store
  #pragma unroll
  for (int mt = 0; mt < MTILES; ++mt){
    #pragma unroll
    for (int nt = 0; nt < 2; ++nt){
      const int col = c0 + nt*16;
      #pragma unroll
      for (int r = 0; r < 4; ++r){
        const int row = mt*16 + lk*4 + r;
        if (row < MDST){
          float v = fmaf(acc2[mt][nt][r], LO_INV, acc1[mt][nt][r]);
          store_hl<MDST>(dst, row, col, mish_f(v));
        }
      }
    }
  }
}

__global__ __launch_bounds__(256, 2)
void fused_kernel(const void* __restrict__ xv, const float* __restrict__ ws, void* __restrict__ outv)
{
  __shared__ __align__(16) f16 bufA[18944];   // [32][74][8] worst case, 37.9 KB
  __shared__ __align__(16) f16 bufB[18944];
  __shared__ float xraw[98];
  __shared__ float xin[8][2][16];
  __shared__ float qbuf[8][48];
  __shared__ float featL[48];
  __shared__ float pkA[16], pkB[16];
  __shared__ float vA[32], vB[32];

  const int tid  = threadIdx.x;
  const int lane = tid & 63;
  const int wv   = tid >> 6;
  const int b    = blockIdx.x;
  const bool bfl = detect_bf16(xv);
  const f16* wf  = (const f16*)ws;

  if (tid < 98) xraw[tid] = rd(xv, b*98 + tid, bfl);
  __syncthreads();

  // 8 rotated 4x4 crops
  {
    const int g = tid >> 5, r = tid & 31, c = r >> 4, p = r & 15;
    const int ri = p >> 2, rj = p & 3;
    const int k  = (0x13023120u >> (g*4)) & 0xF;
    const int y0 = (g >= 4) ? 3 : 0;
    const int x0 = (g >= 2 && g <= 5) ? 3 : 0;
    int sy, sx;
    if      (k == 0){ sy = ri;     sx = rj;     }
    else if (k == 1){ sy = rj;     sx = 3 - ri; }
    else if (k == 2){ sy = 3 - ri; sx = 3 - rj; }
    else            { sy = 3 - rj; sx = ri;     }
    xin[g][c][p] = xraw[c*49 + (y0 + sy)*7 + (x0 + sx)];
  }
  __syncthreads();

  // L1 ladder (ci=2): 4x4 -> 3x3 + mish, VALU, write hi/lo into bufA (72 rows)
  {
    const int o = tid & 127, sgp = tid >> 7;
    float wt[3][2];
    #pragma unroll
    for (int tp = 0; tp < 3; ++tp){
      wt[tp][0] = ws[OFF_W1 + (tp*2 + 0)*128 + o];
      wt[tp][1] = ws[OFF_W1 + (tp*2 + 1)*128 + o];
    }
    const float bb = ws[OFF_B1 + o];
    #pragma unroll
    for (int gi = 0; gi < 4; ++gi){
      const int g = sgp + 2*gi;
      #pragma unroll
      for (int i = 0; i < 3; ++i)
      #pragma unroll
      for (int j = 0; j < 3; ++j){
        float a = bb;
        a = fmaf(wt[0][0], xin[g][0][i*4 + j],         a);
        a = fmaf(wt[0][1], xin[g][1][i*4 + j],         a);
        a = fmaf(wt[1][0], xin[g][0][(i+1)*4 + j],     a);
        a = fmaf(wt[1][1], xin[g][1][(i+1)*4 + j],     a);
        a = fmaf(wt[2][0], xin[g][0][(i+1)*4 + j + 1], a);
        a = fmaf(wt[2][1], xin[g][1][(i+1)*4 + j + 1], a);
        store_hl<72>(bufA, g*9 + i*3 + j, o, mish_f(a));
      }
    }
  }
  __syncthreads();

  mfma_layer<5,72,72,1,0>(wf, FW_CH,          FW_CL,          ws, OFF_CB,       bufA, bufB, lane, wv);
  __syncthreads();
  mfma_layer<2,72,32,3,1>(wf, FW_LH,          FW_LL,          ws, OFF_LB,       bufB, bufA, lane, wv);
  __syncthreads();
  mfma_layer<2,32,32,1,0>(wf, FW_CH + 16384,  FW_CL + 16384,  ws, OFF_CB + 128, bufA, bufB, lane, wv);
  __syncthreads();
  mfma_layer<1,32, 8,3,2>(wf, FW_LH + 49152,  FW_LL + 49152,  ws, OFF_LB + 128, bufB, bufA, lane, wv);
  __syncthreads();
  mfma_layer<1, 8, 8,1,0>(wf, FW_CH + 32768,  FW_CL + 32768,  ws, OFF_CB + 256, bufA, bufB, lane, wv);
  __syncthreads();

  // final 128 -> 48 (no act) + fake_quant into qbuf; waves 0..2, one 16-col tile each
  if (wv < 3){
    const int lr = lane & 15, lk = lane >> 4;
    const int col = wv*16 + lr;
    const int rowin = lr > 7 ? 7 : lr;
    const float bb = ws[OFF_FB + col];
    f32x4 a1 = (f32x4){bb, bb, bb, bb};
    f32x4 a2 = (f32x4){0.f, 0.f, 0.f, 0.f};
    #pragma unroll
    for (int s = 0; s < 4; ++s){
      const int kseg = 4*s + lk;
      f16x8 af = *(const f16x8*)(bufB + aidx<8>(kseg, rowin, 0));
      f16x8 bh = *(const f16x8*)(wf + FW_FH + (kseg*48 + col)*8);
      a1 = __builtin_amdgcn_mfma_f32_16x16x32_f16(af, bh, a1, 0, 0, 0);
      f16x8 bl = *(const f16x8*)(wf + FW_FL + (kseg*48 + col)*8);
      a2 = __builtin_amdgcn_mfma_f32_16x16x32_f16(af, bl, a2, 0, 0, 0);
      f16x8 al = *(const f16x8*)(bufB + aidx<8>(16 + kseg, rowin, 0));
      a2 = __builtin_amdgcn_mfma_f32_16x16x32_f16(al, bh, a2, 0, 0, 0);
    }
    #pragma unroll
    for (int r = 0; r < 4; ++r){
      const int row = lk*4 + r;
      if (row < 8){
        float v = fmaf(a2[r], LO_INV, a1[r]);
        float h = fminf(fmaxf(v, -1.0f), QMAXF);
        qbuf[row][col] = rintf(h * 128.0f) * 0.0078125f;
      }
    }
  }
  __syncthreads();

  if (tid < 48){
    float f = 0.0f;
    #pragma unroll
    for (int g = 0; g < 8; ++g) f += qbuf[g][tid];
    featL[tid] = f;
  }
  __syncthreads();

  // heads (fp32 VALU, exact integer-grid value head)
  if (tid < 16){
    float a = ws[OFF_PB1 + tid];
    #pragma unroll
    for (int c = 0; c < 16; ++c) a = fmaf(featL[c], ws[OFF_PW1 + tid*16 + c], a);
    pkA[tid] = fmaxf(a, 0.0f);
  } else if (tid >= 64 && tid < 96){
    const int oo = tid - 64;
    float a = ws[OFF_QB + oo];
    #pragma unroll
    for (int c = 0; c < 32; ++c)
      a = fmaf(fminf(fmaxf(featL[16 + c], 0.0f), QMAXF), ws[OFF_QW + oo*32 + c], a);
    vA[oo] = a;
  }
  __syncthreads();

  if (tid < 16){
    float a = ws[OFF_PB2 + tid];
    #pragma unroll
    for (int c = 0; c < 16; ++c) a = fmaf(pkA[c], ws[OFF_PW2 + tid*16 + c], a);
    pkB[tid] = a;
  } else if (tid >= 64 && tid < 96){
    const int oo = tid - 64;
    float a = ws[OFF_QB + 32 + oo];
    #pragma unroll
    for (int c = 0; c < 32; ++c)
      a = fmaf(fminf(fmaxf(vA[c], 0.0f), QMAXF), ws[OFF_QW + 1024 + oo*32 + c], a);
    vB[oo] = a;
  }
  __syncthreads();

  if (tid < 49){
    float a = 0.0f;
    #pragma unroll
    for (int c = 0; c < 16; ++c) a = fmaf(pkB[c], ws[OFF_PQ + tid*16 + c], a);
    const int idx = 49152 + b*49 + tid;
    if (bfl) ((__hip_bfloat16*)outv)[idx] = __float2bfloat16(a);
    else     ((float*)outv)[idx] = a;
  } else if (tid >= 64 && tid < 96){
    const int oo = tid - 64;
    float a = ws[OFF_QB + 64 + oo];
    #pragma unroll
    for (int c = 0; c < 32; ++c)
      a = fmaf(fminf(fmaxf(vB[c], 0.0f), QMAXF), ws[OFF_QW + 2048 + oo*32 + c], a);
    vA[oo] = a;
  }
  __syncthreads();

  if (tid < 3){
    float a = ws[OFF_QB4 + tid];
    #pragma unroll
    for (int c = 0; c < 32; ++c)
      a = fmaf(fminf(fmaxf(vA[c], 0.0f), QMAXF), ws[OFF_QW4 + tid*32 + c], a);
    const int idx = b*3 + tid;
    if (bfl) ((__hip_bfloat16*)outv)[idx] = __float2bfloat16(a);
    else     ((float*)outv)[idx] = a;
  }
}

extern "C" void kernel_launch(void* const* d_in, const int* in_sizes, int n_in,
                              void* d_out, int out_size, void* d_ws, size_t ws_size,
                              hipStream_t stream)
{
  (void)in_sizes; (void)n_in; (void)out_size; (void)ws_size;
  float* ws = (float*)d_ws;
  prep_kernel<<<256, 256, 0, stream>>>(
      d_in[0],  d_in[1],  d_in[2],  d_in[3],  d_in[4],  d_in[5],  d_in[6],  d_in[7],
      d_in[8],  d_in[9],  d_in[10], d_in[11], d_in[12], d_in[13], d_in[14], d_in[15],
      d_in[16], d_in[17], d_in[18], d_in[19], d_in[20], d_in[21], ws);
  fused_kernel<<<16384, 256, 0, stream>>>(d_in[0], ws, d_out);
}

// Round 5
// 356.900 us; speedup vs baseline: 8.1401x; 1.9092x over previous
//
#include <hip/hip_runtime.h>
#include <hip/hip_bf16.h>

typedef _Float16 f16;
typedef f16 f16x8 __attribute__((ext_vector_type(8)));
typedef float f32x4 __attribute__((ext_vector_type(4)));

#define QMAXF (127.0f/128.0f)

// float-slot offsets for fp32 scalar region (kept identical to round 4).
enum {
  OFF_W1 = 153600, OFF_B1 = 154368, OFF_CB = 154496, OFF_LB = 154880,
  OFF_FB = 155136, OFF_PW1 = 155184, OFF_PB1 = 155440, OFF_PW2 = 155456,
  OFF_PB2 = 155712, OFF_PQ = 155728, OFF_QW = 156512, OFF_QB = 159584,
  OFF_QW4 = 159680, OFF_QB4 = 159776, WS_TOTAL = 159779
};
// f16-element offsets inside the weight region (hi-only now).
enum {
  GW_C = 0,            // 3 conv1x1 layers x [16 kseg][128 col][8] = 3*16384
  GW_L = 49152,        // 6 ladder tap-mats x 16384
  GW_F = 147456,       // final 128->48: [16 kseg][48 col][8]
  GW_TOTAL = 153600
};

__device__ __forceinline__ bool detect_bf16(const void* x){
  const unsigned short* u = (const unsigned short*)x;
  int hits = 0;
  #pragma unroll
  for (int i = 0; i < 32; i += 2){
    unsigned short h = u[i];
    hits += (h >= 0x3800 && h <= 0x3F80) ? 1 : 0;
  }
  return hits >= 12;
}

__device__ __forceinline__ float rd(const void* p, int i, bool bfl){
  return bfl ? __bfloat162float(((const __hip_bfloat16*)p)[i]) : ((const float*)p)[i];
}

// mish(x) = x * n/(n+2),  n = u*(u+2), u = exp(x)  — algebraically exact.
__device__ __forceinline__ float mish_f(float x){
  float u = __expf(fminf(x, 30.0f));
  float n = u * (u + 2.0f);
  return x * n * __builtin_amdgcn_rcpf(n + 2.0f);
}

__global__ void prep_kernel(const void* x, const void* lw1, const void* lb1, const void* lw23,
                            const void* lb23, const void* cw, const void* cb, const void* cs,
                            const void* ct, const void* cwf, const void* cbf, const void* csf,
                            const void* ctf, const void* pw1, const void* pb1, const void* pw2,
                            const void* pb2, const void* pq, const void* vw, const void* vb,
                            const void* vw4, const void* vb4, float* ws)
{
  const bool bfl = detect_bf16(x);
  f16* wf = (f16*)ws;
  const int t0 = blockIdx.x*blockDim.x + threadIdx.x;
  const int stride = gridDim.x*blockDim.x;

  // ---- f16 fragment-packed weights (single hi part) ----
  for (int e = t0; e < GW_TOTAL; e += stride){
    float w;
    if (e < GW_L){                                    // conv1x1 layers (cw*cs)
      int l = e >> 14, r = e & 16383;
      int kseg = r >> 10, col = (r >> 3) & 127, j = r & 7, k = kseg*8 + j;
      w = rd(cw, (l*128 + col)*128 + k, bfl) * rd(cs, l*128 + col, bfl);
    } else if (e < GW_F){                             // ladder taps lw23
      int ee = e - GW_L;
      int lt = ee >> 14, r = ee & 16383;
      int kseg = r >> 10, col = (r >> 3) & 127, j = r & 7, k = kseg*8 + j;
      w = rd(lw23, lt*16384 + col*128 + k, bfl);
    } else {                                          // final 128->48 (cwf*csf)
      int ee = e - GW_F;
      int kseg = ee / 384, r = ee % 384, col = r >> 3, j = r & 7, k = kseg*8 + j;
      w = rd(cwf, col*128 + k, bfl) * rd(csf, col, bfl);
    }
    wf[e] = (f16)w;
  }

  // ---- fp32 scalar region (unchanged) ----
  for (int i = t0; i < 6179; i += stride){
    float v; int s = i;
    if (s < 768){ int tap = s>>8, r = s&255, c = r>>7, o = r&127; v = rd(lw1,(tap*128+o)*2+c,bfl); }
    else if (s < 896){ v = rd(lb1, s-768, bfl); }
    else if (s < 1280){ int idx = s-896; v = rd(cb,idx,bfl)*rd(cs,idx,bfl)+rd(ct,idx,bfl); }
    else if (s < 1536){ v = rd(lb23, s-1280, bfl); }
    else if (s < 1584){ int m = s-1536; v = rd(cbf,m,bfl)*rd(csf,m,bfl)+rd(ctf,m,bfl); }
    else if (s < 1840){ v = rd(pw1, s-1584, bfl); }
    else if (s < 1856){ v = rd(pb1, s-1840, bfl); }
    else if (s < 2112){ v = rd(pw2, s-1856, bfl); }
    else if (s < 2128){ v = rd(pb2, s-2112, bfl); }
    else if (s < 2912){ v = rd(pq, s-2128, bfl); }
    else if (s < 5984){ float w = rd(vw, s-2912, bfl); w = fminf(fmaxf(w,-1.f),QMAXF); v = rintf(w*128.f)*0.0078125f; }
    else if (s < 6080){ v = rintf(rd(vb, s-5984, bfl)*16384.f)*6.103515625e-05f; }
    else if (s < 6176){ float w = rd(vw4, s-6080, bfl); w = fminf(fmaxf(w,-1.f),QMAXF); v = rintf(w*128.f)*0.0078125f; }
    else { v = rintf(rd(vb4, s-6176, bfl)*16384.f)*6.103515625e-05f; }
    ws[153600 + i] = v;
  }
}

// row mapping: 0 = identity(1x1), 1 = ladder 3x3->2x2, 2 = ladder 2x2->1
template<int LMAP, int MSRC>
__device__ __forceinline__ int map_row(int ro, int tap){
  if (LMAP == 0){ return ro < MSRC ? ro : MSRC-1; }
  if (LMAP == 1){
    int g = ro >> 2, p = ro & 3;
    int base = g*9 + (p>>1)*3 + (p&1);
    return base + (tap==0 ? 0 : (tap==1 ? 3 : 4));
  }
  int g = ro > 7 ? 7 : ro;
  return g*4 + (tap==0 ? 0 : (tap==1 ? 2 : 3));
}

// Activation buffer: [16 kseg-planes][M+2 rows][8 f16]. Plane stride M+2 is
// EVEN so parity(group) == parity(row); e^=(row&8) swaps rows 8<->9, 10<->11
// within each plane — bijective, 16B-aligned, same involution on store+load.
template<int M>
__device__ __forceinline__ int aidx(int plane, int row, int c7){
  int e = (plane*(M+2) + row)*8 + c7;
  return e ^ (row & 8);
}

template<int MDST>
__device__ __forceinline__ void store_h(f16* buf, int row, int col, float v){
  buf[aidx<MDST>(col >> 3, row, col & 7)] = (f16)v;
}

template<int MTILES, int MSRC, int MDST, int TAPS, int LMAP>
__device__ __forceinline__ void mfma_layer(const f16* __restrict__ wf, int wbase,
                                           const float* __restrict__ ws, int boff,
                                           const f16* src, f16* dst, int lane, int wv)
{
  const int lr = lane & 15;
  const int lk = lane >> 4;
  const int c0 = wv*32 + lr;          // cols: c0 + nt*16

  f32x4 acc[MTILES][2];
  #pragma unroll
  for (int mt = 0; mt < MTILES; ++mt){
    #pragma unroll
    for (int nt = 0; nt < 2; ++nt){
      float bb = ws[boff + c0 + nt*16];
      acc[mt][nt] = (f32x4){bb, bb, bb, bb};
    }
  }

  #pragma unroll
  for (int tap = 0; tap < TAPS; ++tap){
    int rowin[MTILES];
    #pragma unroll
    for (int mt = 0; mt < MTILES; ++mt)
      rowin[mt] = map_row<LMAP, MSRC>(mt*16 + lr, tap);

    const f16* wh = wf + wbase + tap*16384;

    #pragma unroll
    for (int s = 0; s < 4; ++s){
      const int kseg = 4*s + lk;
      f16x8 ah[MTILES], bh[2];
      #pragma unroll
      for (int mt = 0; mt < MTILES; ++mt)
        ah[mt] = *(const f16x8*)(src + aidx<MSRC>(kseg, rowin[mt], 0));
      #pragma unroll
      for (int nt = 0; nt < 2; ++nt)
        bh[nt] = *(const f16x8*)(wh + (kseg*128 + c0 + nt*16)*8);
      #pragma unroll
      for (int mt = 0; mt < MTILES; ++mt)
        #pragma unroll
        for (int nt = 0; nt < 2; ++nt)
          acc[mt][nt] = __builtin_amdgcn_mfma_f32_16x16x32_f16(ah[mt], bh[nt], acc[mt][nt], 0, 0, 0);
    }
  }

  // epilogue: bias already in acc; mish, store single f16
  #pragma unroll
  for (int mt = 0; mt < MTILES; ++mt){
    #pragma unroll
    for (int nt = 0; nt < 2; ++nt){
      const int col = c0 + nt*16;
      #pragma unroll
      for (int r = 0; r < 4; ++r){
        const int row = mt*16 + lk*4 + r;
        if (row < MDST)
          store_h<MDST>(dst, row, col, mish_f(acc[mt][nt][r]));
      }
    }
  }
}

__global__ __launch_bounds__(256, 4)
void fused_kernel(const void* __restrict__ xv, const float* __restrict__ ws, void* __restrict__ outv)
{
  // bufA/bufB: [16][74][8] f16 = 18.5 KB each. Head scratch aliases dead
  // buffer regions (all uses separated by __syncthreads):
  //   bufB alias: xraw(98f) + xin[8][2][16] (used only before CH1 writes bufB)
  //   bufA alias: qbuf[8][48], featL, pkA/B, vA/B (used only after CH3 reads bufA)
  __shared__ __align__(16) f16 bufA[9472];
  __shared__ __align__(16) f16 bufB[9472];

  float* xraw = (float*)bufB;                    // 98 floats
  float* xin  = (float*)bufB + 128;              // [8][2][16] = 256 floats
  float* qbuf = (float*)bufA;                    // [8][48] = 384 floats
  float* featL= (float*)bufA + 384;              // 48
  float* pkA  = (float*)bufA + 432;              // 16
  float* pkB  = (float*)bufA + 448;              // 16
  float* vA   = (float*)bufA + 464;              // 32
  float* vB   = (float*)bufA + 496;              // 32

  const int tid  = threadIdx.x;
  const int lane = tid & 63;
  const int wv   = tid >> 6;
  const int b    = blockIdx.x;
  const bool bfl = detect_bf16(xv);
  const f16* wf  = (const f16*)ws;

  if (tid < 98) xraw[tid] = rd(xv, b*98 + tid, bfl);
  __syncthreads();

  // 8 rotated 4x4 crops
  {
    const int g = tid >> 5, r = tid & 31, c = r >> 4, p = r & 15;
    const int ri = p >> 2, rj = p & 3;
    const int k  = (0x13023120u >> (g*4)) & 0xF;
    const int y0 = (g >= 4) ? 3 : 0;
    const int x0 = (g >= 2 && g <= 5) ? 3 : 0;
    int sy, sx;
    if      (k == 0){ sy = ri;     sx = rj;     }
    else if (k == 1){ sy = rj;     sx = 3 - ri; }
    else if (k == 2){ sy = 3 - ri; sx = 3 - rj; }
    else            { sy = 3 - rj; sx = ri;     }
    xin[(g*2 + c)*16 + p] = xraw[c*49 + (y0 + sy)*7 + (x0 + sx)];
  }
  __syncthreads();

  // L1 ladder (ci=2): 4x4 -> 3x3 + mish, fp32 VALU, f16 store into bufA (72 rows)
  {
    const int o = tid & 127, sgp = tid >> 7;
    float wt[3][2];
    #pragma unroll
    for (int tp = 0; tp < 3; ++tp){
      wt[tp][0] = ws[OFF_W1 + (tp*2 + 0)*128 + o];
      wt[tp][1] = ws[OFF_W1 + (tp*2 + 1)*128 + o];
    }
    const float bb = ws[OFF_B1 + o];
    #pragma unroll
    for (int gi = 0; gi < 4; ++gi){
      const int g = sgp + 2*gi;
      const float* xg0 = xin + (g*2 + 0)*16;
      const float* xg1 = xin + (g*2 + 1)*16;
      #pragma unroll
      for (int i = 0; i < 3; ++i)
      #pragma unroll
      for (int j = 0; j < 3; ++j){
        float a = bb;
        a = fmaf(wt[0][0], xg0[i*4 + j],         a);
        a = fmaf(wt[0][1], xg1[i*4 + j],         a);
        a = fmaf(wt[1][0], xg0[(i+1)*4 + j],     a);
        a = fmaf(wt[1][1], xg1[(i+1)*4 + j],     a);
        a = fmaf(wt[2][0], xg0[(i+1)*4 + j + 1], a);
        a = fmaf(wt[2][1], xg1[(i+1)*4 + j + 1], a);
        store_h<72>(bufA, g*9 + i*3 + j, o, mish_f(a));
      }
    }
  }
  __syncthreads();

  mfma_layer<5,72,72,1,0>(wf, GW_C,          ws, OFF_CB,       bufA, bufB, lane, wv);
  __syncthreads();
  mfma_layer<2,72,32,3,1>(wf, GW_L,          ws, OFF_LB,       bufB, bufA, lane, wv);
  __syncthreads();
  mfma_layer<2,32,32,1,0>(wf, GW_C + 16384,  ws, OFF_CB + 128, bufA, bufB, lane, wv);
  __syncthreads();
  mfma_layer<1,32, 8,3,2>(wf, GW_L + 49152,  ws, OFF_LB + 128, bufB, bufA, lane, wv);
  __syncthreads();
  mfma_layer<1, 8, 8,1,0>(wf, GW_C + 32768,  ws, OFF_CB + 256, bufA, bufB, lane, wv);
  __syncthreads();

  // final 128 -> 48 (no act) + fake_quant into qbuf; waves 0..2, one 16-col tile each
  if (wv < 3){
    const int lr = lane & 15, lk = lane >> 4;
    const int col = wv*16 + lr;
    const int rowin = lr > 7 ? 7 : lr;
    const float bb = ws[OFF_FB + col];
    f32x4 a1 = (f32x4){bb, bb, bb, bb};
    #pragma unroll
    for (int s = 0; s < 4; ++s){
      const int kseg = 4*s + lk;
      f16x8 af = *(const f16x8*)(bufB + aidx<8>(kseg, rowin, 0));
      f16x8 bh = *(const f16x8*)(wf + GW_F + (kseg*48 + col)*8);
      a1 = __builtin_amdgcn_mfma_f32_16x16x32_f16(af, bh, a1, 0, 0, 0);
    }
    #pragma unroll
    for (int r = 0; r < 4; ++r){
      const int row = lk*4 + r;
      if (row < 8){
        float h = fminf(fmaxf(a1[r], -1.0f), QMAXF);
        qbuf[row*48 + col] = rintf(h * 128.0f) * 0.0078125f;
      }
    }
  }
  __syncthreads();

  if (tid < 48){
    float f = 0.0f;
    #pragma unroll
    for (int g = 0; g < 8; ++g) f += qbuf[g*48 + tid];
    featL[tid] = f;
  }
  __syncthreads();

  // heads (fp32 VALU, exact integer-grid value head)
  if (tid < 16){
    float a = ws[OFF_PB1 + tid];
    #pragma unroll
    for (int c = 0; c < 16; ++c) a = fmaf(featL[c], ws[OFF_PW1 + tid*16 + c], a);
    pkA[tid] = fmaxf(a, 0.0f);
  } else if (tid >= 64 && tid < 96){
    const int oo = tid - 64;
    float a = ws[OFF_QB + oo];
    #pragma unroll
    for (int c = 0; c < 32; ++c)
      a = fmaf(fminf(fmaxf(featL[16 + c], 0.0f), QMAXF), ws[OFF_QW + oo*32 + c], a);
    vA[oo] = a;
  }
  __syncthreads();

  if (tid < 16){
    float a = ws[OFF_PB2 + tid];
    #pragma unroll
    for (int c = 0; c < 16; ++c) a = fmaf(pkA[c], ws[OFF_PW2 + tid*16 + c], a);
    pkB[tid] = a;
  } else if (tid >= 64 && tid < 96){
    const int oo = tid - 64;
    float a = ws[OFF_QB + 32 + oo];
    #pragma unroll
    for (int c = 0; c < 32; ++c)
      a = fmaf(fminf(fmaxf(vA[c], 0.0f), QMAXF), ws[OFF_QW + 1024 + oo*32 + c], a);
    vB[oo] = a;
  }
  __syncthreads();

  if (tid < 49){
    float a = 0.0f;
    #pragma unroll
    for (int c = 0; c < 16; ++c) a = fmaf(pkB[c], ws[OFF_PQ + tid*16 + c], a);
    const int idx = 49152 + b*49 + tid;
    if (bfl) ((__hip_bfloat16*)outv)[idx] = __float2bfloat16(a);
    else     ((float*)outv)[idx] = a;
  } else if (tid >= 64 && tid < 96){
    const int oo = tid - 64;
    float a = ws[OFF_QB + 64 + oo];
    #pragma unroll
    for (int c = 0; c < 32; ++c)
      a = fmaf(fminf(fmaxf(vB[c], 0.0f), QMAXF), ws[OFF_QW + 2048 + oo*32 + c], a);
    vA[oo] = a;
  }
  __syncthreads();

  if (tid < 3){
    float a = ws[OFF_QB4 + tid];
    #pragma unroll
    for (int c = 0; c < 32; ++c)
      a = fmaf(fminf(fmaxf(vA[c], 0.0f), QMAXF), ws[OFF_QW4 + tid*32 + c], a);
    const int idx = b*3 + tid;
    if (bfl) ((__hip_bfloat16*)outv)[idx] = __float2bfloat16(a);
    else     ((float*)outv)[idx] = a;
  }
}

extern "C" void kernel_launch(void* const* d_in, const int* in_sizes, int n_in,
                              void* d_out, int out_size, void* d_ws, size_t ws_size,
                              hipStream_t stream)
{
  (void)in_sizes; (void)n_in; (void)out_size; (void)ws_size;
  float* ws = (float*)d_ws;
  prep_kernel<<<256, 256, 0, stream>>>(
      d_in[0],  d_in[1],  d_in[2],  d_in[3],  d_in[4],  d_in[5],  d_in[6],  d_in[7],
      d_in[8],  d_in[9],  d_in[10], d_in[11], d_in[12], d_in[13], d_in[14], d_in[15],
      d_in[16], d_in[17], d_in[18], d_in[19], d_in[20], d_in[21], ws);
  fused_kernel<<<16384, 256, 0, stream>>>(d_in[0], ws, d_out);
}

// Round 6
// 334.106 us; speedup vs baseline: 8.6955x; 1.0682x over previous
//
#include <hip/hip_runtime.h>
#include <hip/hip_bf16.h>

typedef _Float16 f16;
typedef f16 f16x8 __attribute__((ext_vector_type(8)));
typedef float f32x4 __attribute__((ext_vector_type(4)));

#define QMAXF (127.0f/128.0f)

// float-slot offsets for fp32 scalar region.
enum {
  OFF_W1 = 153600, OFF_B1 = 154368, OFF_CB = 154496, OFF_LB = 154880,
  OFF_FB = 155136, OFF_PW1 = 155184, OFF_PB1 = 155440, OFF_PW2 = 155456,
  OFF_PB2 = 155712, OFF_PQ = 155728, OFF_QW = 156512, OFF_QB = 159584,
  OFF_QW4 = 159680, OFF_QB4 = 159776, WS_TOTAL = 159779
};
// f16-element offsets inside the weight region.
enum {
  GW_C = 0,            // 3 conv1x1 layers x [16 kseg][128 col][8]
  GW_L = 49152,        // 6 ladder tap-mats x 16384
  GW_F = 147456,       // final 128->48: [16 kseg][48 col][8]
  GW_TOTAL = 153600
};

__device__ __forceinline__ bool detect_bf16(const void* x){
  const unsigned short* u = (const unsigned short*)x;
  int hits = 0;
  #pragma unroll
  for (int i = 0; i < 32; i += 2){
    unsigned short h = u[i];
    hits += (h >= 0x3800 && h <= 0x3F80) ? 1 : 0;
  }
  return hits >= 12;
}

__device__ __forceinline__ float rd(const void* p, int i, bool bfl){
  return bfl ? __bfloat162float(((const __hip_bfloat16*)p)[i]) : ((const float*)p)[i];
}

// mish(x) = x*(m-2)*rcp(m), m = u^2+2u+2, u = exp(x). 6 VALU + 2 trans.
__device__ __forceinline__ float mish_f(float x){
  float u = __expf(fminf(x, 30.0f));
  float m = fmaf(u, u + 2.0f, 2.0f);
  return x * (m - 2.0f) * __builtin_amdgcn_rcpf(m);
}

__global__ void prep_kernel(const void* x, const void* lw1, const void* lb1, const void* lw23,
                            const void* lb23, const void* cw, const void* cb, const void* cs,
                            const void* ct, const void* cwf, const void* cbf, const void* csf,
                            const void* ctf, const void* pw1, const void* pb1, const void* pw2,
                            const void* pb2, const void* pq, const void* vw, const void* vb,
                            const void* vw4, const void* vb4, float* ws)
{
  const bool bfl = detect_bf16(x);
  f16* wf = (f16*)ws;
  const int t0 = blockIdx.x*blockDim.x + threadIdx.x;
  const int stride = gridDim.x*blockDim.x;

  for (int e = t0; e < GW_TOTAL; e += stride){
    float w;
    if (e < GW_L){
      int l = e >> 14, r = e & 16383;
      int kseg = r >> 10, col = (r >> 3) & 127, j = r & 7, k = kseg*8 + j;
      w = rd(cw, (l*128 + col)*128 + k, bfl) * rd(cs, l*128 + col, bfl);
    } else if (e < GW_F){
      int ee = e - GW_L;
      int lt = ee >> 14, r = ee & 16383;
      int kseg = r >> 10, col = (r >> 3) & 127, j = r & 7, k = kseg*8 + j;
      w = rd(lw23, lt*16384 + col*128 + k, bfl);
    } else {
      int ee = e - GW_F;
      int kseg = ee / 384, r = ee % 384, col = r >> 3, j = r & 7, k = kseg*8 + j;
      w = rd(cwf, col*128 + k, bfl) * rd(csf, col, bfl);
    }
    wf[e] = (f16)w;
  }

  for (int i = t0; i < 6179; i += stride){
    float v; int s = i;
    if (s < 768){ int tap = s>>8, r = s&255, c = r>>7, o = r&127; v = rd(lw1,(tap*128+o)*2+c,bfl); }
    else if (s < 896){ v = rd(lb1, s-768, bfl); }
    else if (s < 1280){ int idx = s-896; v = rd(cb,idx,bfl)*rd(cs,idx,bfl)+rd(ct,idx,bfl); }
    else if (s < 1536){ v = rd(lb23, s-1280, bfl); }
    else if (s < 1584){ int m = s-1536; v = rd(cbf,m,bfl)*rd(csf,m,bfl)+rd(ctf,m,bfl); }
    else if (s < 1840){ v = rd(pw1, s-1584, bfl); }
    else if (s < 1856){ v = rd(pb1, s-1840, bfl); }
    else if (s < 2112){ v = rd(pw2, s-1856, bfl); }
    else if (s < 2128){ v = rd(pb2, s-2112, bfl); }
    else if (s < 2912){ v = rd(pq, s-2128, bfl); }
    else if (s < 5984){ float w = rd(vw, s-2912, bfl); w = fminf(fmaxf(w,-1.f),QMAXF); v = rintf(w*128.f)*0.0078125f; }
    else if (s < 6080){ v = rintf(rd(vb, s-5984, bfl)*16384.f)*6.103515625e-05f; }
    else if (s < 6176){ float w = rd(vw4, s-6080, bfl); w = fminf(fmaxf(w,-1.f),QMAXF); v = rintf(w*128.f)*0.0078125f; }
    else { v = rintf(rd(vb4, s-6176, bfl)*16384.f)*6.103515625e-05f; }
    ws[153600 + i] = v;
  }
}

// 2-sample row maps. LMAP0 identity (all tilings exact).
// LMAP1: L2 out row ro in [0,64): smp=ro>>5, w=ro&31, g=w>>2, p=w&3
//        src = smp*72 + g*9 + (p>>1)*3 + (p&1) + {0,3,4}[tap]
// LMAP2: L3 out row ro in [0,16): smp=ro>>3, g=ro&7
//        src = smp*32 + g*4 + {0,2,3}[tap]
template<int LMAP>
__device__ __forceinline__ int map_row2(int ro, int tap){
  if (LMAP == 0) return ro;
  if (LMAP == 1){
    int smp = ro >> 5, w = ro & 31, g = w >> 2, p = w & 3;
    return smp*72 + g*9 + (p>>1)*3 + (p&1) + (tap==0 ? 0 : (tap==1 ? 3 : 4));
  }
  int smp = ro >> 3, g = ro & 7;
  return smp*32 + g*4 + (tap==0 ? 0 : (tap==1 ? 2 : 3));
}

// Activation buffer: [16 kseg-planes][M+2 rows][8 f16]. Even plane stride =>
// parity(group) == parity(row); e^=(row&8) swaps rows 8<->9,10<->11 within a
// plane: bijective, 16B-aligned, same involution on store and load.
template<int M>
__device__ __forceinline__ int aidx(int plane, int row, int c7){
  int e = (plane*(M+2) + row)*8 + c7;
  return e ^ (row & 8);
}

template<int MDST>
__device__ __forceinline__ void store_h(f16* buf, int row, int col, float v){
  buf[aidx<MDST>(col >> 3, row, col & 7)] = (f16)v;
}

// 8 waves, wave wv owns cols [wv*16, wv*16+16). Exact M tiling, no guards.
template<int MTILES, int MSRC, int MDST, int TAPS, int LMAP>
__device__ __forceinline__ void mfma_layer(const f16* __restrict__ wf, int wbase,
                                           const float* __restrict__ ws, int boff,
                                           const f16* src, f16* dst, int lane, int wv)
{
  const int lr = lane & 15;
  const int lk = lane >> 4;
  const int c0 = wv*16 + lr;

  f32x4 acc[MTILES];
  const float bb = ws[boff + c0];
  #pragma unroll
  for (int mt = 0; mt < MTILES; ++mt) acc[mt] = (f32x4){bb, bb, bb, bb};

  #pragma unroll
  for (int tap = 0; tap < TAPS; ++tap){
    int rowin[MTILES];
    #pragma unroll
    for (int mt = 0; mt < MTILES; ++mt)
      rowin[mt] = map_row2<LMAP>(mt*16 + lr, tap);

    const f16* wh = wf + wbase + tap*16384;

    #pragma unroll
    for (int s = 0; s < 4; ++s){
      const int kseg = 4*s + lk;
      f16x8 bh = *(const f16x8*)(wh + (kseg*128 + c0)*8);
      #pragma unroll
      for (int mt = 0; mt < MTILES; ++mt){
        f16x8 ah = *(const f16x8*)(src + aidx<MSRC>(kseg, rowin[mt], 0));
        acc[mt] = __builtin_amdgcn_mfma_f32_16x16x32_f16(ah, bh, acc[mt], 0, 0, 0);
      }
    }
  }

  #pragma unroll
  for (int mt = 0; mt < MTILES; ++mt)
    #pragma unroll
    for (int r = 0; r < 4; ++r)
      store_h<MDST>(dst, mt*16 + lk*4 + r, c0, mish_f(acc[mt][r]));
}

__global__ __launch_bounds__(512, 4)
void fused_kernel(const void* __restrict__ xv, const float* __restrict__ ws, void* __restrict__ outv)
{
  // [16][146][8] f16 = 36.5 KB each; 73 KB total -> 2 blocks/CU.
  // Scratch aliases dead buffer regions (separated by __syncthreads):
  //   bufB alias: xraw(196f) + xin(512f)  — dead once CH1 writes bufB
  //   bufA alias: qbuf(768f) feat(96) pk(64) v(128) — live after CH3 reads bufA
  __shared__ __align__(16) f16 bufA[18688];
  __shared__ __align__(16) f16 bufB[18688];

  float* xraw = (float*)bufB;                 // [2][98]
  float* xin  = (float*)bufB + 256;           // [2][8][2][16]
  float* qbuf = (float*)bufA;                 // [16][48]
  float* featL= (float*)bufA + 768;           // [2][48]
  float* pkA  = (float*)bufA + 864;           // [2][16]
  float* pkB  = (float*)bufA + 896;           // [2][16]
  float* vA   = (float*)bufA + 928;           // [2][32]
  float* vB   = (float*)bufA + 992;           // [2][32]

  const int tid  = threadIdx.x;
  const int lane = tid & 63;
  const int wv   = tid >> 6;                  // 0..7
  const int b    = blockIdx.x;                // 2 samples: b*2, b*2+1
  const bool bfl = detect_bf16(xv);
  const f16* wf  = (const f16*)ws;

  if (tid < 196){
    int smp = tid >= 98 ? 1 : 0;
    int q = tid - 98*smp;
    xraw[smp*98 + q] = rd(xv, (b*2 + smp)*98 + q, bfl);
  }
  __syncthreads();

  // 16 rotated 4x4 crops (2 samples x 8 chunks) — exactly 512 threads
  {
    const int smp = tid >> 8, rest = tid & 255;
    const int g = rest >> 5, r2 = rest & 31, c = r2 >> 4, p = r2 & 15;
    const int ri = p >> 2, rj = p & 3;
    const int k  = (0x13023120u >> (g*4)) & 0xF;
    const int y0 = (g >= 4) ? 3 : 0;
    const int x0 = (g >= 2 && g <= 5) ? 3 : 0;
    int sy, sx;
    if      (k == 0){ sy = ri;     sx = rj;     }
    else if (k == 1){ sy = rj;     sx = 3 - ri; }
    else if (k == 2){ sy = 3 - ri; sx = 3 - rj; }
    else            { sy = 3 - rj; sx = ri;     }
    xin[((smp*8 + g)*2 + c)*16 + p] = xraw[smp*98 + c*49 + (y0 + sy)*7 + (x0 + sx)];
  }
  __syncthreads();

  // L1 ladder (ci=2): 4x4 -> 3x3 + mish, fp32 VALU, f16 store (144 rows)
  {
    const int o = tid & 127, grp = tid >> 7;        // grp 0..3
    const int smp = grp >> 1, sgp = grp & 1;
    float wt[3][2];
    #pragma unroll
    for (int tp = 0; tp < 3; ++tp){
      wt[tp][0] = ws[OFF_W1 + (tp*2 + 0)*128 + o];
      wt[tp][1] = ws[OFF_W1 + (tp*2 + 1)*128 + o];
    }
    const float bb = ws[OFF_B1 + o];
    #pragma unroll
    for (int gi = 0; gi < 4; ++gi){
      const int g = sgp + 2*gi;
      const float* xg0 = xin + ((smp*8 + g)*2 + 0)*16;
      const float* xg1 = xin + ((smp*8 + g)*2 + 1)*16;
      #pragma unroll
      for (int i = 0; i < 3; ++i)
      #pragma unroll
      for (int j = 0; j < 3; ++j){
        float a = bb;
        a = fmaf(wt[0][0], xg0[i*4 + j],         a);
        a = fmaf(wt[0][1], xg1[i*4 + j],         a);
        a = fmaf(wt[1][0], xg0[(i+1)*4 + j],     a);
        a = fmaf(wt[1][1], xg1[(i+1)*4 + j],     a);
        a = fmaf(wt[2][0], xg0[(i+1)*4 + j + 1], a);
        a = fmaf(wt[2][1], xg1[(i+1)*4 + j + 1], a);
        store_h<144>(bufA, smp*72 + g*9 + i*3 + j, o, mish_f(a));
      }
    }
  }
  __syncthreads();

  mfma_layer<9,144,144,1,0>(wf, GW_C,          ws, OFF_CB,       bufA, bufB, lane, wv);
  __syncthreads();
  mfma_layer<4,144, 64,3,1>(wf, GW_L,          ws, OFF_LB,       bufB, bufA, lane, wv);
  __syncthreads();
  mfma_layer<4, 64, 64,1,0>(wf, GW_C + 16384,  ws, OFF_CB + 128, bufA, bufB, lane, wv);
  __syncthreads();
  mfma_layer<1, 64, 16,3,2>(wf, GW_L + 49152,  ws, OFF_LB + 128, bufB, bufA, lane, wv);
  __syncthreads();
  mfma_layer<1, 16, 16,1,0>(wf, GW_C + 32768,  ws, OFF_CB + 256, bufA, bufB, lane, wv);
  __syncthreads();

  // final 128->48 (no act) + fake_quant; waves 0..2, 16 rows = 2 samples exact
  if (wv < 3){
    const int lr = lane & 15, lk = lane >> 4;
    const int col = wv*16 + lr;
    const float bb = ws[OFF_FB + col];
    f32x4 a1 = (f32x4){bb, bb, bb, bb};
    #pragma unroll
    for (int s = 0; s < 4; ++s){
      const int kseg = 4*s + lk;
      f16x8 af = *(const f16x8*)(bufB + aidx<16>(kseg, lr, 0));
      f16x8 bh = *(const f16x8*)(wf + GW_F + (kseg*48 + col)*8);
      a1 = __builtin_amdgcn_mfma_f32_16x16x32_f16(af, bh, a1, 0, 0, 0);
    }
    #pragma unroll
    for (int r = 0; r < 4; ++r){
      const int row = lk*4 + r;                    // 0..15 = smp*8+g
      float h = fminf(fmaxf(a1[r], -1.0f), QMAXF);
      qbuf[row*48 + col] = rintf(h * 128.0f) * 0.0078125f;
    }
  }
  __syncthreads();

  const int t = tid & 255, smp = tid >> 8;
  if (t < 48){
    float f = 0.0f;
    #pragma unroll
    for (int g = 0; g < 8; ++g) f += qbuf[(smp*8 + g)*48 + t];
    featL[smp*48 + t] = f;
  }
  __syncthreads();

  if (t < 16){
    float a = ws[OFF_PB1 + t];
    #pragma unroll
    for (int c = 0; c < 16; ++c) a = fmaf(featL[smp*48 + c], ws[OFF_PW1 + t*16 + c], a);
    pkA[smp*16 + t] = fmaxf(a, 0.0f);
  } else if (t >= 64 && t < 96){
    const int oo = t - 64;
    float a = ws[OFF_QB + oo];
    #pragma unroll
    for (int c = 0; c < 32; ++c)
      a = fmaf(fminf(fmaxf(featL[smp*48 + 16 + c], 0.0f), QMAXF), ws[OFF_QW + oo*32 + c], a);
    vA[smp*32 + oo] = a;
  }
  __syncthreads();

  if (t < 16){
    float a = ws[OFF_PB2 + t];
    #pragma unroll
    for (int c = 0; c < 16; ++c) a = fmaf(pkA[smp*16 + c], ws[OFF_PW2 + t*16 + c], a);
    pkB[smp*16 + t] = a;
  } else if (t >= 64 && t < 96){
    const int oo = t - 64;
    float a = ws[OFF_QB + 32 + oo];
    #pragma unroll
    for (int c = 0; c < 32; ++c)
      a = fmaf(fminf(fmaxf(vA[smp*32 + c], 0.0f), QMAXF), ws[OFF_QW + 1024 + oo*32 + c], a);
    vB[smp*32 + oo] = a;
  }
  __syncthreads();

  if (t < 49){
    float a = 0.0f;
    #pragma unroll
    for (int c = 0; c < 16; ++c) a = fmaf(pkB[smp*16 + c], ws[OFF_PQ + t*16 + c], a);
    const int idx = 49152 + (b*2 + smp)*49 + t;
    if (bfl) ((__hip_bfloat16*)outv)[idx] = __float2bfloat16(a);
    else     ((float*)outv)[idx] = a;
  } else if (t >= 64 && t < 96){
    const int oo = t - 64;
    float a = ws[OFF_QB + 64 + oo];
    #pragma unroll
    for (int c = 0; c < 32; ++c)
      a = fmaf(fminf(fmaxf(vB[smp*32 + c], 0.0f), QMAXF), ws[OFF_QW + 2048 + oo*32 + c], a);
    vA[smp*32 + oo] = a;
  }
  __syncthreads();

  if (t < 3){
    float a = ws[OFF_QB4 + t];
    #pragma unroll
    for (int c = 0; c < 32; ++c)
      a = fmaf(fminf(fmaxf(vA[smp*32 + c], 0.0f), QMAXF), ws[OFF_QW4 + t*32 + c], a);
    const int idx = (b*2 + smp)*3 + t;
    if (bfl) ((__hip_bfloat16*)outv)[idx] = __float2bfloat16(a);
    else     ((float*)outv)[idx] = a;
  }
}

extern "C" void kernel_launch(void* const* d_in, const int* in_sizes, int n_in,
                              void* d_out, int out_size, void* d_ws, size_t ws_size,
                              hipStream_t stream)
{
  (void)in_sizes; (void)n_in; (void)out_size; (void)ws_size;
  float* ws = (float*)d_ws;
  prep_kernel<<<256, 256, 0, stream>>>(
      d_in[0],  d_in[1],  d_in[2],  d_in[3],  d_in[4],  d_in[5],  d_in[6],  d_in[7],
      d_in[8],  d_in[9],  d_in[10], d_in[11], d_in[12], d_in[13], d_in[14], d_in[15],
      d_in[16], d_in[17], d_in[18], d_in[19], d_in[20], d_in[21], ws);
  fused_kernel<<<8192, 512, 0, stream>>>(d_in[0], ws, d_out);
}

// Round 7
// 302.348 us; speedup vs baseline: 9.6088x; 1.1050x over previous
//
#include <hip/hip_runtime.h>
#include <hip/hip_bf16.h>

typedef _Float16 f16;
typedef f16 f16x8 __attribute__((ext_vector_type(8)));
typedef float f32x4 __attribute__((ext_vector_type(4)));

#define QMAXF (127.0f/128.0f)

// float-slot offsets for fp32 scalar region.
enum {
  OFF_W1 = 153600, OFF_B1 = 154368, OFF_CB = 154496, OFF_LB = 154880,
  OFF_FB = 155136, OFF_PW1 = 155184, OFF_PB1 = 155440, OFF_PW2 = 155456,
  OFF_PB2 = 155712, OFF_PQ = 155728, OFF_QW = 156512, OFF_QB = 159584,
  OFF_QW4 = 159680, OFF_QB4 = 159776, WS_TOTAL = 159779
};
// f16-element offsets inside the weight region.
enum {
  GW_C = 0,            // 3 conv1x1 layers x [16 kseg][128 col][8]
  GW_L = 49152,        // 6 ladder tap-mats x 16384
  GW_F = 147456,       // final 128->48: [16 kseg][48 col][8]
  GW_TOTAL = 153600
};

__device__ __forceinline__ bool detect_bf16(const void* x){
  const unsigned short* u = (const unsigned short*)x;
  int hits = 0;
  #pragma unroll
  for (int i = 0; i < 32; i += 2){
    unsigned short h = u[i];
    hits += (h >= 0x3800 && h <= 0x3F80) ? 1 : 0;
  }
  return hits >= 12;
}

__device__ __forceinline__ float rd(const void* p, int i, bool bfl){
  return bfl ? __bfloat162float(((const __hip_bfloat16*)p)[i]) : ((const float*)p)[i];
}

// mish(x) = x - 2x/(u(u+2)+2), u = exp(x). 5 VALU + 2 trans.
__device__ __forceinline__ float mish_f(float x){
  float u = __expf(fminf(x, 30.0f));
  float m = fmaf(u, u + 2.0f, 2.0f);
  return fmaf(-2.0f*x, __builtin_amdgcn_rcpf(m), x);
}

__global__ void prep_kernel(const void* x, const void* lw1, const void* lb1, const void* lw23,
                            const void* lb23, const void* cw, const void* cb, const void* cs,
                            const void* ct, const void* cwf, const void* cbf, const void* csf,
                            const void* ctf, const void* pw1, const void* pb1, const void* pw2,
                            const void* pb2, const void* pq, const void* vw, const void* vb,
                            const void* vw4, const void* vb4, float* ws)
{
  const bool bfl = detect_bf16(x);
  f16* wf = (f16*)ws;
  const int t0 = blockIdx.x*blockDim.x + threadIdx.x;
  const int stride = gridDim.x*blockDim.x;

  for (int e = t0; e < GW_TOTAL; e += stride){
    float w;
    if (e < GW_L){
      int l = e >> 14, r = e & 16383;
      int kseg = r >> 10, col = (r >> 3) & 127, j = r & 7, k = kseg*8 + j;
      w = rd(cw, (l*128 + col)*128 + k, bfl) * rd(cs, l*128 + col, bfl);
    } else if (e < GW_F){
      int ee = e - GW_L;
      int lt = ee >> 14, r = ee & 16383;
      int kseg = r >> 10, col = (r >> 3) & 127, j = r & 7, k = kseg*8 + j;
      w = rd(lw23, lt*16384 + col*128 + k, bfl);
    } else {
      int ee = e - GW_F;
      int kseg = ee / 384, r = ee % 384, col = r >> 3, j = r & 7, k = kseg*8 + j;
      w = rd(cwf, col*128 + k, bfl) * rd(csf, col, bfl);
    }
    wf[e] = (f16)w;
  }

  for (int i = t0; i < 6179; i += stride){
    float v; int s = i;
    if (s < 768){ int tap = s>>8, r = s&255, c = r>>7, o = r&127; v = rd(lw1,(tap*128+o)*2+c,bfl); }
    else if (s < 896){ v = rd(lb1, s-768, bfl); }
    else if (s < 1280){ int idx = s-896; v = rd(cb,idx,bfl)*rd(cs,idx,bfl)+rd(ct,idx,bfl); }
    else if (s < 1536){ v = rd(lb23, s-1280, bfl); }
    else if (s < 1584){ int m = s-1536; v = rd(cbf,m,bfl)*rd(csf,m,bfl)+rd(ctf,m,bfl); }
    else if (s < 1840){ v = rd(pw1, s-1584, bfl); }
    else if (s < 1856){ v = rd(pb1, s-1840, bfl); }
    else if (s < 2112){ v = rd(pw2, s-1856, bfl); }
    else if (s < 2128){ v = rd(pb2, s-2112, bfl); }
    else if (s < 2912){ v = rd(pq, s-2128, bfl); }
    else if (s < 5984){ float w = rd(vw, s-2912, bfl); w = fminf(fmaxf(w,-1.f),QMAXF); v = rintf(w*128.f)*0.0078125f; }
    else if (s < 6080){ v = rintf(rd(vb, s-5984, bfl)*16384.f)*6.103515625e-05f; }
    else if (s < 6176){ float w = rd(vw4, s-6080, bfl); w = fminf(fmaxf(w,-1.f),QMAXF); v = rintf(w*128.f)*0.0078125f; }
    else { v = rintf(rd(vb4, s-6176, bfl)*16384.f)*6.103515625e-05f; }
    ws[153600 + i] = v;
  }
}

// 2-sample row maps (row index within the activation matrix).
template<int LMAP>
__device__ __forceinline__ int map_row2(int ro, int tap){
  if (LMAP == 0) return ro;
  if (LMAP == 1){
    int smp = ro >> 5, w = ro & 31, g = w >> 2, p = w & 3;
    return smp*72 + g*9 + (p>>1)*3 + (p&1) + (tap==0 ? 0 : (tap==1 ? 3 : 4));
  }
  int smp = ro >> 3, g = ro & 7;
  return smp*32 + g*4 + (tap==0 ? 0 : (tap==1 ? 2 : 3));
}

// Activation layout: [16 kseg-planes][M+2 rows][8 f16], purely affine (no
// XOR). Plane stride (M+2)*16B with M+2 even => plane step = 8 banks mod 32:
// b128 reads balance 8 lanes/bank-quad (BW floor); 2B epilogue stores are
// <=2-way (free, m136). Affine indices let LLVM fold all LDS addressing into
// per-thread bases + ds offset immediates.

// 8 waves, wave wv owns cols [wv*16, wv*16+16). Exact M tiling, no guards.
template<int MTILES, int MSRC, int MDST, int TAPS, int LMAP>
__device__ __forceinline__ void mfma_layer(const f16* __restrict__ wf, int wbase,
                                           const float* __restrict__ ws, int boff,
                                           const f16* src, f16* dst, int lane, int wv)
{
  const int lr = lane & 15;
  const int lk = lane >> 4;
  const int c0 = wv*16 + lr;
  constexpr int SS = MSRC + 2;
  constexpr int SD = MDST + 2;

  const f16* srck = src + lk*SS*8;                       // per-thread base
  f16* dstw = dst + ((c0>>3)*SD + lk*4)*8 + (c0&7);      // per-thread base

  f32x4 acc[MTILES];
  const float bb = ws[boff + c0];
  #pragma unroll
  for (int mt = 0; mt < MTILES; ++mt) acc[mt] = (f32x4){bb, bb, bb, bb};

  #pragma unroll
  for (int tap = 0; tap < TAPS; ++tap){
    int rowoff[MTILES];
    #pragma unroll
    for (int mt = 0; mt < MTILES; ++mt)
      rowoff[mt] = map_row2<LMAP>(mt*16 + lr, tap) * 8;

    const f16* whk = wf + wbase + tap*16384 + (lk*128 + c0)*8;

    #pragma unroll
    for (int s = 0; s < 4; ++s){
      f16x8 bh = *(const f16x8*)(whk + s*4096);
      #pragma unroll
      for (int mt = 0; mt < MTILES; ++mt){
        f16x8 ah = *(const f16x8*)(srck + s*4*SS*8 + rowoff[mt]);
        acc[mt] = __builtin_amdgcn_mfma_f32_16x16x32_f16(ah, bh, acc[mt], 0, 0, 0);
      }
    }
  }

  #pragma unroll
  for (int mt = 0; mt < MTILES; ++mt)
    #pragma unroll
    for (int r = 0; r < 4; ++r)
      dstw[(mt*16 + r)*8] = (f16)mish_f(acc[mt][r]);   // static ds offsets
}

__global__ __launch_bounds__(512, 4)
void fused_kernel(const void* __restrict__ xv, const float* __restrict__ ws, void* __restrict__ outv)
{
  // [16][146][8] f16 = 36.5 KB each; 73 KB total -> 2 blocks/CU.
  // Scratch aliases dead buffer regions (separated by __syncthreads):
  //   bufB alias: xraw(196f) + xin(512f)  — dead once CH1 writes bufB
  //   bufA alias: qbuf(768f) feat(96) pk(64) v(128) — live after CH3 reads bufA
  __shared__ __align__(16) f16 bufA[18688];
  __shared__ __align__(16) f16 bufB[18688];

  float* xraw = (float*)bufB;                 // [2][98]
  float* xin  = (float*)bufB + 256;           // [2][8][2][16]
  float* qbuf = (float*)bufA;                 // [16][48]
  float* featL= (float*)bufA + 768;           // [2][48]
  float* pkA  = (float*)bufA + 864;           // [2][16]
  float* pkB  = (float*)bufA + 896;           // [2][16]
  float* vA   = (float*)bufA + 928;           // [2][32]
  float* vB   = (float*)bufA + 992;           // [2][32]

  const int tid  = threadIdx.x;
  const int lane = tid & 63;
  const int wv   = tid >> 6;                  // 0..7
  const int b    = blockIdx.x;                // 2 samples: b*2, b*2+1
  const bool bfl = detect_bf16(xv);
  const f16* wf  = (const f16*)ws;

  if (tid < 196){
    int smp = tid >= 98 ? 1 : 0;
    int q = tid - 98*smp;
    xraw[smp*98 + q] = rd(xv, (b*2 + smp)*98 + q, bfl);
  }
  __syncthreads();

  // 16 rotated 4x4 crops (2 samples x 8 chunks) — exactly 512 threads
  {
    const int smp = tid >> 8, rest = tid & 255;
    const int g = rest >> 5, r2 = rest & 31, c = r2 >> 4, p = r2 & 15;
    const int ri = p >> 2, rj = p & 3;
    const int k  = (0x13023120u >> (g*4)) & 0xF;
    const int y0 = (g >= 4) ? 3 : 0;
    const int x0 = (g >= 2 && g <= 5) ? 3 : 0;
    int sy, sx;
    if      (k == 0){ sy = ri;     sx = rj;     }
    else if (k == 1){ sy = rj;     sx = 3 - ri; }
    else if (k == 2){ sy = 3 - ri; sx = 3 - rj; }
    else            { sy = 3 - rj; sx = ri;     }
    xin[((smp*8 + g)*2 + c)*16 + p] = xraw[smp*98 + c*49 + (y0 + sy)*7 + (x0 + sx)];
  }
  __syncthreads();

  // L1 ladder (ci=2): 4x4 -> 3x3 + mish, fp32 VALU, f16 store (144 rows)
  {
    const int o = tid & 127, grp = tid >> 7;        // grp 0..3
    const int smp = grp >> 1, sgp = grp & 1;
    float wt[3][2];
    #pragma unroll
    for (int tp = 0; tp < 3; ++tp){
      wt[tp][0] = ws[OFF_W1 + (tp*2 + 0)*128 + o];
      wt[tp][1] = ws[OFF_W1 + (tp*2 + 1)*128 + o];
    }
    const float bb = ws[OFF_B1 + o];
    // per-thread store base: ((o>>3)*146 + smp*72 + sgp*9)*8 + (o&7)
    f16* d1 = bufA + ((o>>3)*146 + smp*72 + sgp*9)*8 + (o&7);
    #pragma unroll
    for (int gi = 0; gi < 4; ++gi){
      const int g = sgp + 2*gi;
      const float* xg0 = xin + ((smp*8 + g)*2 + 0)*16;
      const float* xg1 = xin + ((smp*8 + g)*2 + 1)*16;
      #pragma unroll
      for (int i = 0; i < 3; ++i)
      #pragma unroll
      for (int j = 0; j < 3; ++j){
        float a = bb;
        a = fmaf(wt[0][0], xg0[i*4 + j],         a);
        a = fmaf(wt[0][1], xg1[i*4 + j],         a);
        a = fmaf(wt[1][0], xg0[(i+1)*4 + j],     a);
        a = fmaf(wt[1][1], xg1[(i+1)*4 + j],     a);
        a = fmaf(wt[2][0], xg0[(i+1)*4 + j + 1], a);
        a = fmaf(wt[2][1], xg1[(i+1)*4 + j + 1], a);
        d1[(2*gi*9 + i*3 + j)*8] = (f16)mish_f(a);   // static ds offsets
      }
    }
  }
  __syncthreads();

  mfma_layer<9,144,144,1,0>(wf, GW_C,          ws, OFF_CB,       bufA, bufB, lane, wv);
  __syncthreads();
  mfma_layer<4,144, 64,3,1>(wf, GW_L,          ws, OFF_LB,       bufB, bufA, lane, wv);
  __syncthreads();
  mfma_layer<4, 64, 64,1,0>(wf, GW_C + 16384,  ws, OFF_CB + 128, bufA, bufB, lane, wv);
  __syncthreads();
  mfma_layer<1, 64, 16,3,2>(wf, GW_L + 49152,  ws, OFF_LB + 128, bufB, bufA, lane, wv);
  __syncthreads();
  mfma_layer<1, 16, 16,1,0>(wf, GW_C + 32768,  ws, OFF_CB + 256, bufA, bufB, lane, wv);
  __syncthreads();

  // final 128->48 (no act) + fake_quant; waves 0..2, 16 rows = 2 samples exact
  if (wv < 3){
    const int lr = lane & 15, lk = lane >> 4;
    const int col = wv*16 + lr;
    const float bb = ws[OFF_FB + col];
    const f16* srck = bufB + lk*18*8 + lr*8;
    f32x4 a1 = (f32x4){bb, bb, bb, bb};
    #pragma unroll
    for (int s = 0; s < 4; ++s){
      f16x8 af = *(const f16x8*)(srck + s*4*18*8);
      f16x8 bh = *(const f16x8*)(wf + GW_F + ((4*s + lk)*48 + col)*8);
      a1 = __builtin_amdgcn_mfma_f32_16x16x32_f16(af, bh, a1, 0, 0, 0);
    }
    #pragma unroll
    for (int r = 0; r < 4; ++r){
      const int row = lk*4 + r;                    // 0..15 = smp*8+g
      float h = fminf(fmaxf(a1[r], -1.0f), QMAXF);
      qbuf[row*48 + col] = rintf(h * 128.0f) * 0.0078125f;
    }
  }
  __syncthreads();

  const int t = tid & 255, smp = tid >> 8;
  if (t < 48){
    float f = 0.0f;
    #pragma unroll
    for (int g = 0; g < 8; ++g) f += qbuf[(smp*8 + g)*48 + t];
    featL[smp*48 + t] = f;
  }
  __syncthreads();

  if (t < 16){
    float a = ws[OFF_PB1 + t];
    #pragma unroll
    for (int c = 0; c < 16; ++c) a = fmaf(featL[smp*48 + c], ws[OFF_PW1 + t*16 + c], a);
    pkA[smp*16 + t] = fmaxf(a, 0.0f);
  } else if (t >= 64 && t < 96){
    const int oo = t - 64;
    float a = ws[OFF_QB + oo];
    #pragma unroll
    for (int c = 0; c < 32; ++c)
      a = fmaf(fminf(fmaxf(featL[smp*48 + 16 + c], 0.0f), QMAXF), ws[OFF_QW + oo*32 + c], a);
    vA[smp*32 + oo] = a;
  }
  __syncthreads();

  if (t < 16){
    float a = ws[OFF_PB2 + t];
    #pragma unroll
    for (int c = 0; c < 16; ++c) a = fmaf(pkA[smp*16 + c], ws[OFF_PW2 + t*16 + c], a);
    pkB[smp*16 + t] = a;
  } else if (t >= 64 && t < 96){
    const int oo = t - 64;
    float a = ws[OFF_QB + 32 + oo];
    #pragma unroll
    for (int c = 0; c < 32; ++c)
      a = fmaf(fminf(fmaxf(vA[smp*32 + c], 0.0f), QMAXF), ws[OFF_QW + 1024 + oo*32 + c], a);
    vB[smp*32 + oo] = a;
  }
  __syncthreads();

  if (t < 49){
    float a = 0.0f;
    #pragma unroll
    for (int c = 0; c < 16; ++c) a = fmaf(pkB[smp*16 + c], ws[OFF_PQ + t*16 + c], a);
    const int idx = 49152 + (b*2 + smp)*49 + t;
    if (bfl) ((__hip_bfloat16*)outv)[idx] = __float2bfloat16(a);
    else     ((float*)outv)[idx] = a;
  } else if (t >= 64 && t < 96){
    const int oo = t - 64;
    float a = ws[OFF_QB + 64 + oo];
    #pragma unroll
    for (int c = 0; c < 32; ++c)
      a = fmaf(fminf(fmaxf(vB[smp*32 + c], 0.0f), QMAXF), ws[OFF_QW + 2048 + oo*32 + c], a);
    vA[smp*32 + oo] = a;
  }
  __syncthreads();

  if (t < 3){
    float a = ws[OFF_QB4 + t];
    #pragma unroll
    for (int c = 0; c < 32; ++c)
      a = fmaf(fminf(fmaxf(vA[smp*32 + c], 0.0f), QMAXF), ws[OFF_QW4 + t*32 + c], a);
    const int idx = (b*2 + smp)*3 + t;
    if (bfl) ((__hip_bfloat16*)outv)[idx] = __float2bfloat16(a);
    else     ((float*)outv)[idx] = a;
  }
}

extern "C" void kernel_launch(void* const* d_in, const int* in_sizes, int n_in,
                              void* d_out, int out_size, void* d_ws, size_t ws_size,
                              hipStream_t stream)
{
  (void)in_sizes; (void)n_in; (void)out_size; (void)ws_size;
  float* ws = (float*)d_ws;
  prep_kernel<<<256, 256, 0, stream>>>(
      d_in[0],  d_in[1],  d_in[2],  d_in[3],  d_in[4],  d_in[5],  d_in[6],  d_in[7],
      d_in[8],  d_in[9],  d_in[10], d_in[11], d_in[12], d_in[13], d_in[14], d_in[15],
      d_in[16], d_in[17], d_in[18], d_in[19], d_in[20], d_in[21], ws);
  fused_kernel<<<8192, 512, 0, stream>>>(d_in[0], ws, d_out);
}

// Round 8
// 269.317 us; speedup vs baseline: 10.7873x; 1.1226x over previous
//
#include <hip/hip_runtime.h>
#include <hip/hip_bf16.h>

typedef _Float16 f16;
typedef f16 f16x2 __attribute__((ext_vector_type(2)));
typedef f16 f16x8 __attribute__((ext_vector_type(8)));
typedef float f32x4 __attribute__((ext_vector_type(4)));

#define QMAXF (127.0f/128.0f)

// float-slot offsets for fp32 scalar region.
enum {
  OFF_W1 = 153600, OFF_B1 = 154368, OFF_CB = 154496, OFF_LB = 154880,
  OFF_FB = 155136, OFF_PW1 = 155184, OFF_PB1 = 155440, OFF_PW2 = 155456,
  OFF_PB2 = 155712, OFF_PQ = 155728, OFF_QW = 156512, OFF_QB = 159584,
  OFF_QW4 = 159680, OFF_QB4 = 159776, WS_TOTAL = 159779
};
// f16-element offsets inside the weight region.
enum {
  GW_C = 0,            // 3 conv1x1 layers x [16 kseg][128 col][8]
  GW_L = 49152,        // 6 ladder tap-mats x 16384
  GW_F = 147456,       // final 128->48: [16 kseg][48 col][8]
  GW_1 = 153600,       // L1 MFMA B: [4 kseg][128][8], only k=0..5 nonzero
  GW_TOTAL = 157696    // bytes 315392 < scalar region start (614400)
};

__device__ __forceinline__ bool detect_bf16(const void* x){
  const unsigned short* u = (const unsigned short*)x;
  int hits = 0;
  #pragma unroll
  for (int i = 0; i < 32; i += 2){
    unsigned short h = u[i];
    hits += (h >= 0x3800 && h <= 0x3F80) ? 1 : 0;
  }
  return hits >= 12;
}

__device__ __forceinline__ float rd(const void* p, int i, bool bfl){
  return bfl ? __bfloat162float(((const __hip_bfloat16*)p)[i]) : ((const float*)p)[i];
}

// mish(x) = x - 2x/(u(u+2)+2), u = exp(x). No clamp needed: u=inf -> m=inf
// -> rcp=0 -> x (correct limit); u underflow -> m=2 -> x-2x*0.5 = 0 (correct).
__device__ __forceinline__ float mish_f(float x){
  float u = __expf(x);
  float m = fmaf(u, u + 2.0f, 2.0f);
  return fmaf(-2.0f*x, __builtin_amdgcn_rcpf(m), x);
}

__global__ void prep_kernel(const void* x, const void* lw1, const void* lb1, const void* lw23,
                            const void* lb23, const void* cw, const void* cb, const void* cs,
                            const void* ct, const void* cwf, const void* cbf, const void* csf,
                            const void* ctf, const void* pw1, const void* pb1, const void* pw2,
                            const void* pb2, const void* pq, const void* vw, const void* vb,
                            const void* vw4, const void* vb4, float* ws)
{
  const bool bfl = detect_bf16(x);
  f16* wf = (f16*)ws;
  const int t0 = blockIdx.x*blockDim.x + threadIdx.x;
  const int stride = gridDim.x*blockDim.x;

  for (int e = t0; e < GW_TOTAL; e += stride){
    float w;
    if (e < GW_L){
      int l = e >> 14, r = e & 16383;
      int kseg = r >> 10, col = (r >> 3) & 127, j = r & 7, k = kseg*8 + j;
      w = rd(cw, (l*128 + col)*128 + k, bfl) * rd(cs, l*128 + col, bfl);
    } else if (e < GW_F){
      int ee = e - GW_L;
      int lt = ee >> 14, r = ee & 16383;
      int kseg = r >> 10, col = (r >> 3) & 127, j = r & 7, k = kseg*8 + j;
      w = rd(lw23, lt*16384 + col*128 + k, bfl);
    } else if (e < GW_1){
      int ee = e - GW_F;
      int kseg = ee / 384, r = ee % 384, col = r >> 3, j = r & 7, k = kseg*8 + j;
      w = rd(cwf, col*128 + k, bfl) * rd(csf, col, bfl);
    } else {
      // L1 B: [kseg][col][8]; k=(tap<<1)|c for k<6, zero otherwise.
      int ee = e - GW_1;
      int kseg = ee >> 10, col = (ee >> 3) & 127, j = ee & 7;
      w = (kseg == 0 && j < 6) ? rd(lw1, ((j>>1)*128 + col)*2 + (j&1), bfl) : 0.0f;
    }
    wf[e] = (f16)w;
  }

  for (int i = t0; i < 6179; i += stride){
    float v; int s = i;
    if (s < 768){ int tap = s>>8, r = s&255, c = r>>7, o = r&127; v = rd(lw1,(tap*128+o)*2+c,bfl); }
    else if (s < 896){ v = rd(lb1, s-768, bfl); }
    else if (s < 1280){ int idx = s-896; v = rd(cb,idx,bfl)*rd(cs,idx,bfl)+rd(ct,idx,bfl); }
    else if (s < 1536){ v = rd(lb23, s-1280, bfl); }
    else if (s < 1584){ int m = s-1536; v = rd(cbf,m,bfl)*rd(csf,m,bfl)+rd(ctf,m,bfl); }
    else if (s < 1840){ v = rd(pw1, s-1584, bfl); }
    else if (s < 1856){ v = rd(pb1, s-1840, bfl); }
    else if (s < 2112){ v = rd(pw2, s-1856, bfl); }
    else if (s < 2128){ v = rd(pb2, s-2112, bfl); }
    else if (s < 2912){ v = rd(pq, s-2128, bfl); }
    else if (s < 5984){ float w = rd(vw, s-2912, bfl); w = fminf(fmaxf(w,-1.f),QMAXF); v = rintf(w*128.f)*0.0078125f; }
    else if (s < 6080){ v = rintf(rd(vb, s-5984, bfl)*16384.f)*6.103515625e-05f; }
    else if (s < 6176){ float w = rd(vw4, s-6080, bfl); w = fminf(fmaxf(w,-1.f),QMAXF); v = rintf(w*128.f)*0.0078125f; }
    else { v = rintf(rd(vb4, s-6176, bfl)*16384.f)*6.103515625e-05f; }
    ws[153600 + i] = v;
  }
}

// 2-sample row maps (row index within the activation matrix).
template<int LMAP>
__device__ __forceinline__ int map_row2(int ro, int tap){
  if (LMAP == 0) return ro;
  if (LMAP == 1){
    int smp = ro >> 5, w = ro & 31, g = w >> 2, p = w & 3;
    return smp*72 + g*9 + (p>>1)*3 + (p&1) + (tap==0 ? 0 : (tap==1 ? 3 : 4));
  }
  int smp = ro >> 3, g = ro & 7;
  return smp*32 + g*4 + (tap==0 ? 0 : (tap==1 ? 2 : 3));
}

// Activation layout: [16 kseg-planes][M+2 rows][8 f16], purely affine.

// 8 waves, wave wv owns cols [wv*16, wv*16+16). Exact M tiling, no guards.
template<int MTILES, int MSRC, int MDST, int TAPS, int LMAP>
__device__ __forceinline__ void mfma_layer(const f16* __restrict__ wf, int wbase,
                                           const float* __restrict__ ws, int boff,
                                           const f16* src, f16* dst, int lane, int wv)
{
  const int lr = lane & 15;
  const int lk = lane >> 4;
  const int c0 = wv*16 + lr;
  constexpr int SS = MSRC + 2;
  constexpr int SD = MDST + 2;

  const f16* srck = src + lk*SS*8;                       // per-thread base
  f16* dstw = dst + ((c0>>3)*SD + lk*4)*8 + (c0&7);      // per-thread base

  f32x4 acc[MTILES];
  const float bb = ws[boff + c0];
  #pragma unroll
  for (int mt = 0; mt < MTILES; ++mt) acc[mt] = (f32x4){bb, bb, bb, bb};

  #pragma unroll
  for (int tap = 0; tap < TAPS; ++tap){
    int rowoff[MTILES];
    #pragma unroll
    for (int mt = 0; mt < MTILES; ++mt)
      rowoff[mt] = map_row2<LMAP>(mt*16 + lr, tap) * 8;

    const f16* whk = wf + wbase + tap*16384 + (lk*128 + c0)*8;

    #pragma unroll
    for (int s = 0; s < 4; ++s){
      f16x8 bh = *(const f16x8*)(whk + s*4096);
      #pragma unroll
      for (int mt = 0; mt < MTILES; ++mt){
        f16x8 ah = *(const f16x8*)(srck + s*4*SS*8 + rowoff[mt]);
        acc[mt] = __builtin_amdgcn_mfma_f32_16x16x32_f16(ah, bh, acc[mt], 0, 0, 0);
      }
    }
  }

  #pragma unroll
  for (int mt = 0; mt < MTILES; ++mt)
    #pragma unroll
    for (int r = 0; r < 4; ++r)
      dstw[(mt*16 + r)*8] = (f16)mish_f(acc[mt][r]);   // static ds offsets
}

__global__ __launch_bounds__(512, 4)
void fused_kernel(const void* __restrict__ xv, const float* __restrict__ ws, void* __restrict__ outv)
{
  // [16][146][8] f16 = 36.5 KB each; 73 KB total -> 2 blocks/CU.
  // Scratch aliases dead buffer regions (separated by __syncthreads):
  //   bufB alias: xraw(196f) + A_L1[144][8] f16 @ +400 — dead once CH1 writes bufB
  //   bufA alias: qbuf..vC — live only after CH3 consumed bufA
  __shared__ __align__(16) f16 bufA[18688];
  __shared__ __align__(16) f16 bufB[18688];

  float* xraw = (float*)bufB;                 // [2][98]
  f16*   a1   = bufB + 400;                   // [144][8] L1 MFMA A-plane
  float* qbuf = (float*)bufA;                 // [16][48]
  float* featL= (float*)bufA + 768;           // [2][48]
  float* pkA  = (float*)bufA + 864;           // [2][16]
  float* pkB  = (float*)bufA + 896;           // [2][16]
  float* vA   = (float*)bufA + 928;           // [2][32]
  float* vB   = (float*)bufA + 992;           // [2][32]
  float* vC   = (float*)bufA + 1056;          // [2][32]

  const int tid  = threadIdx.x;
  const int lane = tid & 63;
  const int wv   = tid >> 6;                  // 0..7
  const int b    = blockIdx.x;                // 2 samples: b*2, b*2+1
  const bool bfl = detect_bf16(xv);
  const f16* wf  = (const f16*)ws;

  if (tid < 196){
    int smp = tid >= 98 ? 1 : 0;
    int q = tid - 98*smp;
    xraw[smp*98 + q] = rd(xv, (b*2 + smp)*98 + q, bfl);
  }
  __syncthreads();

  // Build A_L1[row=(smp,g,i,j)][k=(tap,c)] directly from xraw with the
  // rotation math. 1152 f16 as 576 f16x2 pairs; kh=3 -> zero pad (k=6,7).
  for (int e2 = tid; e2 < 576; e2 += 512){
    const int row = e2 >> 2, kh = e2 & 3;
    f16x2 hv = (f16x2){(f16)0.f, (f16)0.f};
    if (kh < 3){
      const int smp = row >= 72 ? 1 : 0;
      const int rr = row - 72*smp;
      const int g = (rr*57) >> 9;            // rr/9 for rr<72
      const int q = rr - 9*g;
      const int i = (q*11) >> 5;             // q/3 for q<9
      const int j = q - 3*i;
      const int ri = i + (kh >= 1), rj = j + (kh == 2);   // tap = kh
      const int kk = (0x13023120u >> (g*4)) & 0xF;
      const int y0 = (g >= 4) ? 3 : 0;
      const int x0 = (g >= 2 && g <= 5) ? 3 : 0;
      int sy, sx;
      if      (kk == 0){ sy = ri;     sx = rj;     }
      else if (kk == 1){ sy = rj;     sx = 3 - ri; }
      else if (kk == 2){ sy = 3 - ri; sx = 3 - rj; }
      else             { sy = 3 - rj; sx = ri;     }
      const int base = smp*98 + (y0 + sy)*7 + (x0 + sx);
      hv[0] = (f16)xraw[base];        // c=0
      hv[1] = (f16)xraw[base + 49];   // c=1
    }
    *(f16x2*)(a1 + row*8 + kh*2) = hv;
  }
  __syncthreads();

  // L1 as MFMA: B has zeros for k>=6 and ksegs 1-3, so lanes lk>=1 may read
  // any A data (broadcast plane 0) — their products are exactly zero.
  {
    const int lr = lane & 15, lk = lane >> 4;
    const int c0 = wv*16 + lr;
    const f16x8 bh = *(const f16x8*)(wf + GW_1 + (lk*128 + c0)*8);
    const float bb = ws[OFF_B1 + c0];
    f16* dstw = bufA + ((c0>>3)*146 + lk*4)*8 + (c0&7);
    f32x4 acc[9];
    #pragma unroll
    for (int mt = 0; mt < 9; ++mt) acc[mt] = (f32x4){bb, bb, bb, bb};
    #pragma unroll
    for (int mt = 0; mt < 9; ++mt){
      f16x8 ah = *(const f16x8*)(a1 + (mt*16 + lr)*8);
      acc[mt] = __builtin_amdgcn_mfma_f32_16x16x32_f16(ah, bh, acc[mt], 0, 0, 0);
    }
    #pragma unroll
    for (int mt = 0; mt < 9; ++mt)
      #pragma unroll
      for (int r = 0; r < 4; ++r)
        dstw[(mt*16 + r)*8] = (f16)mish_f(acc[mt][r]);
  }
  __syncthreads();

  mfma_layer<9,144,144,1,0>(wf, GW_C,          ws, OFF_CB,       bufA, bufB, lane, wv);
  __syncthreads();
  mfma_layer<4,144, 64,3,1>(wf, GW_L,          ws, OFF_LB,       bufB, bufA, lane, wv);
  __syncthreads();
  mfma_layer<4, 64, 64,1,0>(wf, GW_C + 16384,  ws, OFF_CB + 128, bufA, bufB, lane, wv);
  __syncthreads();
  mfma_layer<1, 64, 16,3,2>(wf, GW_L + 49152,  ws, OFF_LB + 128, bufB, bufA, lane, wv);
  __syncthreads();
  mfma_layer<1, 16, 16,1,0>(wf, GW_C + 32768,  ws, OFF_CB + 256, bufA, bufB, lane, wv);
  __syncthreads();

  // final 128->48 (no act) + fake_quant; waves 0..2, 16 rows = 2 samples exact
  if (wv < 3){
    const int lr = lane & 15, lk = lane >> 4;
    const int col = wv*16 + lr;
    const float bb = ws[OFF_FB + col];
    const f16* srck = bufB + lk*18*8 + lr*8;
    f32x4 a1acc = (f32x4){bb, bb, bb, bb};
    #pragma unroll
    for (int s = 0; s < 4; ++s){
      f16x8 af = *(const f16x8*)(srck + s*4*18*8);
      f16x8 bh = *(const f16x8*)(wf + GW_F + ((4*s + lk)*48 + col)*8);
      a1acc = __builtin_amdgcn_mfma_f32_16x16x32_f16(af, bh, a1acc, 0, 0, 0);
    }
    #pragma unroll
    for (int r = 0; r < 4; ++r){
      const int row = lk*4 + r;                    // 0..15 = smp*8+g
      float h = fminf(fmaxf(a1acc[r], -1.0f), QMAXF);
      qbuf[row*48 + col] = rintf(h * 128.0f) * 0.0078125f;
    }
  }
  __syncthreads();

  // Heads: wave-local chains (producer/consumer within one wave => in-order
  // LDS + compiler lgkmcnt, no barriers). wv0/1: policy smp0/1; wv2/3: value.
  if (wv < 4){
    const int hsmp = wv & 1;
    const int bi = b*2 + hsmp;
    if (wv < 2){
      if (lane < 16){
        float f = 0.f;
        #pragma unroll
        for (int g = 0; g < 8; ++g) f += qbuf[(hsmp*8 + g)*48 + lane];
        featL[hsmp*48 + lane] = f;
      }
      if (lane < 16){
        float a = ws[OFF_PB1 + lane];
        #pragma unroll
        for (int c = 0; c < 16; ++c) a = fmaf(featL[hsmp*48 + c], ws[OFF_PW1 + lane*16 + c], a);
        pkA[hsmp*16 + lane] = fmaxf(a, 0.0f);
      }
      if (lane < 16){
        float a = ws[OFF_PB2 + lane];
        #pragma unroll
        for (int c = 0; c < 16; ++c) a = fmaf(pkA[hsmp*16 + c], ws[OFF_PW2 + lane*16 + c], a);
        pkB[hsmp*16 + lane] = a;
      }
      if (lane < 49){
        float a = 0.0f;
        #pragma unroll
        for (int c = 0; c < 16; ++c) a = fmaf(pkB[hsmp*16 + c], ws[OFF_PQ + lane*16 + c], a);
        const int idx = 49152 + bi*49 + lane;
        if (bfl) ((__hip_bfloat16*)outv)[idx] = __float2bfloat16(a);
        else     ((float*)outv)[idx] = a;
      }
    } else {
      if (lane < 32){
        float f = 0.f;
        #pragma unroll
        for (int g = 0; g < 8; ++g) f += qbuf[(hsmp*8 + g)*48 + 16 + lane];
        featL[hsmp*48 + 16 + lane] = f;
      }
      if (lane < 32){
        float a = ws[OFF_QB + lane];
        #pragma unroll
        for (int c = 0; c < 32; ++c)
          a = fmaf(fminf(fmaxf(featL[hsmp*48 + 16 + c], 0.0f), QMAXF), ws[OFF_QW + lane*32 + c], a);
        vA[hsmp*32 + lane] = a;
      }
      if (lane < 32){
        float a = ws[OFF_QB + 32 + lane];
        #pragma unroll
        for (int c = 0; c < 32; ++c)
          a = fmaf(fminf(fmaxf(vA[hsmp*32 + c], 0.0f), QMAXF), ws[OFF_QW + 1024 + lane*32 + c], a);
        vB[hsmp*32 + lane] = a;
      }
      if (lane < 32){
        float a = ws[OFF_QB + 64 + lane];
        #pragma unroll
        for (int c = 0; c < 32; ++c)
          a = fmaf(fminf(fmaxf(vB[hsmp*32 + c], 0.0f), QMAXF), ws[OFF_QW + 2048 + lane*32 + c], a);
        vC[hsmp*32 + lane] = a;
      }
      if (lane < 3){
        float a = ws[OFF_QB4 + lane];
        #pragma unroll
        for (int c = 0; c < 32; ++c)
          a = fmaf(fminf(fmaxf(vC[hsmp*32 + c], 0.0f), QMAXF), ws[OFF_QW4 + lane*32 + c], a);
        const int idx = bi*3 + lane;
        if (bfl) ((__hip_bfloat16*)outv)[idx] = __float2bfloat16(a);
        else     ((float*)outv)[idx] = a;
      }
    }
  }
}

extern "C" void kernel_launch(void* const* d_in, const int* in_sizes, int n_in,
                              void* d_out, int out_size, void* d_ws, size_t ws_size,
                              hipStream_t stream)
{
  (void)in_sizes; (void)n_in; (void)out_size; (void)ws_size;
  float* ws = (float*)d_ws;
  prep_kernel<<<256, 256, 0, stream>>>(
      d_in[0],  d_in[1],  d_in[2],  d_in[3],  d_in[4],  d_in[5],  d_in[6],  d_in[7],
      d_in[8],  d_in[9],  d_in[10], d_in[11], d_in[12], d_in[13], d_in[14], d_in[15],
      d_in[16], d_in[17], d_in[18], d_in[19], d_in[20], d_in[21], ws);
  fused_kernel<<<8192, 512, 0, stream>>>(d_in[0], ws, d_out);
}

// Round 10
// 257.292 us; speedup vs baseline: 11.2915x; 1.0467x over previous
//
#include <hip/hip_runtime.h>
#include <hip/hip_bf16.h>

typedef _Float16 f16;
typedef f16 f16x2 __attribute__((ext_vector_type(2)));
typedef f16 f16x8 __attribute__((ext_vector_type(8)));
typedef float f32x4 __attribute__((ext_vector_type(4)));

#define QMAXF (127.0f/128.0f)

// float-slot offsets for fp32 scalar region (round-8 numerics, unscaled).
enum {
  OFF_W1 = 153600, OFF_B1 = 154368, OFF_CB = 154496, OFF_LB = 154880,
  OFF_FB = 155136, OFF_PW1 = 155184, OFF_PB1 = 155440, OFF_PW2 = 155456,
  OFF_PB2 = 155712, OFF_PQ = 155728, OFF_QW = 156512, OFF_QB = 159584,
  OFF_QW4 = 159680, OFF_QB4 = 159776, WS_TOTAL = 159779
};
// f16-element offsets inside the weight region.
enum {
  GW_C = 0,            // 3 conv1x1 layers x [16 kseg][128 col][8]
  GW_L = 49152,        // 6 ladder tap-mats x 16384
  GW_F = 147456,       // final 128->48: [16 kseg][48 col][8]
  GW_1 = 153600,       // L1 MFMA B: [4 kseg][128][8], k=0..5 nonzero
  GW_TOTAL = 157696
};

__device__ __forceinline__ bool detect_bf16(const void* x){
  const unsigned short* u = (const unsigned short*)x;
  int hits = 0;
  #pragma unroll
  for (int i = 0; i < 32; i += 2){
    unsigned short h = u[i];
    hits += (h >= 0x3800 && h <= 0x3F80) ? 1 : 0;
  }
  return hits >= 12;
}

__device__ __forceinline__ float rd(const void* p, int i, bool bfl){
  return bfl ? __bfloat162float(((const __hip_bfloat16*)p)[i]) : ((const float*)p)[i];
}

// mish(x) = x - 2x/(u(u+2)+2), u = exp(x). Round-8 known-good form.
__device__ __forceinline__ float mish_f(float x){
  float u = __expf(x);
  float m = fmaf(u, u + 2.0f, 2.0f);
  return fmaf(-2.0f*x, __builtin_amdgcn_rcpf(m), x);
}

__global__ void prep_kernel(const void* x, const void* lw1, const void* lb1, const void* lw23,
                            const void* lb23, const void* cw, const void* cb, const void* cs,
                            const void* ct, const void* cwf, const void* cbf, const void* csf,
                            const void* ctf, const void* pw1, const void* pb1, const void* pw2,
                            const void* pb2, const void* pq, const void* vw, const void* vb,
                            const void* vw4, const void* vb4, float* ws)
{
  const bool bfl = detect_bf16(x);
  f16* wf = (f16*)ws;
  const int t0 = blockIdx.x*blockDim.x + threadIdx.x;
  const int stride = gridDim.x*blockDim.x;

  for (int e = t0; e < GW_TOTAL; e += stride){
    float w;
    if (e < GW_L){
      int l = e >> 14, r = e & 16383;
      int kseg = r >> 10, col = (r >> 3) & 127, j = r & 7, k = kseg*8 + j;
      w = rd(cw, (l*128 + col)*128 + k, bfl) * rd(cs, l*128 + col, bfl);
    } else if (e < GW_F){
      int ee = e - GW_L;
      int lt = ee >> 14, r = ee & 16383;
      int kseg = r >> 10, col = (r >> 3) & 127, j = r & 7, k = kseg*8 + j;
      w = rd(lw23, lt*16384 + col*128 + k, bfl);
    } else if (e < GW_1){
      int ee = e - GW_F;
      int kseg = ee / 384, r = ee % 384, col = r >> 3, j = r & 7, k = kseg*8 + j;
      w = rd(cwf, col*128 + k, bfl) * rd(csf, col, bfl);
    } else {
      // L1 B: [kseg][col][8]; k=(tap<<1)|c for k<6, zero otherwise.
      int ee = e - GW_1;
      int kseg = ee >> 10, col = (ee >> 3) & 127, j = ee & 7;
      w = (kseg == 0 && j < 6) ? rd(lw1, ((j>>1)*128 + col)*2 + (j&1), bfl) : 0.0f;
    }
    wf[e] = (f16)w;
  }

  for (int i = t0; i < 6179; i += stride){
    float v; int s = i;
    if (s < 768){ int tap = s>>8, r = s&255, c = r>>7, o = r&127; v = rd(lw1,(tap*128+o)*2+c,bfl); }
    else if (s < 896){ v = rd(lb1, s-768, bfl); }
    else if (s < 1280){ int idx = s-896; v = rd(cb,idx,bfl)*rd(cs,idx,bfl)+rd(ct,idx,bfl); }
    else if (s < 1536){ v = rd(lb23, s-1280, bfl); }
    else if (s < 1584){ int m = s-1536; v = rd(cbf,m,bfl)*rd(csf,m,bfl)+rd(ctf,m,bfl); }
    else if (s < 1840){ v = rd(pw1, s-1584, bfl); }
    else if (s < 1856){ v = rd(pb1, s-1840, bfl); }
    else if (s < 2112){ v = rd(pw2, s-1856, bfl); }
    else if (s < 2128){ v = rd(pb2, s-2112, bfl); }
    else if (s < 2912){ v = rd(pq, s-2128, bfl); }
    else if (s < 5984){ float w = rd(vw, s-2912, bfl); w = fminf(fmaxf(w,-1.f),QMAXF); v = rintf(w*128.f)*0.0078125f; }
    else if (s < 6080){ v = rintf(rd(vb, s-5984, bfl)*16384.f)*6.103515625e-05f; }
    else if (s < 6176){ float w = rd(vw4, s-6080, bfl); w = fminf(fmaxf(w,-1.f),QMAXF); v = rintf(w*128.f)*0.0078125f; }
    else { v = rintf(rd(vb4, s-6176, bfl)*16384.f)*6.103515625e-05f; }
    ws[153600 + i] = v;
  }
}

// 2-sample row maps (absolute row index within the 144-row activation matrix).
template<int LMAP>
__device__ __forceinline__ int map_row2(int ro, int tap){
  if (LMAP == 0) return ro;
  if (LMAP == 1){
    int smp = ro >> 5, w = ro & 31, g = w >> 2, p = w & 3;
    return smp*72 + g*9 + (p>>1)*3 + (p&1) + (tap==0 ? 0 : (tap==1 ? 3 : 4));
  }
  int smp = ro >> 3, g = ro & 7;
  return smp*32 + g*4 + (tap==0 ? 0 : (tap==1 ? 2 : 3));
}

// Single in-place activation buffer: [16 kseg-planes][146 rows][8 f16].
// Every layer reads ALL its inputs before its internal barrier, then writes.
// Read-row-set vs write-row-set is disjoint-or-equal per pass:
//   conv passes (LMAP0): reads rows [ROW0,ROW0+16*MT) == writes (safe in-place)
//   ladders: writes subset of reads, separated by the internal barrier.
#define BS 146   // plane stride in rows (even => plane step = 8 banks mod 32)

template<int MTILES, int ROW0, int TAPS, int LMAP>
__device__ __forceinline__ void layer_ip(const f16* __restrict__ wf, int wbase,
                                         const float* __restrict__ ws, int boff,
                                         f16* buf, int lane, int wv)
{
  const int lr = lane & 15;
  const int lk = lane >> 4;
  const int c0 = wv*16 + lr;

  const f16* srck = buf + lk*BS*8;                             // per-thread base
  f16* dstw = buf + ((c0>>3)*BS + ROW0 + lk*4)*8 + (c0&7);     // per-thread base

  f32x4 acc[MTILES];
  const float bb = ws[boff + c0];
  #pragma unroll
  for (int mt = 0; mt < MTILES; ++mt) acc[mt] = (f32x4){bb, bb, bb, bb};

  #pragma unroll
  for (int tap = 0; tap < TAPS; ++tap){
    int rowoff[MTILES];
    #pragma unroll
    for (int mt = 0; mt < MTILES; ++mt)
      rowoff[mt] = map_row2<LMAP>(ROW0 + mt*16 + lr, tap) * 8;

    const f16* whk = wf + wbase + tap*16384 + (lk*128 + c0)*8;

    #pragma unroll
    for (int s = 0; s < 4; ++s){
      f16x8 bh = *(const f16x8*)(whk + s*4096);
      #pragma unroll
      for (int mt = 0; mt < MTILES; ++mt){
        f16x8 ah = *(const f16x8*)(srck + s*4*BS*8 + rowoff[mt]);
        acc[mt] = __builtin_amdgcn_mfma_f32_16x16x32_f16(ah, bh, acc[mt], 0, 0, 0);
      }
    }
  }

  __syncthreads();   // all waves' reads complete before any write lands

  #pragma unroll
  for (int mt = 0; mt < MTILES; ++mt)
    #pragma unroll
    for (int r = 0; r < 4; ++r)
      dstw[(mt*16 + r)*8] = (f16)mish_f(acc[mt][r]);   // static ds offsets
}

__global__ __launch_bounds__(512, 6)
void fused_kernel(const void* __restrict__ xv, const float* __restrict__ ws, void* __restrict__ outv)
{
  // One 36.5 KB activation buffer + 4.4 KB scratch = ~41 KB -> 3 blocks/CU.
  __shared__ __align__(16) f16 buf[16*BS*8];
  __shared__ __align__(16) float scratch[1120];

  f16*   a1   = (f16*)scratch;                // [144][8] f16, dead before qbuf
  float* qbuf = scratch;                      // [16][48]
  float* featL= scratch + 768;                // [2][48]
  float* pkA  = scratch + 864;                // [2][16]
  float* pkB  = scratch + 896;                // [2][16]
  float* vA   = scratch + 928;                // [2][32]
  float* vB   = scratch + 992;                // [2][32]
  float* vC   = scratch + 1056;               // [2][32]

  const int tid  = threadIdx.x;
  const int lane = tid & 63;
  const int wv   = tid >> 6;                  // 0..7
  const int b    = blockIdx.x;                // 2 samples: b*2, b*2+1
  const bool bfl = detect_bf16(xv);
  const f16* wf  = (const f16*)ws;

  // Build A_L1[row=(smp,g,i,j)][k=(tap,c)] directly from global x.
  for (int e2 = tid; e2 < 576; e2 += 512){
    const int row = e2 >> 2, kh = e2 & 3;
    f16x2 hv = (f16x2){(f16)0.f, (f16)0.f};
    if (kh < 3){
      const int smp = row >= 72 ? 1 : 0;
      const int rr = row - 72*smp;
      const int g = (rr*57) >> 9;            // rr/9 for rr<72
      const int q = rr - 9*g;
      const int i = (q*11) >> 5;             // q/3 for q<9
      const int j = q - 3*i;
      const int ri = i + (kh >= 1), rj = j + (kh == 2);   // tap = kh
      const int kk = (0x13023120u >> (g*4)) & 0xF;
      const int y0 = (g >= 4) ? 3 : 0;
      const int x0 = (g >= 2 && g <= 5) ? 3 : 0;
      int sy, sx;
      if      (kk == 0){ sy = ri;     sx = rj;     }
      else if (kk == 1){ sy = rj;     sx = 3 - ri; }
      else if (kk == 2){ sy = 3 - ri; sx = 3 - rj; }
      else             { sy = 3 - rj; sx = ri;     }
      const int gi = (b*2 + smp)*98 + (y0 + sy)*7 + (x0 + sx);
      hv[0] = (f16)rd(xv, gi, bfl);        // c=0
      hv[1] = (f16)rd(xv, gi + 49, bfl);   // c=1
    }
    *(f16x2*)(a1 + row*8 + kh*2) = hv;
  }
  __syncthreads();

  // L1 as MFMA (reads a1 in scratch, writes buf rows 0..143): B is zero for
  // k>=6 and ksegs 1..3, so lanes lk>=1 broadcast-read plane-0 A; products 0.
  {
    const int lr = lane & 15, lk = lane >> 4;
    const int c0 = wv*16 + lr;
    const f16x8 bh = *(const f16x8*)(wf + GW_1 + (lk*128 + c0)*8);
    const float bb = ws[OFF_B1 + c0];
    f16* dstw = buf + ((c0>>3)*BS + lk*4)*8 + (c0&7);
    f32x4 acc[9];
    #pragma unroll
    for (int mt = 0; mt < 9; ++mt) acc[mt] = (f32x4){bb, bb, bb, bb};
    #pragma unroll
    for (int mt = 0; mt < 9; ++mt){
      f16x8 ah = *(const f16x8*)(a1 + (mt*16 + lr)*8);
      acc[mt] = __builtin_amdgcn_mfma_f32_16x16x32_f16(ah, bh, acc[mt], 0, 0, 0);
    }
    #pragma unroll
    for (int mt = 0; mt < 9; ++mt)
      #pragma unroll
      for (int r = 0; r < 4; ++r)
        dstw[(mt*16 + r)*8] = (f16)mish_f(acc[mt][r]);
  }
  __syncthreads();

  // CH1 (144->144, K=128) split into two in-place row passes (reg pressure).
  layer_ip<5,  0, 1, 0>(wf, GW_C,         ws, OFF_CB,       buf, lane, wv);
  layer_ip<4, 80, 1, 0>(wf, GW_C,         ws, OFF_CB,       buf, lane, wv);
  __syncthreads();
  layer_ip<4,  0, 3, 1>(wf, GW_L,         ws, OFF_LB,       buf, lane, wv);   // L2: 144->64
  __syncthreads();
  layer_ip<4,  0, 1, 0>(wf, GW_C + 16384, ws, OFF_CB + 128, buf, lane, wv);   // CH2: 64->64
  __syncthreads();
  layer_ip<1,  0, 3, 2>(wf, GW_L + 49152, ws, OFF_LB + 128, buf, lane, wv);   // L3: 64->16
  __syncthreads();
  layer_ip<1,  0, 1, 0>(wf, GW_C + 32768, ws, OFF_CB + 256, buf, lane, wv);   // CH3: 16->16
  __syncthreads();

  // final 128->48 (no act) + fake_quant into qbuf; waves 0..2 (48 cols).
  // Reads buf rows 0..15; writes scratch (disjoint) -> no internal barrier.
  if (wv < 3){
    const int lr = lane & 15, lk = lane >> 4;
    const int col = wv*16 + lr;
    const float bb = ws[OFF_FB + col];
    const f16* srck = buf + (lk*BS + lr)*8;
    f32x4 fa = (f32x4){bb, bb, bb, bb};
    #pragma unroll
    for (int s = 0; s < 4; ++s){
      f16x8 af = *(const f16x8*)(srck + s*4*BS*8);
      f16x8 bh = *(const f16x8*)(wf + GW_F + ((4*s + lk)*48 + col)*8);
      fa = __builtin_amdgcn_mfma_f32_16x16x32_f16(af, bh, fa, 0, 0, 0);
    }
    #pragma unroll
    for (int r = 0; r < 4; ++r){
      const int row = lk*4 + r;                    // 0..15 = smp*8+g
      float h = fminf(fmaxf(fa[r], -1.0f), QMAXF);
      qbuf[row*48 + col] = rintf(h * 128.0f) * 0.0078125f;
    }
  }
  __syncthreads();

  // Heads: wave-local chains (producer/consumer within one wave => in-order
  // LDS, no barriers). wv0/1: policy smp0/1; wv2/3: value smp0/1.
  if (wv < 4){
    const int hsmp = wv & 1;
    const int bi = b*2 + hsmp;
    if (wv < 2){
      if (lane < 16){
        float f = 0.f;
        #pragma unroll
        for (int g = 0; g < 8; ++g) f += qbuf[(hsmp*8 + g)*48 + lane];
        featL[hsmp*48 + lane] = f;
      }
      if (lane < 16){
        float a = ws[OFF_PB1 + lane];
        #pragma unroll
        for (int c = 0; c < 16; ++c) a = fmaf(featL[hsmp*48 + c], ws[OFF_PW1 + lane*16 + c], a);
        pkA[hsmp*16 + lane] = fmaxf(a, 0.0f);
      }
      if (lane < 16){
        float a = ws[OFF_PB2 + lane];
        #pragma unroll
        for (int c = 0; c < 16; ++c) a = fmaf(pkA[hsmp*16 + c], ws[OFF_PW2 + lane*16 + c], a);
        pkB[hsmp*16 + lane] = a;
      }
      if (lane < 49){
        float a = 0.0f;
        #pragma unroll
        for (int c = 0; c < 16; ++c) a = fmaf(pkB[hsmp*16 + c], ws[OFF_PQ + lane*16 + c], a);
        const int idx = 49152 + bi*49 + lane;
        if (bfl) ((__hip_bfloat16*)outv)[idx] = __float2bfloat16(a);
        else     ((float*)outv)[idx] = a;
      }
    } else {
      if (lane < 32){
        float f = 0.f;
        #pragma unroll
        for (int g = 0; g < 8; ++g) f += qbuf[(hsmp*8 + g)*48 + 16 + lane];
        featL[hsmp*48 + 16 + lane] = f;
      }
      if (lane < 32){
        float a = ws[OFF_QB + lane];
        #pragma unroll
        for (int c = 0; c < 32; ++c)
          a = fmaf(fminf(fmaxf(featL[hsmp*48 + 16 + c], 0.0f), QMAXF), ws[OFF_QW + lane*32 + c], a);
        vA[hsmp*32 + lane] = a;
      }
      if (lane < 32){
        float a = ws[OFF_QB + 32 + lane];
        #pragma unroll
        for (int c = 0; c < 32; ++c)
          a = fmaf(fminf(fmaxf(vA[hsmp*32 + c], 0.0f), QMAXF), ws[OFF_QW + 1024 + lane*32 + c], a);
        vB[hsmp*32 + lane] = a;
      }
      if (lane < 32){
        float a = ws[OFF_QB + 64 + lane];
        #pragma unroll
        for (int c = 0; c < 32; ++c)
          a = fmaf(fminf(fmaxf(vB[hsmp*32 + c], 0.0f), QMAXF), ws[OFF_QW + 2048 + lane*32 + c], a);
        vC[hsmp*32 + lane] = a;
      }
      if (lane < 3){
        float a = ws[OFF_QB4 + lane];
        #pragma unroll
        for (int c = 0; c < 32; ++c)
          a = fmaf(fminf(fmaxf(vC[hsmp*32 + c], 0.0f), QMAXF), ws[OFF_QW4 + lane*32 + c], a);
        const int idx = bi*3 + lane;
        if (bfl) ((__hip_bfloat16*)outv)[idx] = __float2bfloat16(a);
        else     ((float*)outv)[idx] = a;
      }
    }
  }
}

extern "C" void kernel_launch(void* const* d_in, const int* in_sizes, int n_in,
                              void* d_out, int out_size, void* d_ws, size_t ws_size,
                              hipStream_t stream)
{
  (void)in_sizes; (void)n_in; (void)out_size; (void)ws_size;
  float* ws = (float*)d_ws;
  prep_kernel<<<256, 256, 0, stream>>>(
      d_in[0],  d_in[1],  d_in[2],  d_in[3],  d_in[4],  d_in[5],  d_in[6],  d_in[7],
      d_in[8],  d_in[9],  d_in[10], d_in[11], d_in[12], d_in[13], d_in[14], d_in[15],
      d_in[16], d_in[17], d_in[18], d_in[19], d_in[20], d_in[21], ws);
  fused_kernel<<<8192, 512, 0, stream>>>(d_in[0], ws, d_out);
}

// Round 12
// 254.051 us; speedup vs baseline: 11.4355x; 1.0128x over previous
//
#include <hip/hip_runtime.h>
#include <hip/hip_bf16.h>

typedef _Float16 f16;
typedef f16 f16x2 __attribute__((ext_vector_type(2)));
typedef f16 f16x4 __attribute__((ext_vector_type(4)));
typedef f16 f16x8 __attribute__((ext_vector_type(8)));
typedef float f32x4 __attribute__((ext_vector_type(4)));

#define QMAXF (127.0f/128.0f)

// float-slot offsets for fp32 scalar region (round-8 numerics, unscaled).
enum {
  OFF_W1 = 153600, OFF_B1 = 154368, OFF_CB = 154496, OFF_LB = 154880,
  OFF_FB = 155136, OFF_PW1 = 155184, OFF_PB1 = 155440, OFF_PW2 = 155456,
  OFF_PB2 = 155712, OFF_PQ = 155728, OFF_QW = 156512, OFF_QB = 159584,
  OFF_QW4 = 159680, OFF_QB4 = 159776, WS_TOTAL = 159779
};
// f16-element offsets inside the weight region.
enum {
  GW_C = 0,            // 3 conv1x1 layers x [16 kseg][128 col][8]
  GW_L = 49152,        // 6 ladder tap-mats x 16384
  GW_F = 147456,       // final 128->48: [16 kseg][48 col][8]
  GW_1 = 153600,       // L1 MFMA B: [4 kseg][128][8], k=0..5 nonzero
  GW_TOTAL = 157696
};

__device__ __forceinline__ bool detect_bf16(const void* x){
  const unsigned short* u = (const unsigned short*)x;
  int hits = 0;
  #pragma unroll
  for (int i = 0; i < 32; i += 2){
    unsigned short h = u[i];
    hits += (h >= 0x3800 && h <= 0x3F80) ? 1 : 0;
  }
  return hits >= 12;
}

__device__ __forceinline__ float rd(const void* p, int i, bool bfl){
  return bfl ? __bfloat162float(((const __hip_bfloat16*)p)[i]) : ((const float*)p)[i];
}

// mish(x) = x - 2x/(u(u+2)+2), u = exp(x). Round-8 known-good form.
__device__ __forceinline__ float mish_f(float x){
  float u = __expf(x);
  float m = fmaf(u, u + 2.0f, 2.0f);
  return fmaf(-2.0f*x, __builtin_amdgcn_rcpf(m), x);
}

// pack 4 f32 -> 4 contiguous f16 (RTZ via v_cvt_pkrtz). The builtin returns
// __fp16-vectors; bit_cast to our _Float16 vector (identical layout).
__device__ __forceinline__ f16x4 pk4(float a, float b, float c, float d){
  f16x2 lo = __builtin_bit_cast(f16x2, __builtin_amdgcn_cvt_pkrtz(a, b));
  f16x2 hi = __builtin_bit_cast(f16x2, __builtin_amdgcn_cvt_pkrtz(c, d));
  return (f16x4){lo[0], lo[1], hi[0], hi[1]};
}

__global__ void prep_kernel(const void* x, const void* lw1, const void* lb1, const void* lw23,
                            const void* lb23, const void* cw, const void* cb, const void* cs,
                            const void* ct, const void* cwf, const void* cbf, const void* csf,
                            const void* ctf, const void* pw1, const void* pb1, const void* pw2,
                            const void* pb2, const void* pq, const void* vw, const void* vb,
                            const void* vw4, const void* vb4, float* ws)
{
  const bool bfl = detect_bf16(x);
  f16* wf = (f16*)ws;
  const int t0 = blockIdx.x*blockDim.x + threadIdx.x;
  const int stride = gridDim.x*blockDim.x;

  for (int e = t0; e < GW_TOTAL; e += stride){
    float w;
    if (e < GW_L){
      int l = e >> 14, r = e & 16383;
      int kseg = r >> 10, col = (r >> 3) & 127, j = r & 7, k = kseg*8 + j;
      w = rd(cw, (l*128 + col)*128 + k, bfl) * rd(cs, l*128 + col, bfl);
    } else if (e < GW_F){
      int ee = e - GW_L;
      int lt = ee >> 14, r = ee & 16383;
      int kseg = r >> 10, col = (r >> 3) & 127, j = r & 7, k = kseg*8 + j;
      w = rd(lw23, lt*16384 + col*128 + k, bfl);
    } else if (e < GW_1){
      int ee = e - GW_F;
      int kseg = ee / 384, r = ee % 384, col = r >> 3, j = r & 7, k = kseg*8 + j;
      w = rd(cwf, col*128 + k, bfl) * rd(csf, col, bfl);
    } else {
      // L1 B: [kseg][col][8]; k=(tap<<1)|c for k<6, zero otherwise.
      int ee = e - GW_1;
      int kseg = ee >> 10, col = (ee >> 3) & 127, j = ee & 7;
      w = (kseg == 0 && j < 6) ? rd(lw1, ((j>>1)*128 + col)*2 + (j&1), bfl) : 0.0f;
    }
    wf[e] = (f16)w;
  }

  for (int i = t0; i < 6179; i += stride){
    float v; int s = i;
    if (s < 768){ int tap = s>>8, r = s&255, c = r>>7, o = r&127; v = rd(lw1,(tap*128+o)*2+c,bfl); }
    else if (s < 896){ v = rd(lb1, s-768, bfl); }
    else if (s < 1280){ int idx = s-896; v = rd(cb,idx,bfl)*rd(cs,idx,bfl)+rd(ct,idx,bfl); }
    else if (s < 1536){ v = rd(lb23, s-1280, bfl); }
    else if (s < 1584){ int m = s-1536; v = rd(cbf,m,bfl)*rd(csf,m,bfl)+rd(ctf,m,bfl); }
    else if (s < 1840){ v = rd(pw1, s-1584, bfl); }
    else if (s < 1856){ v = rd(pb1, s-1840, bfl); }
    else if (s < 2112){ v = rd(pw2, s-1856, bfl); }
    else if (s < 2128){ v = rd(pb2, s-2112, bfl); }
    else if (s < 2912){ v = rd(pq, s-2128, bfl); }
    else if (s < 5984){ float w = rd(vw, s-2912, bfl); w = fminf(fmaxf(w,-1.f),QMAXF); v = rintf(w*128.f)*0.0078125f; }
    else if (s < 6080){ v = rintf(rd(vb, s-5984, bfl)*16384.f)*6.103515625e-05f; }
    else if (s < 6176){ float w = rd(vw4, s-6080, bfl); w = fminf(fmaxf(w,-1.f),QMAXF); v = rintf(w*128.f)*0.0078125f; }
    else { v = rintf(rd(vb4, s-6176, bfl)*16384.f)*6.103515625e-05f; }
    ws[153600 + i] = v;
  }
}

// 2-sample row maps (absolute row index within the 144-row activation matrix).
template<int LMAP>
__device__ __forceinline__ int map_row2(int ro, int tap){
  if (LMAP == 0) return ro;
  if (LMAP == 1){
    int smp = ro >> 5, w = ro & 31, g = w >> 2, p = w & 3;
    return smp*72 + g*9 + (p>>1)*3 + (p&1) + (tap==0 ? 0 : (tap==1 ? 3 : 4));
  }
  int smp = ro >> 3, g = ro & 7;
  return smp*32 + g*4 + (tap==0 ? 0 : (tap==1 ? 2 : 3));
}

// Single in-place activation buffer: [16 kseg-planes][146 rows][8 f16].
#define BS 146

// Operand-swapped layer: D = mfma(W_frag, Act_frag) -> each thread holds
// 4 CONTIGUOUS out-channels (oc = wv*16 + lk*4 + r) at one position
// (p = nt*16 + lr). All reads are byte-identical to the unswapped version;
// the epilogue becomes cvt_pkrtz x2 + one ds_write_b64 per position-tile.
template<int NTILES, int ROW0, int TAPS, int LMAP>
__device__ __forceinline__ void layer_ip(const f16* __restrict__ wf, int wbase,
                                         const float* __restrict__ ws, int boff,
                                         f16* buf, int lane, int wv)
{
  const int lr = lane & 15;
  const int lk = lane >> 4;
  const int o0 = wv*16;
  const int oc = o0 + lk*4;            // thread's 4 contiguous channels

  const f16* srck = buf + lk*BS*8;                            // act base
  const f16* wbk  = wf + wbase + (lk*128 + o0 + lr)*8;        // weight base
  f16* dstw = buf + ((oc>>3)*BS + ROW0 + lr)*8 + (oc&7);      // store base

  f32x4 acc[NTILES];
  const f32x4 bb = *(const f32x4*)(ws + boff + oc);           // per-channel bias
  #pragma unroll
  for (int nt = 0; nt < NTILES; ++nt) acc[nt] = bb;

  #pragma unroll
  for (int tap = 0; tap < TAPS; ++tap){
    int rowoff[NTILES];
    #pragma unroll
    for (int nt = 0; nt < NTILES; ++nt)
      rowoff[nt] = map_row2<LMAP>(ROW0 + nt*16 + lr, tap) * 8;

    const f16* whk = wbk + tap*16384;

    #pragma unroll
    for (int s = 0; s < 4; ++s){
      f16x8 wa = *(const f16x8*)(whk + s*4096);
      #pragma unroll
      for (int nt = 0; nt < NTILES; ++nt){
        f16x8 ab = *(const f16x8*)(srck + s*4*BS*8 + rowoff[nt]);
        acc[nt] = __builtin_amdgcn_mfma_f32_16x16x32_f16(wa, ab, acc[nt], 0, 0, 0);
      }
    }
  }

  __syncthreads();   // all waves' reads complete before any write lands

  #pragma unroll
  for (int nt = 0; nt < NTILES; ++nt)
    *(f16x4*)(dstw + nt*128) = pk4(mish_f(acc[nt][0]), mish_f(acc[nt][1]),
                                   mish_f(acc[nt][2]), mish_f(acc[nt][3]));
}

__global__ __launch_bounds__(512, 6)
void fused_kernel(const void* __restrict__ xv, const float* __restrict__ ws, void* __restrict__ outv)
{
  // One 36.5 KB activation buffer + 4.4 KB scratch = ~41 KB -> 3 blocks/CU.
  __shared__ __align__(16) f16 buf[16*BS*8];
  __shared__ __align__(16) float scratch[1120];

  f16*   a1   = (f16*)scratch;                // [144][8] f16, dead before qbuf
  float* qbuf = scratch;                      // [16][48]
  float* featL= scratch + 768;                // [2][48]
  float* pkA  = scratch + 864;                // [2][16]
  float* pkB  = scratch + 896;                // [2][16]
  float* vA   = scratch + 928;                // [2][32]
  float* vB   = scratch + 992;                // [2][32]
  float* vC   = scratch + 1056;               // [2][32]

  const int tid  = threadIdx.x;
  const int lane = tid & 63;
  const int wv   = tid >> 6;                  // 0..7
  const int b    = blockIdx.x;                // 2 samples: b*2, b*2+1
  const bool bfl = detect_bf16(xv);
  const f16* wf  = (const f16*)ws;

  // Build A_L1[row=(smp,g,i,j)][k=(tap,c)] directly from global x.
  for (int e2 = tid; e2 < 576; e2 += 512){
    const int row = e2 >> 2, kh = e2 & 3;
    f16x2 hv = (f16x2){(f16)0.f, (f16)0.f};
    if (kh < 3){
      const int smp = row >= 72 ? 1 : 0;
      const int rr = row - 72*smp;
      const int g = (rr*57) >> 9;            // rr/9 for rr<72
      const int q = rr - 9*g;
      const int i = (q*11) >> 5;             // q/3 for q<9
      const int j = q - 3*i;
      const int ri = i + (kh >= 1), rj = j + (kh == 2);   // tap = kh
      const int kk = (0x13023120u >> (g*4)) & 0xF;
      const int y0 = (g >= 4) ? 3 : 0;
      const int x0 = (g >= 2 && g <= 5) ? 3 : 0;
      int sy, sx;
      if      (kk == 0){ sy = ri;     sx = rj;     }
      else if (kk == 1){ sy = rj;     sx = 3 - ri; }
      else if (kk == 2){ sy = 3 - ri; sx = 3 - rj; }
      else             { sy = 3 - rj; sx = ri;     }
      const int gi = (b*2 + smp)*98 + (y0 + sy)*7 + (x0 + sx);
      hv[0] = (f16)rd(xv, gi, bfl);        // c=0
      hv[1] = (f16)rd(xv, gi + 49, bfl);   // c=1
    }
    *(f16x2*)(a1 + row*8 + kh*2) = hv;
  }
  __syncthreads();

  // L1 as swapped MFMA (weights first operand; zeros for k>=6, ksegs 1..3 so
  // act second-operand reads can broadcast plane 0 for all lk).
  {
    const int lr = lane & 15, lk = lane >> 4;
    const int o0 = wv*16, oc = o0 + lk*4;
    const f16x8 wa = *(const f16x8*)(wf + GW_1 + (lk*128 + o0 + lr)*8);
    const f32x4 bb = *(const f32x4*)(ws + OFF_B1 + oc);
    f16* dstw = buf + ((oc>>3)*BS + lr)*8 + (oc&7);
    f32x4 acc[9];
    #pragma unroll
    for (int nt = 0; nt < 9; ++nt) acc[nt] = bb;
    #pragma unroll
    for (int nt = 0; nt < 9; ++nt){
      f16x8 ab = *(const f16x8*)(a1 + (nt*16 + lr)*8);
      acc[nt] = __builtin_amdgcn_mfma_f32_16x16x32_f16(wa, ab, acc[nt], 0, 0, 0);
    }
    #pragma unroll
    for (int nt = 0; nt < 9; ++nt)
      *(f16x4*)(dstw + nt*128) = pk4(mish_f(acc[nt][0]), mish_f(acc[nt][1]),
                                     mish_f(acc[nt][2]), mish_f(acc[nt][3]));
  }
  __syncthreads();

  // CH1 (144->144, K=128) split into two in-place row passes (reg pressure).
  layer_ip<5,  0, 1, 0>(wf, GW_C,         ws, OFF_CB,       buf, lane, wv);
  layer_ip<4, 80, 1, 0>(wf, GW_C,         ws, OFF_CB,       buf, lane, wv);
  __syncthreads();
  layer_ip<4,  0, 3, 1>(wf, GW_L,         ws, OFF_LB,       buf, lane, wv);   // L2: 144->64
  __syncthreads();
  layer_ip<4,  0, 1, 0>(wf, GW_C + 16384, ws, OFF_CB + 128, buf, lane, wv);   // CH2: 64->64
  __syncthreads();
  layer_ip<1,  0, 3, 2>(wf, GW_L + 49152, ws, OFF_LB + 128, buf, lane, wv);   // L3: 64->16
  __syncthreads();
  layer_ip<1,  0, 1, 0>(wf, GW_C + 32768, ws, OFF_CB + 256, buf, lane, wv);   // CH3: 16->16
  __syncthreads();

  // final 128->48 (no act) + fake_quant; waves 0..2 own 48 channels; each
  // thread holds 4 contiguous channels at position p=lr -> float4 qbuf write.
  if (wv < 3){
    const int lr = lane & 15, lk = lane >> 4;
    const int oc = wv*16 + lk*4;
    const f16* srck = buf + (lk*BS + lr)*8;
    const f16* wbk  = wf + GW_F + (lk*48 + wv*16 + lr)*8;
    f32x4 fa = *(const f32x4*)(ws + OFF_FB + oc);
    #pragma unroll
    for (int s = 0; s < 4; ++s){
      f16x8 wa = *(const f16x8*)(wbk + s*1536);
      f16x8 ab = *(const f16x8*)(srck + s*4*BS*8);
      fa = __builtin_amdgcn_mfma_f32_16x16x32_f16(wa, ab, fa, 0, 0, 0);
    }
    f32x4 q;
    #pragma unroll
    for (int r = 0; r < 4; ++r){
      float h = fminf(fmaxf(fa[r], -1.0f), QMAXF);
      q[r] = rintf(h * 128.0f) * 0.0078125f;
    }
    *(f32x4*)(qbuf + lr*48 + oc) = q;       // p = lr = smp*8+g
  }
  __syncthreads();

  // Heads: wave-local chains (producer/consumer within one wave => in-order
  // LDS, no barriers). wv0/1: policy smp0/1; wv2/3: value smp0/1.
  if (wv < 4){
    const int hsmp = wv & 1;
    const int bi = b*2 + hsmp;
    if (wv < 2){
      if (lane < 16){
        float f = 0.f;
        #pragma unroll
        for (int g = 0; g < 8; ++g) f += qbuf[(hsmp*8 + g)*48 + lane];
        featL[hsmp*48 + lane] = f;
      }
      if (lane < 16){
        float a = ws[OFF_PB1 + lane];
        #pragma unroll
        for (int c = 0; c < 16; ++c) a = fmaf(featL[hsmp*48 + c], ws[OFF_PW1 + lane*16 + c], a);
        pkA[hsmp*16 + lane] = fmaxf(a, 0.0f);
      }
      if (lane < 16){
        float a = ws[OFF_PB2 + lane];
        #pragma unroll
        for (int c = 0; c < 16; ++c) a = fmaf(pkA[hsmp*16 + c], ws[OFF_PW2 + lane*16 + c], a);
        pkB[hsmp*16 + lane] = a;
      }
      if (lane < 49){
        float a = 0.0f;
        #pragma unroll
        for (int c = 0; c < 16; ++c) a = fmaf(pkB[hsmp*16 + c], ws[OFF_PQ + lane*16 + c], a);
        const int idx = 49152 + bi*49 + lane;
        if (bfl) ((__hip_bfloat16*)outv)[idx] = __float2bfloat16(a);
        else     ((float*)outv)[idx] = a;
      }
    } else {
      if (lane < 32){
        float f = 0.f;
        #pragma unroll
        for (int g = 0; g < 8; ++g) f += qbuf[(hsmp*8 + g)*48 + 16 + lane];
        featL[hsmp*48 + 16 + lane] = f;
      }
      if (lane < 32){
        float a = ws[OFF_QB + lane];
        #pragma unroll
        for (int c = 0; c < 32; ++c)
          a = fmaf(fminf(fmaxf(featL[hsmp*48 + 16 + c], 0.0f), QMAXF), ws[OFF_QW + lane*32 + c], a);
        vA[hsmp*32 + lane] = a;
      }
      if (lane < 32){
        float a = ws[OFF_QB + 32 + lane];
        #pragma unroll
        for (int c = 0; c < 32; ++c)
          a = fmaf(fminf(fmaxf(vA[hsmp*32 + c], 0.0f), QMAXF), ws[OFF_QW + 1024 + lane*32 + c], a);
        vB[hsmp*32 + lane] = a;
      }
      if (lane < 32){
        float a = ws[OFF_QB + 64 + lane];
        #pragma unroll
        for (int c = 0; c < 32; ++c)
          a = fmaf(fminf(fmaxf(vB[hsmp*32 + c], 0.0f), QMAXF), ws[OFF_QW + 2048 + lane*32 + c], a);
        vC[hsmp*32 + lane] = a;
      }
      if (lane < 3){
        float a = ws[OFF_QB4 + lane];
        #pragma unroll
        for (int c = 0; c < 32; ++c)
          a = fmaf(fminf(fmaxf(vC[hsmp*32 + c], 0.0f), QMAXF), ws[OFF_QW4 + lane*32 + c], a);
        const int idx = bi*3 + lane;
        if (bfl) ((__hip_bfloat16*)outv)[idx] = __float2bfloat16(a);
        else     ((float*)outv)[idx] = a;
      }
    }
  }
}

extern "C" void kernel_launch(void* const* d_in, const int* in_sizes, int n_in,
                              void* d_out, int out_size, void* d_ws, size_t ws_size,
                              hipStream_t stream)
{
  (void)in_sizes; (void)n_in; (void)out_size; (void)ws_size;
  float* ws = (float*)d_ws;
  prep_kernel<<<256, 256, 0, stream>>>(
      d_in[0],  d_in[1],  d_in[2],  d_in[3],  d_in[4],  d_in[5],  d_in[6],  d_in[7],
      d_in[8],  d_in[9],  d_in[10], d_in[11], d_in[12], d_in[13], d_in[14], d_in[15],
      d_in[16], d_in[17], d_in[18], d_in[19], d_in[20], d_in[21], ws);
  fused_kernel<<<8192, 512, 0, stream>>>(d_in[0], ws, d_out);
}

// Round 13
// 249.835 us; speedup vs baseline: 11.6285x; 1.0169x over previous
//
#include <hip/hip_runtime.h>
#include <hip/hip_bf16.h>

typedef _Float16 f16;
typedef f16 f16x2 __attribute__((ext_vector_type(2)));
typedef f16 f16x4 __attribute__((ext_vector_type(4)));
typedef f16 f16x8 __attribute__((ext_vector_type(8)));
typedef float f32x4 __attribute__((ext_vector_type(4)));

#define QMAXF (127.0f/128.0f)

// float-slot offsets for fp32 scalar region (round-8 numerics, unscaled).
enum {
  OFF_W1 = 153600, OFF_B1 = 154368, OFF_CB = 154496, OFF_LB = 154880,
  OFF_FB = 155136, OFF_PW1 = 155184, OFF_PB1 = 155440, OFF_PW2 = 155456,
  OFF_PB2 = 155712, OFF_PQ = 155728, OFF_QW = 156512, OFF_QB = 159584,
  OFF_QW4 = 159680, OFF_QB4 = 159776, WS_TOTAL = 159779
};
// f16-element offsets inside the weight region.
enum {
  GW_C = 0,            // 3 conv1x1 layers x [16 kseg][128 col][8]
  GW_L = 49152,        // 6 ladder tap-mats x 16384
  GW_F = 147456,       // final 128->48: [16 kseg][48 col][8]
  GW_1 = 153600,       // L1 MFMA B: [4 kseg][128][8], k=0..5 nonzero
  GW_TOTAL = 157696
};

__device__ __forceinline__ bool detect_bf16(const void* x){
  const unsigned short* u = (const unsigned short*)x;
  int hits = 0;
  #pragma unroll
  for (int i = 0; i < 32; i += 2){
    unsigned short h = u[i];
    hits += (h >= 0x3800 && h <= 0x3F80) ? 1 : 0;
  }
  return hits >= 12;
}

__device__ __forceinline__ float rd(const void* p, int i, bool bfl){
  return bfl ? __bfloat162float(((const __hip_bfloat16*)p)[i]) : ((const float*)p)[i];
}

// mish(x) = x - 2x/(u(u+2)+2), u = exp(x). Round-8 known-good form.
__device__ __forceinline__ float mish_f(float x){
  float u = __expf(x);
  float m = fmaf(u, u + 2.0f, 2.0f);
  return fmaf(-2.0f*x, __builtin_amdgcn_rcpf(m), x);
}

// pack 4 f32 -> 4 contiguous f16 (RTZ via v_cvt_pkrtz; bit_cast for typing).
__device__ __forceinline__ f16x4 pk4(float a, float b, float c, float d){
  f16x2 lo = __builtin_bit_cast(f16x2, __builtin_amdgcn_cvt_pkrtz(a, b));
  f16x2 hi = __builtin_bit_cast(f16x2, __builtin_amdgcn_cvt_pkrtz(c, d));
  return (f16x4){lo[0], lo[1], hi[0], hi[1]};
}

__global__ void prep_kernel(const void* x, const void* lw1, const void* lb1, const void* lw23,
                            const void* lb23, const void* cw, const void* cb, const void* cs,
                            const void* ct, const void* cwf, const void* cbf, const void* csf,
                            const void* ctf, const void* pw1, const void* pb1, const void* pw2,
                            const void* pb2, const void* pq, const void* vw, const void* vb,
                            const void* vw4, const void* vb4, float* ws)
{
  const bool bfl = detect_bf16(x);
  f16* wf = (f16*)ws;
  const int t0 = blockIdx.x*blockDim.x + threadIdx.x;
  const int stride = gridDim.x*blockDim.x;

  for (int e = t0; e < GW_TOTAL; e += stride){
    float w;
    if (e < GW_L){
      int l = e >> 14, r = e & 16383;
      int kseg = r >> 10, col = (r >> 3) & 127, j = r & 7, k = kseg*8 + j;
      w = rd(cw, (l*128 + col)*128 + k, bfl) * rd(cs, l*128 + col, bfl);
    } else if (e < GW_F){
      int ee = e - GW_L;
      int lt = ee >> 14, r = ee & 16383;
      int kseg = r >> 10, col = (r >> 3) & 127, j = r & 7, k = kseg*8 + j;
      w = rd(lw23, lt*16384 + col*128 + k, bfl);
    } else if (e < GW_1){
      int ee = e - GW_F;
      int kseg = ee / 384, r = ee % 384, col = r >> 3, j = r & 7, k = kseg*8 + j;
      w = rd(cwf, col*128 + k, bfl) * rd(csf, col, bfl);
    } else {
      // L1 B: [kseg][col][8]; k=(tap<<1)|c for k<6, zero otherwise.
      int ee = e - GW_1;
      int kseg = ee >> 10, col = (ee >> 3) & 127, j = ee & 7;
      w = (kseg == 0 && j < 6) ? rd(lw1, ((j>>1)*128 + col)*2 + (j&1), bfl) : 0.0f;
    }
    wf[e] = (f16)w;
  }

  for (int i = t0; i < 6179; i += stride){
    float v; int s = i;
    if (s < 768){ int tap = s>>8, r = s&255, c = r>>7, o = r&127; v = rd(lw1,(tap*128+o)*2+c,bfl); }
    else if (s < 896){ v = rd(lb1, s-768, bfl); }
    else if (s < 1280){ int idx = s-896; v = rd(cb,idx,bfl)*rd(cs,idx,bfl)+rd(ct,idx,bfl); }
    else if (s < 1536){ v = rd(lb23, s-1280, bfl); }
    else if (s < 1584){ int m = s-1536; v = rd(cbf,m,bfl)*rd(csf,m,bfl)+rd(ctf,m,bfl); }
    else if (s < 1840){ v = rd(pw1, s-1584, bfl); }
    else if (s < 1856){ v = rd(pb1, s-1840, bfl); }
    else if (s < 2112){ v = rd(pw2, s-1856, bfl); }
    else if (s < 2128){ v = rd(pb2, s-2112, bfl); }
    else if (s < 2912){ v = rd(pq, s-2128, bfl); }
    else if (s < 5984){ float w = rd(vw, s-2912, bfl); w = fminf(fmaxf(w,-1.f),QMAXF); v = rintf(w*128.f)*0.0078125f; }
    else if (s < 6080){ v = rintf(rd(vb, s-5984, bfl)*16384.f)*6.103515625e-05f; }
    else if (s < 6176){ float w = rd(vw4, s-6080, bfl); w = fminf(fmaxf(w,-1.f),QMAXF); v = rintf(w*128.f)*0.0078125f; }
    else { v = rintf(rd(vb4, s-6176, bfl)*16384.f)*6.103515625e-05f; }
    ws[153600 + i] = v;
  }
}

// 2-sample row maps (absolute row index within the 144-row activation matrix).
template<int LMAP>
__device__ __forceinline__ int map_row2(int ro, int tap){
  if (LMAP == 0) return ro;
  if (LMAP == 1){
    int smp = ro >> 5, w = ro & 31, g = w >> 2, p = w & 3;
    return smp*72 + g*9 + (p>>1)*3 + (p&1) + (tap==0 ? 0 : (tap==1 ? 3 : 4));
  }
  int smp = ro >> 3, g = ro & 7;
  return smp*32 + g*4 + (tap==0 ? 0 : (tap==1 ? 2 : 3));
}

// Single in-place activation buffer: [16 kseg-planes][146 rows][8 f16].
// BS=146 keeps plane step = 8 banks mod 32 (144 would be 0 -> 4-way conflict).
#define BS 146

// Operand-swapped layer: D = mfma(W_frag, Act_frag) -> each thread holds
// 4 CONTIGUOUS out-channels (oc = wv*16 + lk*4 + r) at one position
// (p = nt*16 + lr); epilogue = 2x cvt_pkrtz + 1 ds_write_b64 per tile.
template<int NTILES, int ROW0, int TAPS, int LMAP>
__device__ __forceinline__ void layer_ip(const f16* __restrict__ wf, int wbase,
                                         const float* __restrict__ ws, int boff,
                                         f16* buf, int lane, int wv)
{
  const int lr = lane & 15;
  const int lk = lane >> 4;
  const int o0 = wv*16;
  const int oc = o0 + lk*4;            // thread's 4 contiguous channels

  const f16* srck = buf + lk*BS*8;                            // act base
  const f16* wbk  = wf + wbase + (lk*128 + o0 + lr)*8;        // weight base
  f16* dstw = buf + ((oc>>3)*BS + ROW0 + lr)*8 + (oc&7);      // store base

  f32x4 acc[NTILES];
  const f32x4 bb = *(const f32x4*)(ws + boff + oc);           // per-channel bias
  #pragma unroll
  for (int nt = 0; nt < NTILES; ++nt) acc[nt] = bb;

  #pragma unroll
  for (int tap = 0; tap < TAPS; ++tap){
    int rowoff[NTILES];
    #pragma unroll
    for (int nt = 0; nt < NTILES; ++nt)
      rowoff[nt] = map_row2<LMAP>(ROW0 + nt*16 + lr, tap) * 8;

    const f16* whk = wbk + tap*16384;

    #pragma unroll
    for (int s = 0; s < 4; ++s){
      f16x8 wa = *(const f16x8*)(whk + s*4096);
      #pragma unroll
      for (int nt = 0; nt < NTILES; ++nt){
        f16x8 ab = *(const f16x8*)(srck + s*4*BS*8 + rowoff[nt]);
        acc[nt] = __builtin_amdgcn_mfma_f32_16x16x32_f16(wa, ab, acc[nt], 0, 0, 0);
      }
    }
  }

  __syncthreads();   // all waves' reads complete before any write lands

  #pragma unroll
  for (int nt = 0; nt < NTILES; ++nt)
    *(f16x4*)(dstw + nt*128) = pk4(mish_f(acc[nt][0]), mish_f(acc[nt][1]),
                                   mish_f(acc[nt][2]), mish_f(acc[nt][3]));
}

__global__ __launch_bounds__(512, 8)
void fused_kernel(const void* __restrict__ xv, const float* __restrict__ ws, void* __restrict__ outv)
{
  // buf 37376 B + scratch 2304 B = 39680 B <= 40 KB -> 4 blocks/CU (32 w/CU).
  // Scratch layout (bytes): [0,1536) qbufh f16[16][48] (aliases a1 f16[144][8]
  // which is dead before qbufh is written); [1536,1920) featL f32[2][48];
  // [1920,2048) pk f32[2][16] (pkB aliases pkA: wave-lockstep => all lane
  // reads precede any lane write); [2048,2304) v f32[2][32] ping-pong.
  __shared__ __align__(16) f16 buf[16*BS*8];
  __shared__ __align__(16) unsigned char scratch[2304];

  f16*   a1    = (f16*)scratch;               // [144][8] f16 (2304 B, whole)
  f16*   qbufh = (f16*)scratch;               // [16][48] f16
  float* featL = (float*)(scratch + 1536);    // [2][48]
  float* pk    = (float*)(scratch + 1920);    // [2][16]
  float* vv    = (float*)(scratch + 2048);    // [2][32]

  const int tid  = threadIdx.x;
  const int lane = tid & 63;
  const int wv   = tid >> 6;                  // 0..7
  const int b    = blockIdx.x;                // 2 samples: b*2, b*2+1
  const bool bfl = detect_bf16(xv);
  const f16* wf  = (const f16*)ws;

  // Build A_L1[row=(smp,g,i,j)][k=(tap,c)] directly from global x.
  for (int e2 = tid; e2 < 576; e2 += 512){
    const int row = e2 >> 2, kh = e2 & 3;
    f16x2 hv = (f16x2){(f16)0.f, (f16)0.f};
    if (kh < 3){
      const int smp = row >= 72 ? 1 : 0;
      const int rr = row - 72*smp;
      const int g = (rr*57) >> 9;            // rr/9 for rr<72
      const int q = rr - 9*g;
      const int i = (q*11) >> 5;             // q/3 for q<9
      const int j = q - 3*i;
      const int ri = i + (kh >= 1), rj = j + (kh == 2);   // tap = kh
      const int kk = (0x13023120u >> (g*4)) & 0xF;
      const int y0 = (g >= 4) ? 3 : 0;
      const int x0 = (g >= 2 && g <= 5) ? 3 : 0;
      int sy, sx;
      if      (kk == 0){ sy = ri;     sx = rj;     }
      else if (kk == 1){ sy = rj;     sx = 3 - ri; }
      else if (kk == 2){ sy = 3 - ri; sx = 3 - rj; }
      else             { sy = 3 - rj; sx = ri;     }
      const int gi = (b*2 + smp)*98 + (y0 + sy)*7 + (x0 + sx);
      hv[0] = (f16)rd(xv, gi, bfl);        // c=0
      hv[1] = (f16)rd(xv, gi + 49, bfl);   // c=1
    }
    *(f16x2*)(a1 + row*8 + kh*2) = hv;
  }
  __syncthreads();

  // L1 as swapped MFMA (weights first operand; zeros for k>=6, ksegs 1..3 so
  // act second-operand reads can broadcast plane 0 for all lk).
  {
    const int lr = lane & 15, lk = lane >> 4;
    const int o0 = wv*16, oc = o0 + lk*4;
    const f16x8 wa = *(const f16x8*)(wf + GW_1 + (lk*128 + o0 + lr)*8);
    const f32x4 bb = *(const f32x4*)(ws + OFF_B1 + oc);
    f16* dstw = buf + ((oc>>3)*BS + lr)*8 + (oc&7);
    f32x4 acc[9];
    #pragma unroll
    for (int nt = 0; nt < 9; ++nt) acc[nt] = bb;
    #pragma unroll
    for (int nt = 0; nt < 9; ++nt){
      f16x8 ab = *(const f16x8*)(a1 + (nt*16 + lr)*8);
      acc[nt] = __builtin_amdgcn_mfma_f32_16x16x32_f16(wa, ab, acc[nt], 0, 0, 0);
    }
    #pragma unroll
    for (int nt = 0; nt < 9; ++nt)
      *(f16x4*)(dstw + nt*128) = pk4(mish_f(acc[nt][0]), mish_f(acc[nt][1]),
                                     mish_f(acc[nt][2]), mish_f(acc[nt][3]));
  }
  __syncthreads();

  // CH1 (144->144, K=128) split into two in-place row passes (reg pressure).
  layer_ip<5,  0, 1, 0>(wf, GW_C,         ws, OFF_CB,       buf, lane, wv);
  layer_ip<4, 80, 1, 0>(wf, GW_C,         ws, OFF_CB,       buf, lane, wv);
  __syncthreads();
  layer_ip<4,  0, 3, 1>(wf, GW_L,         ws, OFF_LB,       buf, lane, wv);   // L2: 144->64
  __syncthreads();
  layer_ip<4,  0, 1, 0>(wf, GW_C + 16384, ws, OFF_CB + 128, buf, lane, wv);   // CH2: 64->64
  __syncthreads();
  layer_ip<1,  0, 3, 2>(wf, GW_L + 49152, ws, OFF_LB + 128, buf, lane, wv);   // L3: 64->16
  __syncthreads();
  layer_ip<1,  0, 1, 0>(wf, GW_C + 32768, ws, OFF_CB + 256, buf, lane, wv);   // CH3: 16->16
  __syncthreads();

  // final 128->48 (no act) + fake_quant; waves 0..2 own 48 channels; each
  // thread holds 4 contiguous channels at position p=lr. Quantized values are
  // exact multiples of 1/128 with |k|<=127 -> f16 exact (RTZ lossless).
  if (wv < 3){
    const int lr = lane & 15, lk = lane >> 4;
    const int oc = wv*16 + lk*4;
    const f16* srck = buf + (lk*BS + lr)*8;
    const f16* wbk  = wf + GW_F + (lk*48 + wv*16 + lr)*8;
    f32x4 fa = *(const f32x4*)(ws + OFF_FB + oc);
    #pragma unroll
    for (int s = 0; s < 4; ++s){
      f16x8 wa = *(const f16x8*)(wbk + s*1536);
      f16x8 ab = *(const f16x8*)(srck + s*4*BS*8);
      fa = __builtin_amdgcn_mfma_f32_16x16x32_f16(wa, ab, fa, 0, 0, 0);
    }
    f32x4 q;
    #pragma unroll
    for (int r = 0; r < 4; ++r){
      float h = fminf(fmaxf(fa[r], -1.0f), QMAXF);
      q[r] = rintf(h * 128.0f) * 0.0078125f;
    }
    *(f16x4*)(qbufh + lr*48 + oc) = pk4(q[0], q[1], q[2], q[3]);  // p=lr
  }
  __syncthreads();

  // Heads: wave-local chains (in-wave lockstep => in-order LDS, no barriers).
  // wv0/1: policy smp0/1; wv2/3: value smp0/1.
  if (wv < 4){
    const int hsmp = wv & 1;
    const int bi = b*2 + hsmp;
    if (wv < 2){
      if (lane < 16){
        float f = 0.f;
        #pragma unroll
        for (int g = 0; g < 8; ++g) f += (float)qbufh[(hsmp*8 + g)*48 + lane];
        featL[hsmp*48 + lane] = f;
      }
      if (lane < 16){
        float a = ws[OFF_PB1 + lane];
        #pragma unroll
        for (int c = 0; c < 16; ++c) a = fmaf(featL[hsmp*48 + c], ws[OFF_PW1 + lane*16 + c], a);
        pk[hsmp*16 + lane] = fmaxf(a, 0.0f);
      }
      if (lane < 16){
        float a = ws[OFF_PB2 + lane];
        #pragma unroll
        for (int c = 0; c < 16; ++c) a = fmaf(pk[hsmp*16 + c], ws[OFF_PW2 + lane*16 + c], a);
        pk[hsmp*16 + lane] = a;   // pkB aliases pkA: all reads precede write (lockstep)
      }
      if (lane < 49){
        float a = 0.0f;
        #pragma unroll
        for (int c = 0; c < 16; ++c) a = fmaf(pk[hsmp*16 + c], ws[OFF_PQ + lane*16 + c], a);
        const int idx = 49152 + bi*49 + lane;
        if (bfl) ((__hip_bfloat16*)outv)[idx] = __float2bfloat16(a);
        else     ((float*)outv)[idx] = a;
      }
    } else {
      if (lane < 32){
        float f = 0.f;
        #pragma unroll
        for (int g = 0; g < 8; ++g) f += (float)qbufh[(hsmp*8 + g)*48 + 16 + lane];
        featL[hsmp*48 + 16 + lane] = f;
      }
      if (lane < 32){
        float a = ws[OFF_QB + lane];
        #pragma unroll
        for (int c = 0; c < 32; ++c)
          a = fmaf(fminf(fmaxf(featL[hsmp*48 + 16 + c], 0.0f), QMAXF), ws[OFF_QW + lane*32 + c], a);
        vv[hsmp*32 + lane] = a;
      }
      if (lane < 32){
        float a = ws[OFF_QB + 32 + lane];
        #pragma unroll
        for (int c = 0; c < 32; ++c)
          a = fmaf(fminf(fmaxf(vv[hsmp*32 + c], 0.0f), QMAXF), ws[OFF_QW + 1024 + lane*32 + c], a);
        vv[hsmp*32 + lane] = a;   // ping-pong alias: reads precede write (lockstep)
      }
      if (lane < 32){
        float a = ws[OFF_QB + 64 + lane];
        #pragma unroll
        for (int c = 0; c < 32; ++c)
          a = fmaf(fminf(fmaxf(vv[hsmp*32 + c], 0.0f), QMAXF), ws[OFF_QW + 2048 + lane*32 + c], a);
        vv[hsmp*32 + lane] = a;
      }
      if (lane < 3){
        float a = ws[OFF_QB4 + lane];
        #pragma unroll
        for (int c = 0; c < 32; ++c)
          a = fmaf(fminf(fmaxf(vv[hsmp*32 + c], 0.0f), QMAXF), ws[OFF_QW4 + lane*32 + c], a);
        const int idx = bi*3 + lane;
        if (bfl) ((__hip_bfloat16*)outv)[idx] = __float2bfloat16(a);
        else     ((float*)outv)[idx] = a;
      }
    }
  }
}

extern "C" void kernel_launch(void* const* d_in, const int* in_sizes, int n_in,
                              void* d_out, int out_size, void* d_ws, size_t ws_size,
                              hipStream_t stream)
{
  (void)in_sizes; (void)n_in; (void)out_size; (void)ws_size;
  float* ws = (float*)d_ws;
  prep_kernel<<<256, 256, 0, stream>>>(
      d_in[0],  d_in[1],  d_in[2],  d_in[3],  d_in[4],  d_in[5],  d_in[6],  d_in[7],
      d_in[8],  d_in[9],  d_in[10], d_in[11], d_in[12], d_in[13], d_in[14], d_in[15],
      d_in[16], d_in[17], d_in[18], d_in[19], d_in[20], d_in[21], ws);
  fused_kernel<<<8192, 512, 0, stream>>>(d_in[0], ws, d_out);
}

// Round 14
// 239.450 us; speedup vs baseline: 12.1328x; 1.0434x over previous
//
#include <hip/hip_runtime.h>
#include <hip/hip_bf16.h>

typedef _Float16 f16;
typedef f16 f16x2 __attribute__((ext_vector_type(2)));
typedef f16 f16x4 __attribute__((ext_vector_type(4)));
typedef f16 f16x8 __attribute__((ext_vector_type(8)));
typedef float f32x4 __attribute__((ext_vector_type(4)));

#define QMAXF (127.0f/128.0f)

// float-slot offsets for fp32 scalar region (round-8 numerics, unscaled).
enum {
  OFF_W1 = 153600, OFF_B1 = 154368, OFF_CB = 154496, OFF_LB = 154880,
  OFF_FB = 155136, OFF_PW1 = 155184, OFF_PB1 = 155440, OFF_PW2 = 155456,
  OFF_PB2 = 155712, OFF_PQ = 155728, OFF_QW = 156512, OFF_QB = 159584,
  OFF_QW4 = 159680, OFF_QB4 = 159776, WS_TOTAL = 159779
};
// f16-element offsets inside the weight region.
enum {
  GW_C = 0,            // 3 conv1x1 layers x [16 kseg][128 col][8]
  GW_L = 49152,        // 6 ladder tap-mats x 16384
  GW_F = 147456,       // final 128->48: [16 kseg][48 col][8]
  GW_1 = 153600,       // L1 MFMA B: [4 kseg][128][8], k=0..5 nonzero
  GW_TOTAL = 157696
};

__device__ __forceinline__ bool detect_bf16(const void* x){
  const unsigned short* u = (const unsigned short*)x;
  int hits = 0;
  #pragma unroll
  for (int i = 0; i < 32; i += 2){
    unsigned short h = u[i];
    hits += (h >= 0x3800 && h <= 0x3F80) ? 1 : 0;
  }
  return hits >= 12;
}

__device__ __forceinline__ float rd(const void* p, int i, bool bfl){
  return bfl ? __bfloat162float(((const __hip_bfloat16*)p)[i]) : ((const float*)p)[i];
}

// mish(x) = x - 2x/(u(u+2)+2), u = exp(x). Known-good form.
__device__ __forceinline__ float mish_f(float x){
  float u = __expf(x);
  float m = fmaf(u, u + 2.0f, 2.0f);
  return fmaf(-2.0f*x, __builtin_amdgcn_rcpf(m), x);
}

// pack 4 f32 -> 4 contiguous f16 (RTZ via v_cvt_pkrtz; bit_cast for typing).
__device__ __forceinline__ f16x4 pk4(float a, float b, float c, float d){
  f16x2 lo = __builtin_bit_cast(f16x2, __builtin_amdgcn_cvt_pkrtz(a, b));
  f16x2 hi = __builtin_bit_cast(f16x2, __builtin_amdgcn_cvt_pkrtz(c, d));
  return (f16x4){lo[0], lo[1], hi[0], hi[1]};
}

__global__ void prep_kernel(const void* x, const void* lw1, const void* lb1, const void* lw23,
                            const void* lb23, const void* cw, const void* cb, const void* cs,
                            const void* ct, const void* cwf, const void* cbf, const void* csf,
                            const void* ctf, const void* pw1, const void* pb1, const void* pw2,
                            const void* pb2, const void* pq, const void* vw, const void* vb,
                            const void* vw4, const void* vb4, float* ws)
{
  const bool bfl = detect_bf16(x);
  f16* wf = (f16*)ws;
  const int t0 = blockIdx.x*blockDim.x + threadIdx.x;
  const int stride = gridDim.x*blockDim.x;

  for (int e = t0; e < GW_TOTAL; e += stride){
    float w;
    if (e < GW_L){
      int l = e >> 14, r = e & 16383;
      int kseg = r >> 10, col = (r >> 3) & 127, j = r & 7, k = kseg*8 + j;
      w = rd(cw, (l*128 + col)*128 + k, bfl) * rd(cs, l*128 + col, bfl);
    } else if (e < GW_F){
      int ee = e - GW_L;
      int lt = ee >> 14, r = ee & 16383;
      int kseg = r >> 10, col = (r >> 3) & 127, j = r & 7, k = kseg*8 + j;
      w = rd(lw23, lt*16384 + col*128 + k, bfl);
    } else if (e < GW_1){
      int ee = e - GW_F;
      int kseg = ee / 384, r = ee % 384, col = r >> 3, j = r & 7, k = kseg*8 + j;
      w = rd(cwf, col*128 + k, bfl) * rd(csf, col, bfl);
    } else {
      // L1 B: [kseg][col][8]; k=(tap<<1)|c for k<6, zero otherwise.
      int ee = e - GW_1;
      int kseg = ee >> 10, col = (ee >> 3) & 127, j = ee & 7;
      w = (kseg == 0 && j < 6) ? rd(lw1, ((j>>1)*128 + col)*2 + (j&1), bfl) : 0.0f;
    }
    wf[e] = (f16)w;
  }

  for (int i = t0; i < 6179; i += stride){
    float v; int s = i;
    if (s < 768){ int tap = s>>8, r = s&255, c = r>>7, o = r&127; v = rd(lw1,(tap*128+o)*2+c,bfl); }
    else if (s < 896){ v = rd(lb1, s-768, bfl); }
    else if (s < 1280){ int idx = s-896; v = rd(cb,idx,bfl)*rd(cs,idx,bfl)+rd(ct,idx,bfl); }
    else if (s < 1536){ v = rd(lb23, s-1280, bfl); }
    else if (s < 1584){ int m = s-1536; v = rd(cbf,m,bfl)*rd(csf,m,bfl)+rd(ctf,m,bfl); }
    else if (s < 1840){ v = rd(pw1, s-1584, bfl); }
    else if (s < 1856){ v = rd(pb1, s-1840, bfl); }
    else if (s < 2112){ v = rd(pw2, s-1856, bfl); }
    else if (s < 2128){ v = rd(pb2, s-2112, bfl); }
    else if (s < 2912){ v = rd(pq, s-2128, bfl); }
    else if (s < 5984){ float w = rd(vw, s-2912, bfl); w = fminf(fmaxf(w,-1.f),QMAXF); v = rintf(w*128.f)*0.0078125f; }
    else if (s < 6080){ v = rintf(rd(vb, s-5984, bfl)*16384.f)*6.103515625e-05f; }
    else if (s < 6176){ float w = rd(vw4, s-6080, bfl); w = fminf(fmaxf(w,-1.f),QMAXF); v = rintf(w*128.f)*0.0078125f; }
    else { v = rintf(rd(vb4, s-6176, bfl)*16384.f)*6.103515625e-05f; }
    ws[153600 + i] = v;
  }
}

// Dead-position-eliminated row maps. L1/CH1 keep only the 8 of 9 positions
// the L2 ladder reads (q8: (0,0),(0,1),(1,0),(1,1),(1,2),(2,0),(2,1),(2,2);
// (0,2) is never consumed). 64 rows/sample -> 128 rows/block.
// LMAP1 (L2, 3x3-as-8 -> 2x2): out ro in [0,64): smp=ro>>5, g=(ro>>2)&7,
//   p=ro&3; src = smp*64 + g*8 + {p, p+2+(p>>1), p+3+(p>>1)}[tap]
//   (tap offsets verified: tap0={0,1,2,3}, tap1={2,3,5,6}, tap2={3,4,6,7}).
// LMAP2 (L3, 2x2 -> 1): src = smp*32 + g*4 + {0,2,3}[tap]  (unchanged).
template<int LMAP>
__device__ __forceinline__ int map_row2(int ro, int tap){
  if (LMAP == 0) return ro;
  if (LMAP == 1){
    int smp = ro >> 5, w = ro & 31, g = w >> 2, p = w & 3;
    int off = (tap == 0) ? p : (tap == 1 ? p + 2 + (p>>1) : p + 3 + (p>>1));
    return smp*64 + g*8 + off;
  }
  int smp = ro >> 3, g = ro & 7;
  return smp*32 + g*4 + (tap==0 ? 0 : (tap==1 ? 2 : 3));
}

// Single in-place activation buffer: [16 kseg-planes][130 rows][8 f16].
// BS=130: plane step = 520 words = 8 banks mod 32 (conflict-balanced).
#define BS 130

// Operand-swapped layer: D = mfma(W_frag, Act_frag) -> each thread holds
// 4 CONTIGUOUS out-channels (oc = wv*16 + lk*4 + r) at one position
// (p = nt*16 + lr); epilogue = 2x cvt_pkrtz + 1 ds_write_b64 per tile.
template<int NTILES, int ROW0, int TAPS, int LMAP>
__device__ __forceinline__ void layer_ip(const f16* __restrict__ wf, int wbase,
                                         const float* __restrict__ ws, int boff,
                                         f16* buf, int lane, int wv)
{
  const int lr = lane & 15;
  const int lk = lane >> 4;
  const int o0 = wv*16;
  const int oc = o0 + lk*4;            // thread's 4 contiguous channels

  const f16* srck = buf + lk*BS*8;                            // act base
  const f16* wbk  = wf + wbase + (lk*128 + o0 + lr)*8;        // weight base
  f16* dstw = buf + ((oc>>3)*BS + ROW0 + lr)*8 + (oc&7);      // store base

  f32x4 acc[NTILES];
  const f32x4 bb = *(const f32x4*)(ws + boff + oc);           // per-channel bias
  #pragma unroll
  for (int nt = 0; nt < NTILES; ++nt) acc[nt] = bb;

  #pragma unroll
  for (int tap = 0; tap < TAPS; ++tap){
    int rowoff[NTILES];
    #pragma unroll
    for (int nt = 0; nt < NTILES; ++nt)
      rowoff[nt] = map_row2<LMAP>(ROW0 + nt*16 + lr, tap) * 8;

    const f16* whk = wbk + tap*16384;

    #pragma unroll
    for (int s = 0; s < 4; ++s){
      f16x8 wa = *(const f16x8*)(whk + s*4096);
      #pragma unroll
      for (int nt = 0; nt < NTILES; ++nt){
        f16x8 ab = *(const f16x8*)(srck + s*4*BS*8 + rowoff[nt]);
        acc[nt] = __builtin_amdgcn_mfma_f32_16x16x32_f16(wa, ab, acc[nt], 0, 0, 0);
      }
    }
  }

  __syncthreads();   // all waves' reads complete before any write lands

  #pragma unroll
  for (int nt = 0; nt < NTILES; ++nt)
    *(f16x4*)(dstw + nt*128) = pk4(mish_f(acc[nt][0]), mish_f(acc[nt][1]),
                                   mish_f(acc[nt][2]), mish_f(acc[nt][3]));
}

__global__ __launch_bounds__(512, 8)
void fused_kernel(const void* __restrict__ xv, const float* __restrict__ ws, void* __restrict__ outv)
{
  // buf 33280 B + scratch 2304 B = 35584 B -> 4 blocks/CU (32 waves = max).
  // Scratch: [0,2048) a1 f16[128][8] / [0,1536) qbufh f16[16][48] (a1 dead
  // before qbufh written); [1536,1920) featL f32[2][48]; [1920,2048) pk
  // f32[2][16] (in-place alias, wave-lockstep); [2048,2304) vv f32[2][32].
  __shared__ __align__(16) f16 buf[16*BS*8];
  __shared__ __align__(16) unsigned char scratch[2304];

  f16*   a1    = (f16*)scratch;               // [128][8] f16 (2048 B)
  f16*   qbufh = (f16*)scratch;               // [16][48] f16
  float* featL = (float*)(scratch + 1536);    // [2][48]
  float* pk    = (float*)(scratch + 1920);    // [2][16]
  float* vv    = (float*)(scratch + 2048);    // [2][32]

  const int tid  = threadIdx.x;
  const int lane = tid & 63;
  const int wv   = tid >> 6;                  // 0..7
  const int b    = blockIdx.x;                // 2 samples: b*2, b*2+1
  const bool bfl = detect_bf16(xv);
  const f16* wf  = (const f16*)ws;

  // Build A_L1[row=(smp,g,q8)][k=(tap,c)] from global x. 128 rows x 4
  // kh-pairs = 512 items = exactly one per thread.
  {
    const int row = tid >> 2, kh = tid & 3;
    f16x2 hv = (f16x2){(f16)0.f, (f16)0.f};
    if (kh < 3){
      const int smp = row >> 6;
      const int rr  = row & 63;
      const int g   = rr >> 3;
      const int q8  = rr & 7;
      const int i = (q8 >= 2) + (q8 >= 5);               // q8 -> (i,j), skipping (0,2)
      const int j = q8 - (i == 1 ? 2 : (i == 2 ? 5 : 0));
      const int ri = i + (kh >= 1), rj = j + (kh == 2);  // tap = kh
      const int kk = (0x13023120u >> (g*4)) & 0xF;
      const int y0 = (g >= 4) ? 3 : 0;
      const int x0 = (g >= 2 && g <= 5) ? 3 : 0;
      int sy, sx;
      if      (kk == 0){ sy = ri;     sx = rj;     }
      else if (kk == 1){ sy = rj;     sx = 3 - ri; }
      else if (kk == 2){ sy = 3 - ri; sx = 3 - rj; }
      else             { sy = 3 - rj; sx = ri;     }
      const int gi = (b*2 + smp)*98 + (y0 + sy)*7 + (x0 + sx);
      hv[0] = (f16)rd(xv, gi, bfl);        // c=0
      hv[1] = (f16)rd(xv, gi + 49, bfl);   // c=1
    }
    *(f16x2*)(a1 + row*8 + kh*2) = hv;
  }
  __syncthreads();

  // L1 as swapped MFMA (weights first operand; zeros for k>=6, ksegs 1..3 so
  // act second-operand reads broadcast plane 0 for all lk). 128 rows = 8 tiles.
  {
    const int lr = lane & 15, lk = lane >> 4;
    const int o0 = wv*16, oc = o0 + lk*4;
    const f16x8 wa = *(const f16x8*)(wf + GW_1 + (lk*128 + o0 + lr)*8);
    const f32x4 bb = *(const f32x4*)(ws + OFF_B1 + oc);
    f16* dstw = buf + ((oc>>3)*BS + lr)*8 + (oc&7);
    f32x4 acc[8];
    #pragma unroll
    for (int nt = 0; nt < 8; ++nt) acc[nt] = bb;
    #pragma unroll
    for (int nt = 0; nt < 8; ++nt){
      f16x8 ab = *(const f16x8*)(a1 + (nt*16 + lr)*8);
      acc[nt] = __builtin_amdgcn_mfma_f32_16x16x32_f16(wa, ab, acc[nt], 0, 0, 0);
    }
    #pragma unroll
    for (int nt = 0; nt < 8; ++nt)
      *(f16x4*)(dstw + nt*128) = pk4(mish_f(acc[nt][0]), mish_f(acc[nt][1]),
                                     mish_f(acc[nt][2]), mish_f(acc[nt][3]));
  }
  __syncthreads();

  // CH1 (128 rows, K=128) split into two in-place row passes (reg pressure).
  layer_ip<4,  0, 1, 0>(wf, GW_C,         ws, OFF_CB,       buf, lane, wv);
  layer_ip<4, 64, 1, 0>(wf, GW_C,         ws, OFF_CB,       buf, lane, wv);
  __syncthreads();
  layer_ip<4,  0, 3, 1>(wf, GW_L,         ws, OFF_LB,       buf, lane, wv);   // L2: 128->64
  __syncthreads();
  layer_ip<4,  0, 1, 0>(wf, GW_C + 16384, ws, OFF_CB + 128, buf, lane, wv);   // CH2: 64->64
  __syncthreads();
  layer_ip<1,  0, 3, 2>(wf, GW_L + 49152, ws, OFF_LB + 128, buf, lane, wv);   // L3: 64->16
  __syncthreads();
  layer_ip<1,  0, 1, 0>(wf, GW_C + 32768, ws, OFF_CB + 256, buf, lane, wv);   // CH3: 16->16
  __syncthreads();

  // final 128->48 (no act) + fake_quant; waves 0..2 own 48 channels; each
  // thread holds 4 contiguous channels at position p=lr. Quantized values are
  // exact multiples of 1/128 with |k|<=128 -> f16 exact (RTZ lossless).
  if (wv < 3){
    const int lr = lane & 15, lk = lane >> 4;
    const int oc = wv*16 + lk*4;
    const f16* srck = buf + (lk*BS + lr)*8;
    const f16* wbk  = wf + GW_F + (lk*48 + wv*16 + lr)*8;
    f32x4 fa = *(const f32x4*)(ws + OFF_FB + oc);
    #pragma unroll
    for (int s = 0; s < 4; ++s){
      f16x8 wa = *(const f16x8*)(wbk + s*1536);
      f16x8 ab = *(const f16x8*)(srck + s*4*BS*8);
      fa = __builtin_amdgcn_mfma_f32_16x16x32_f16(wa, ab, fa, 0, 0, 0);
    }
    f32x4 q;
    #pragma unroll
    for (int r = 0; r < 4; ++r){
      float h = fminf(fmaxf(fa[r], -1.0f), QMAXF);
      q[r] = rintf(h * 128.0f) * 0.0078125f;
    }
    *(f16x4*)(qbufh + lr*48 + oc) = pk4(q[0], q[1], q[2], q[3]);  // p=lr
  }
  __syncthreads();

  // Heads: wave-local chains (in-wave lockstep => in-order LDS, no barriers).
  // wv0/1: policy smp0/1; wv2/3: value smp0/1.
  if (wv < 4){
    const int hsmp = wv & 1;
    const int bi = b*2 + hsmp;
    if (wv < 2){
      if (lane < 16){
        float f = 0.f;
        #pragma unroll
        for (int g = 0; g < 8; ++g) f += (float)qbufh[(hsmp*8 + g)*48 + lane];
        featL[hsmp*48 + lane] = f;
      }
      if (lane < 16){
        float a = ws[OFF_PB1 + lane];
        #pragma unroll
        for (int c = 0; c < 16; ++c) a = fmaf(featL[hsmp*48 + c], ws[OFF_PW1 + lane*16 + c], a);
        pk[hsmp*16 + lane] = fmaxf(a, 0.0f);
      }
      if (lane < 16){
        float a = ws[OFF_PB2 + lane];
        #pragma unroll
        for (int c = 0; c < 16; ++c) a = fmaf(pk[hsmp*16 + c], ws[OFF_PW2 + lane*16 + c], a);
        pk[hsmp*16 + lane] = a;   // in-place alias: reads precede write (lockstep)
      }
      if (lane < 49){
        float a = 0.0f;
        #pragma unroll
        for (int c = 0; c < 16; ++c) a = fmaf(pk[hsmp*16 + c], ws[OFF_PQ + lane*16 + c], a);
        const int idx = 49152 + bi*49 + lane;
        if (bfl) ((__hip_bfloat16*)outv)[idx] = __float2bfloat16(a);
        else     ((float*)outv)[idx] = a;
      }
    } else {
      if (lane < 32){
        float f = 0.f;
        #pragma unroll
        for (int g = 0; g < 8; ++g) f += (float)qbufh[(hsmp*8 + g)*48 + 16 + lane];
        featL[hsmp*48 + 16 + lane] = f;
      }
      if (lane < 32){
        float a = ws[OFF_QB + lane];
        #pragma unroll
        for (int c = 0; c < 32; ++c)
          a = fmaf(fminf(fmaxf(featL[hsmp*48 + 16 + c], 0.0f), QMAXF), ws[OFF_QW + lane*32 + c], a);
        vv[hsmp*32 + lane] = a;
      }
      if (lane < 32){
        float a = ws[OFF_QB + 32 + lane];
        #pragma unroll
        for (int c = 0; c < 32; ++c)
          a = fmaf(fminf(fmaxf(vv[hsmp*32 + c], 0.0f), QMAXF), ws[OFF_QW + 1024 + lane*32 + c], a);
        vv[hsmp*32 + lane] = a;   // in-place alias: reads precede write (lockstep)
      }
      if (lane < 32){
        float a = ws[OFF_QB + 64 + lane];
        #pragma unroll
        for (int c = 0; c < 32; ++c)
          a = fmaf(fminf(fmaxf(vv[hsmp*32 + c], 0.0f), QMAXF), ws[OFF_QW + 2048 + lane*32 + c], a);
        vv[hsmp*32 + lane] = a;
      }
      if (lane < 3){
        float a = ws[OFF_QB4 + lane];
        #pragma unroll
        for (int c = 0; c < 32; ++c)
          a = fmaf(fminf(fmaxf(vv[hsmp*32 + c], 0.0f), QMAXF), ws[OFF_QW4 + lane*32 + c], a);
        const int idx = bi*3 + lane;
        if (bfl) ((__hip_bfloat16*)outv)[idx] = __float2bfloat16(a);
        else     ((float*)outv)[idx] = a;
      }
    }
  }
}

extern "C" void kernel_launch(void* const* d_in, const int* in_sizes, int n_in,
                              void* d_out, int out_size, void* d_ws, size_t ws_size,
                              hipStream_t stream)
{
  (void)in_sizes; (void)n_in; (void)out_size; (void)ws_size;
  float* ws = (float*)d_ws;
  prep_kernel<<<256, 256, 0, stream>>>(
      d_in[0],  d_in[1],  d_in[2],  d_in[3],  d_in[4],  d_in[5],  d_in[6],  d_in[7],
      d_in[8],  d_in[9],  d_in[10], d_in[11], d_in[12], d_in[13], d_in[14], d_in[15],
      d_in[16], d_in[17], d_in[18], d_in[19], d_in[20], d_in[21], ws);
  fused_kernel<<<8192, 512, 0, stream>>>(d_in[0], ws, d_out);
}